// Round 1
// baseline (8393.594 us; speedup 1.0000x reference)
//
#include <hip/hip_runtime.h>
#include <math.h>
#include <cmath>

#define SEQ   512
#define NBATCH 64
#define BT    32768      // 64*512 tokens
#define HID   128
#define NHEAD 4
#define HD    32
#define VHD   64
#define VDIM  256
#define FFND  256

__device__ __forceinline__ float gelu_f(float x){ return 0.5f*x*(1.f+erff(x*0.70710678118f)); }

// ---------------- embed: x(BT,5) -> gelu chain -> X(BT,128) ----------------
__global__ __launch_bounds__(256) void embed_kernel(
    const float* __restrict__ x,
    const float* __restrict__ w1, const float* __restrict__ b1,
    const float* __restrict__ w2, const float* __restrict__ b2,
    const float* __restrict__ w3, const float* __restrict__ b3,
    float* __restrict__ X)
{
  __shared__ float sw1[5*32], sw2[32*64], sw3[64*128];
  __shared__ float sb1[32], sb2[64], sb3[128];
  __shared__ float sx[32][6], sh1[32][33], sh2[32][65];
  int t = threadIdx.x;
  for(int i=t;i<160;i+=256)  sw1[i]=w1[i];
  for(int i=t;i<2048;i+=256) sw2[i]=w2[i];
  for(int i=t;i<8192;i+=256) sw3[i]=w3[i];
  if(t<32)  sb1[t]=b1[t];
  if(t<64)  sb2[t]=b2[t];
  if(t<128) sb3[t]=b3[t];
  int tok0 = blockIdx.x*32;
  for(int i=t;i<160;i+=256) sx[i/5][i%5] = x[tok0*5+i];
  __syncthreads();
  // phase1: 32 tok x 32 out
  for(int task=t; task<1024; task+=256){
    int j=task&31, tok=task>>5;
    float a=sb1[j];
    #pragma unroll
    for(int i=0;i<5;i++) a += sx[tok][i]*sw1[i*32+j];
    sh1[tok][j]=gelu_f(a);
  }
  __syncthreads();
  // phase2: 32 tok x 64 out
  for(int task=t; task<2048; task+=256){
    int j=task&63, tok=task>>6;
    float a=sb2[j];
    for(int i=0;i<32;i++) a += sh1[tok][i]*sw2[i*64+j];
    sh2[tok][j]=gelu_f(a);
  }
  __syncthreads();
  // phase3: 32 tok x 128 out
  for(int task=t; task<4096; task+=256){
    int j=task&127, tok=task>>7;
    float a=sb3[j];
    for(int i=0;i<64;i++) a += sh2[tok][i]*sw3[i*128+j];
    X[(tok0+tok)*128 + j]=gelu_f(a);
  }
}

// ---------------- layernorm over 128, wave per token ----------------
__global__ __launch_bounds__(256) void ln_kernel(
    const float* __restrict__ in, const float* __restrict__ w,
    const float* __restrict__ b, float* __restrict__ out)
{
  int wv = threadIdx.x>>6, lane = threadIdx.x&63;
  int tok = blockIdx.x*4 + wv;
  const float* row = in + (size_t)tok*128;
  float x0 = row[lane], x1 = row[lane+64];
  float s = x0+x1, sq = x0*x0+x1*x1;
  #pragma unroll
  for(int off=32; off; off>>=1){ s += __shfl_down(s,off); sq += __shfl_down(sq,off); }
  s = __shfl(s,0); sq = __shfl(sq,0);
  float mu = s*(1.f/128.f);
  float var = sq*(1.f/128.f) - mu*mu;
  float r = rsqrtf(var + 1e-5f);
  out[(size_t)tok*128+lane]    = (x0-mu)*r*w[lane]    + b[lane];
  out[(size_t)tok*128+lane+64] = (x1-mu)*r*w[lane+64] + b[lane+64];
}

// ---------------- fused Q/K/V/G projection with xPos on Q,K ----------------
// Layouts: Q,K: ((b*4+n)*512+l)*32+d ; V: ((b*4+n)*512+l)*64+v ; G: tok*256+v
__global__ __launch_bounds__(256) void qkvg_kernel(
    const float* __restrict__ Xn,
    const float* __restrict__ wq, const float* __restrict__ wk,
    const float* __restrict__ wv, const float* __restrict__ wg,
    float* __restrict__ Q, float* __restrict__ K,
    float* __restrict__ V, float* __restrict__ G)
{
  __shared__ float sX[8][132];
  int t = threadIdx.x;
  int tok0 = blockIdx.x*8;
  for(int i=t;i<1024;i+=256) sX[i>>7][i&127] = Xn[(size_t)tok0*128 + i];
  __syncthreads();
  // 384 pair-tasks per token, token-major so a wave shares one token
  for(int task=t; task<3072; task+=256){
    int tk = task/384, sub = task - tk*384;
    int tok = tok0 + tk; int bb = tok>>9, l = tok&511;
    const float* xr = sX[tk];
    float a0=0.f, a1=0.f;
    if(sub < 128){
      int isK = sub>=64; int p = sub&63; int n = p>>4, i = p&15;
      const float* W = (isK?wk:wq) + n*(128*32) + 2*i;
      for(int h=0;h<128;h++){ float xv=xr[h]; a0 += xv*W[h*32]; a1 += xv*W[h*32+1]; }
      float bs = ((float)i + 12.8f)/44.8f;
      float sc = powf(bs, (float)l*(1.f/512.f));
      if(isK) sc = 1.f/sc;
      float invf = powf(10000.f, -(float)i*(1.f/16.f));
      float ang = (float)l * invf;
      float cs = cosf(ang)*sc, sn = sinf(ang)*sc;
      float o0 = a0*cs - a1*sn;
      float o1 = a1*cs + a0*sn;
      float* O = isK ? K : Q;
      size_t base = ((size_t)(bb*4+n)*512 + l)*32 + 2*i;
      O[base] = o0; O[base+1] = o1;
    } else if(sub < 256){
      int p = sub-128; int n = p>>5, j = p&31;
      const float* W = wv + n*(128*64) + 2*j;
      for(int h=0;h<128;h++){ float xv=xr[h]; a0 += xv*W[h*64]; a1 += xv*W[h*64+1]; }
      size_t base = ((size_t)(bb*4+n)*512 + l)*64 + 2*j;
      V[base]=a0; V[base+1]=a1;
    } else {
      int p = sub-256;
      const float* W = wg + 2*p;
      for(int h=0;h<128;h++){ float xv=xr[h]; a0 += xv*W[h*256]; a1 += xv*W[h*256+1]; }
      G[(size_t)tok*256 + 2*p]   = a0;
      G[(size_t)tok*256 + 2*p+1] = a1;
    }
  }
}

// ---------------- retention: per (b,n) pair, quadratic, tiled 64x64 ----------------
__global__ __launch_bounds__(256) void retention_kernel(
    const float* __restrict__ Q, const float* __restrict__ K,
    const float* __restrict__ V, float* __restrict__ R, float4 log2g)
{
  int bn = blockIdx.x >> 3, lt = blockIdx.x & 7;
  int n = bn & 3;
  float lg2g = (n==0)?log2g.x:(n==1)?log2g.y:(n==2)?log2g.z:log2g.w;
  __shared__ float sQ[64][33];
  __shared__ float sK[64][33];
  __shared__ float sV[64][65];
  __shared__ float sS[64][65];
  int t = threadIdx.x;
  size_t qbase = ((size_t)bn*512 + lt*64)*32;
  for(int i=t;i<2048;i+=256) sQ[i>>5][i&31] = Q[qbase + i];
  __syncthreads();
  int lrow = t>>2, j0 = (t&3)*16;
  float qreg[32];
  #pragma unroll
  for(int d=0;d<32;d++) qreg[d] = sQ[lrow][d];
  float acc[16];
  #pragma unroll
  for(int i=0;i<16;i++) acc[i]=0.f;
  int lglob = lt*64 + lrow;
  int m0 = (t&3)*16;
  for(int mt=0; mt<=lt; mt++){
    __syncthreads();
    size_t kbase = ((size_t)bn*512 + mt*64)*32;
    size_t vbase = ((size_t)bn*512 + mt*64)*64;
    for(int i=t;i<2048;i+=256) sK[i>>5][i&31] = K[kbase + i];
    for(int i=t;i<4096;i+=256) sV[i>>6][i&63] = V[vbase + i];
    __syncthreads();
    float sv[16];
    #pragma unroll
    for(int mm=0;mm<16;mm++){
      int m = m0+mm;
      float a=0.f;
      #pragma unroll
      for(int d=0;d<32;d++) a += qreg[d]*sK[m][d];
      int diff = lglob - (mt*64 + m);
      float wgt = (diff>=0) ? exp2f(lg2g*(float)diff) : 0.f;
      sv[mm] = a*wgt;
    }
    #pragma unroll
    for(int mm=0;mm<16;mm++) sS[lrow][m0+mm]=sv[mm];
    __syncthreads();
    for(int m=0;m<64;m++){
      float sc = sS[lrow][m];
      const float* vr = &sV[m][j0];
      #pragma unroll
      for(int jj=0;jj<16;jj++) acc[jj] += sc*vr[jj];
    }
  }
  size_t rbase = ((size_t)bn*512 + lt*64 + lrow)*64 + j0;
  #pragma unroll
  for(int jj=0;jj<16;jj+=4){
    float4 v4 = make_float4(acc[jj],acc[jj+1],acc[jj+2],acc[jj+3]);
    *(float4*)(R + rbase + jj) = v4;
  }
}

// ---------------- groupnorm(4x64) + affine + silu(G) gate -> gated(BT,256) ----------------
__global__ __launch_bounds__(256) void gatenorm_kernel(
    const float* __restrict__ R, const float* __restrict__ G,
    const float* __restrict__ gnw, const float* __restrict__ gnb,
    float* __restrict__ out)
{
  int wv = threadIdx.x>>6, lane = threadIdx.x&63;
  int tok = blockIdx.x*4 + wv;
  int bb = tok>>9, l = tok&511;
  int n = lane>>4, v0 = (lane&15)*4;
  const float* rp = R + ((size_t)(bb*4+n)*512 + l)*64 + v0;
  float4 y = *(const float4*)rp;
  float yy[4] = {y.x,y.y,y.z,y.w};
  float s = yy[0]+yy[1]+yy[2]+yy[3];
  float sq = yy[0]*yy[0]+yy[1]*yy[1]+yy[2]*yy[2]+yy[3]*yy[3];
  #pragma unroll
  for(int m=1;m<16;m<<=1){ s += __shfl_xor(s,m); sq += __shfl_xor(sq,m); }
  float mu = s*(1.f/64.f);
  float var = sq*(1.f/64.f) - mu*mu;
  float r = rsqrtf(var + 1e-5f);
  int vb = n*64 + v0;
  float o[4];
  #pragma unroll
  for(int i=0;i<4;i++){
    float gg = G[(size_t)tok*256 + vb + i];
    float gate = gg/(1.f+expf(-gg));
    o[i] = gate * ((yy[i]-mu)*r*gnw[vb+i] + gnb[vb+i]);
  }
  *(float4*)(out + (size_t)tok*256 + vb) = make_float4(o[0],o[1],o[2],o[3]);
}

// ---------------- generic skinny GEMM: out(BT,ND) = act(A(BT,KD) @ W + bias) + resid ----------------
template<int KD, int ND, int ACT>
__global__ __launch_bounds__(256) void gemm_kernel(
    const float* __restrict__ A, const float* __restrict__ W,
    const float* __restrict__ bias, const float* __restrict__ resid,
    float* __restrict__ out)
{
  __shared__ float sA[8][KD+4];
  int t = threadIdx.x;
  int tok0 = blockIdx.x*8;
  for(int i=t;i<8*KD;i+=256){ int rr=i/KD, cc=i-rr*KD; sA[rr][cc]=A[(size_t)tok0*KD + i]; }
  __syncthreads();
  constexpr int NP = ND/2;
  for(int task=t; task<NP*8; task+=256){
    int tk = task/NP, sub = task - tk*NP;
    const float* xr = sA[tk];
    const float* Wp = W + 2*sub;
    float a0 = bias ? bias[2*sub]   : 0.f;
    float a1 = bias ? bias[2*sub+1] : 0.f;
    for(int h=0;h<KD;h++){ float xv=xr[h]; a0 += xv*Wp[h*ND]; a1 += xv*Wp[h*ND+1]; }
    if(ACT==1){ a0=gelu_f(a0); a1=gelu_f(a1); }
    int tok = tok0 + tk;
    if(resid){ a0 += resid[(size_t)tok*ND + 2*sub]; a1 += resid[(size_t)tok*ND + 2*sub+1]; }
    out[(size_t)tok*ND + 2*sub]   = a0;
    out[(size_t)tok*ND + 2*sub+1] = a1;
  }
}

// ---------------- decoder: gelu(X@w1+b1)@w2+b2 -> softmax(20) ----------------
__global__ __launch_bounds__(64) void dec_kernel(
    const float* __restrict__ X,
    const float* __restrict__ w1, const float* __restrict__ b1,
    const float* __restrict__ w2, const float* __restrict__ b2,
    float* __restrict__ out)
{
  __shared__ float sX[64][129];
  int t = threadIdx.x;
  int tok0 = blockIdx.x*64;
  for(int i=t;i<8192;i+=64){ sX[i>>7][i&127] = X[(size_t)tok0*128 + i]; }
  __syncthreads();
  float h[64];
  #pragma unroll
  for(int j=0;j<64;j++) h[j]=b1[j];
  for(int k=0;k<128;k++){
    float xv = sX[t][k];
    const float* wr = w1 + k*64;
    #pragma unroll
    for(int j=0;j<64;j++) h[j] += xv*wr[j];
  }
  #pragma unroll
  for(int j=0;j<64;j++) h[j]=gelu_f(h[j]);
  float lg[20];
  #pragma unroll
  for(int o=0;o<20;o++) lg[o]=b2[o];
  #pragma unroll
  for(int j=0;j<64;j++){
    float hv = h[j];
    const float* wr = w2 + j*20;
    #pragma unroll
    for(int o=0;o<20;o++) lg[o] += hv*wr[o];
  }
  float mx = -1e30f;
  #pragma unroll
  for(int o=0;o<20;o++) mx = fmaxf(mx, lg[o]);
  float sum = 0.f;
  #pragma unroll
  for(int o=0;o<20;o++){ lg[o]=expf(lg[o]-mx); sum += lg[o]; }
  float inv = 1.f/sum;
  int tok = tok0 + t;
  #pragma unroll
  for(int o=0;o<20;o++) out[(size_t)tok*20 + o] = lg[o]*inv;
}

extern "C" void kernel_launch(void* const* d_in, const int* in_sizes, int n_in,
                              void* d_out, int out_size, void* d_ws, size_t ws_size,
                              hipStream_t stream) {
  (void)in_sizes; (void)n_in; (void)out_size; (void)ws_size;
  const float* x      = (const float*)d_in[0];
  const float* rem_w1 = (const float*)d_in[1];
  const float* rem_b1 = (const float*)d_in[2];
  const float* rem_w2 = (const float*)d_in[3];
  const float* rem_b2 = (const float*)d_in[4];
  const float* rem_w3 = (const float*)d_in[5];
  const float* rem_b3 = (const float*)d_in[6];
  const float* wq     = (const float*)d_in[7];
  const float* wk     = (const float*)d_in[8];
  const float* wv     = (const float*)d_in[9];
  const float* wg     = (const float*)d_in[10];
  const float* wo     = (const float*)d_in[11];
  const float* gn_w   = (const float*)d_in[12];
  const float* gn_b   = (const float*)d_in[13];
  const float* ln1_w  = (const float*)d_in[14];
  const float* ln1_b  = (const float*)d_in[15];
  const float* ln2_w  = (const float*)d_in[16];
  const float* ln2_b  = (const float*)d_in[17];
  const float* ffn_w1 = (const float*)d_in[18];
  const float* ffn_b1 = (const float*)d_in[19];
  const float* ffn_w2 = (const float*)d_in[20];
  const float* ffn_b2 = (const float*)d_in[21];
  const float* dec_w1 = (const float*)d_in[22];
  const float* dec_b1 = (const float*)d_in[23];
  const float* dec_w2 = (const float*)d_in[24];
  const float* dec_b2 = (const float*)d_in[25];
  float* outp = (float*)d_out;

  // workspace layout (fp32 elements)
  const size_t S128 = (size_t)BT*128;   // 4,194,304
  const size_t S256 = (size_t)BT*256;   // 8,388,608
  float* ws  = (float*)d_ws;
  float* Xb  = ws;                 // X
  float* Xn  = Xb + S128;          // LN out / Z
  float* Qb  = Xn + S128;
  float* Kb  = Qb + S128;
  float* Yr  = Kb + S128;          // residual stream Y
  float* Vb  = Yr + S128;          // V, then gated
  float* Gb  = Vb + S256;          // G, then FFN hidden
  float* Rb  = Gb + S256;          // retention out

  // per-head decay log2(gamma), computed in double to match numpy
  double lgA = log(1.0/32.0), lgB = log(1.0/512.0);
  float4 l2g;
  {
    double g0 = 1.0 - exp(lgA + 0.0*(lgB-lgA)/3.0);
    double g1 = 1.0 - exp(lgA + 1.0*(lgB-lgA)/3.0);
    double g2 = 1.0 - exp(lgA + 2.0*(lgB-lgA)/3.0);
    double g3 = 1.0 - exp(lgA + 3.0*(lgB-lgA)/3.0);
    l2g.x = (float)(log(g0)/log(2.0));
    l2g.y = (float)(log(g1)/log(2.0));
    l2g.z = (float)(log(g2)/log(2.0));
    l2g.w = (float)(log(g3)/log(2.0));
  }

  embed_kernel<<<BT/32, 256, 0, stream>>>(x, rem_w1, rem_b1, rem_w2, rem_b2, rem_w3, rem_b3, Xb);

  for(int li=0; li<4; li++){
    const float* wq_l  = wq + (size_t)li*NHEAD*HID*HD;   // 16384
    const float* wk_l  = wk + (size_t)li*NHEAD*HID*HD;
    const float* wv_l  = wv + (size_t)li*NHEAD*HID*VHD;  // 32768
    const float* wg_l  = wg + (size_t)li*HID*VDIM;       // 32768
    const float* wo_l  = wo + (size_t)li*VDIM*HID;       // 32768
    const float* gnw_l = gn_w + (size_t)li*VDIM;
    const float* gnb_l = gn_b + (size_t)li*VDIM;
    const float* l1w = ln1_w + (size_t)li*HID, *l1b = ln1_b + (size_t)li*HID;
    const float* l2w = ln2_w + (size_t)li*HID, *l2b = ln2_b + (size_t)li*HID;
    const float* f1w = ffn_w1 + (size_t)li*HID*FFND, *f1b = ffn_b1 + (size_t)li*FFND;
    const float* f2w = ffn_w2 + (size_t)li*FFND*HID, *f2b = ffn_b2 + (size_t)li*HID;

    ln_kernel<<<BT/4, 256, 0, stream>>>(Xb, l1w, l1b, Xn);
    qkvg_kernel<<<BT/8, 256, 0, stream>>>(Xn, wq_l, wk_l, wv_l, wg_l, Qb, Kb, Vb, Gb);
    retention_kernel<<<256*8, 256, 0, stream>>>(Qb, Kb, Vb, Rb, l2g);
    gatenorm_kernel<<<BT/4, 256, 0, stream>>>(Rb, Gb, gnw_l, gnb_l, Vb);   // gated -> Vb
    gemm_kernel<256,128,0><<<BT/8, 256, 0, stream>>>(Vb, wo_l, nullptr, Xb, Yr);  // Y = gated@wo + X
    ln_kernel<<<BT/4, 256, 0, stream>>>(Yr, l2w, l2b, Xn);
    gemm_kernel<128,256,1><<<BT/8, 256, 0, stream>>>(Xn, f1w, f1b, nullptr, Gb);  // H = gelu(Z@w1+b1)
    gemm_kernel<256,128,0><<<BT/8, 256, 0, stream>>>(Gb, f2w, f2b, Yr, Xb);       // X = H@w2+b2+Y
  }

  dec_kernel<<<BT/64, 64, 0, stream>>>(Xb, dec_w1, dec_b1, dec_w2, dec_b2, outp);
}

// Round 2
// 3338.555 us; speedup vs baseline: 2.5141x; 2.5141x over previous
//
#include <hip/hip_runtime.h>
#include <math.h>
#include <cmath>

#define SEQ   512
#define NBATCH 64
#define BT    32768      // 64*512 tokens
#define HID   128
#define NHEAD 4
#define HD    32
#define VHD   64
#define VDIM  256
#define FFND  256

typedef __attribute__((ext_vector_type(8))) short bf16x8;
typedef __attribute__((ext_vector_type(4))) float f32x4;
typedef unsigned short u16;

__device__ __forceinline__ float gelu_f(float x){ return 0.5f*x*(1.f+erff(x*0.70710678118f)); }

__device__ __forceinline__ u16 f2bf(float f){
  union{float f; unsigned u;} v; v.f = f;
  unsigned r = v.u + 0x7FFF + ((v.u>>16)&1);
  return (u16)(r>>16);
}
__device__ __forceinline__ float bf2f(u16 u){
  union{unsigned u; float f;} v; v.u = ((unsigned)u)<<16; return v.f;
}

// ---------------- embed: x(BT,5) -> gelu chain -> X(BT,128) ----------------
__global__ __launch_bounds__(256) void embed_kernel(
    const float* __restrict__ x,
    const float* __restrict__ w1, const float* __restrict__ b1,
    const float* __restrict__ w2, const float* __restrict__ b2,
    const float* __restrict__ w3, const float* __restrict__ b3,
    float* __restrict__ X)
{
  __shared__ float sw1[5*32], sw2[32*64], sw3[64*128];
  __shared__ float sb1[32], sb2[64], sb3[128];
  __shared__ float sx[32][6], sh1[32][33], sh2[32][65];
  int t = threadIdx.x;
  for(int i=t;i<160;i+=256)  sw1[i]=w1[i];
  for(int i=t;i<2048;i+=256) sw2[i]=w2[i];
  for(int i=t;i<8192;i+=256) sw3[i]=w3[i];
  if(t<32)  sb1[t]=b1[t];
  if(t<64)  sb2[t]=b2[t];
  if(t<128) sb3[t]=b3[t];
  int tok0 = blockIdx.x*32;
  for(int i=t;i<160;i+=256) sx[i/5][i%5] = x[tok0*5+i];
  __syncthreads();
  for(int task=t; task<1024; task+=256){
    int j=task&31, tok=task>>5;
    float a=sb1[j];
    #pragma unroll
    for(int i=0;i<5;i++) a += sx[tok][i]*sw1[i*32+j];
    sh1[tok][j]=gelu_f(a);
  }
  __syncthreads();
  for(int task=t; task<2048; task+=256){
    int j=task&63, tok=task>>6;
    float a=sb2[j];
    for(int i=0;i<32;i++) a += sh1[tok][i]*sw2[i*64+j];
    sh2[tok][j]=gelu_f(a);
  }
  __syncthreads();
  for(int task=t; task<4096; task+=256){
    int j=task&127, tok=task>>7;
    float a=sb3[j];
    for(int i=0;i<64;i++) a += sh2[tok][i]*sw3[i*128+j];
    X[(tok0+tok)*128 + j]=gelu_f(a);
  }
}

// ---------------- layernorm over 128, wave per token, bf16 out ----------------
__global__ __launch_bounds__(256) void ln_kernel(
    const float* __restrict__ in, const float* __restrict__ w,
    const float* __restrict__ b, u16* __restrict__ out)
{
  int wv = threadIdx.x>>6, lane = threadIdx.x&63;
  int tok = blockIdx.x*4 + wv;
  const float* row = in + (size_t)tok*128;
  float x0 = row[lane], x1 = row[lane+64];
  float s = x0+x1, sq = x0*x0+x1*x1;
  #pragma unroll
  for(int off=32; off; off>>=1){ s += __shfl_down(s,off); sq += __shfl_down(sq,off); }
  s = __shfl(s,0); sq = __shfl(sq,0);
  float mu = s*(1.f/128.f);
  float var = sq*(1.f/128.f) - mu*mu;
  float r = rsqrtf(var + 1e-5f);
  out[(size_t)tok*128+lane]    = f2bf((x0-mu)*r*w[lane]    + b[lane]);
  out[(size_t)tok*128+lane+64] = f2bf((x1-mu)*r*w[lane+64] + b[lane+64]);
}

// ---------------- weight convert + transpose -> bf16 Wt[N][K], all 4 layers ----------------
// per-layer region (196608 u16): [0)qkvg 768x128  [98304)wo 128x256  [131072)f1 256x128  [163840)f2 128x256
__global__ __launch_bounds__(256) void wconv_kernel(
    const float* __restrict__ wq, const float* __restrict__ wk,
    const float* __restrict__ wv, const float* __restrict__ wg,
    const float* __restrict__ wo, const float* __restrict__ f1,
    const float* __restrict__ f2, u16* __restrict__ Wt)
{
  int idx = blockIdx.x*256 + threadIdx.x;   // 0..786431
  int layer = idx / 196608;
  int r = idx - layer*196608;
  u16* W = Wt + (size_t)layer*196608;
  const float* wq_l = wq + (size_t)layer*16384;
  const float* wk_l = wk + (size_t)layer*16384;
  const float* wv_l = wv + (size_t)layer*32768;
  const float* wg_l = wg + (size_t)layer*32768;
  const float* wo_l = wo + (size_t)layer*32768;
  const float* f1_l = f1 + (size_t)layer*32768;
  const float* f2_l = f2 + (size_t)layer*32768;
  float v;
  if(r < 98304){
    int col = r>>7, h = r&127;
    if(col<128){ int n=col>>5, d=col&31; v = wq_l[(n*128+h)*32+d]; }
    else if(col<256){ int c=col-128, n=c>>5, d=c&31; v = wk_l[(n*128+h)*32+d]; }
    else if(col<512){ int c=col-256, n=c>>6, j=c&63; v = wv_l[(n*128+h)*64+j]; }
    else { int p=col-512; v = wg_l[h*256+p]; }
    W[r] = f2bf(v);
  } else if(r < 131072){
    int q = r-98304; int col=q>>8, k=q&255;
    W[r] = f2bf(wo_l[k*128+col]);
  } else if(r < 163840){
    int q = r-131072; int col=q>>7, h=q&127;
    W[r] = f2bf(f1_l[h*256+col]);
  } else {
    int q = r-163840; int col=q>>8, k=q&255;
    W[r] = f2bf(f2_l[k*128+col]);
  }
}

// ---------------- MFMA GEMM: out = A(bf16, M x K) @ Wt^T(bf16, stored [N][K]) ----------------
// block: 64 rows x 128 cols; 4 waves, each 32 rows x 64 cols (2x4 mfma tiles)
// MODE 0: qkvg N=768 -> xPos Q/K fp32 head-layout, V fp32 head-layout, G bf16
// MODE 1: wo   N=128 -> fo0 = acc + resid (fp32)
// MODE 2: ffn1 N=256 -> uo  = bf16(gelu(acc + bias))
// MODE 3: ffn2 N=128 -> fo0 = acc + bias + resid (fp32)
template<int K, int MODE>
__global__ __launch_bounds__(256) void mgemm_kernel(
    const u16* __restrict__ A, const u16* __restrict__ Wt,
    const float* __restrict__ bias, const float* __restrict__ resid,
    float* __restrict__ fo0, float* __restrict__ fo1,
    float* __restrict__ fo2, u16* __restrict__ uo)
{
  __shared__ u16 sA[64][136];
  __shared__ u16 sW[128][136];
  int t = threadIdx.x;
  int tok0 = blockIdx.x*64;
  int n0 = blockIdx.y*128;
  int lane = t&63, wid = t>>6;
  int r0 = (wid>>1)*32, c0 = (wid&1)*64;
  int mrow = lane&15, quad = lane>>4;

  f32x4 acc[2][4];
  #pragma unroll
  for(int rr=0;rr<2;rr++)
    #pragma unroll
    for(int cc=0;cc<4;cc++) acc[rr][cc] = (f32x4){0.f,0.f,0.f,0.f};

  #pragma unroll
  for(int kc=0; kc<K/128; kc++){
    if(kc) __syncthreads();
    for(int c=t; c<1024; c+=256){
      int row=c>>4, col8=(c&15)*8;
      *(uint4*)&sA[row][col8] = *(const uint4*)&A[(size_t)(tok0+row)*K + kc*128 + col8];
    }
    for(int c=t; c<2048; c+=256){
      int row=c>>4, col8=(c&15)*8;
      *(uint4*)&sW[row][col8] = *(const uint4*)&Wt[(size_t)(n0+row)*K + kc*128 + col8];
    }
    __syncthreads();
    #pragma unroll
    for(int ks=0; ks<4; ks++){
      int koff = ks*32 + quad*8;
      bf16x8 a0 = *(const bf16x8*)&sA[r0+mrow][koff];
      bf16x8 a1 = *(const bf16x8*)&sA[r0+16+mrow][koff];
      #pragma unroll
      for(int cc=0; cc<4; cc++){
        bf16x8 b = *(const bf16x8*)&sW[c0+cc*16+mrow][koff];
        acc[0][cc] = __builtin_amdgcn_mfma_f32_16x16x32_bf16(a0,b,acc[0][cc],0,0,0);
        acc[1][cc] = __builtin_amdgcn_mfma_f32_16x16x32_bf16(a1,b,acc[1][cc],0,0,0);
      }
    }
  }

  #pragma unroll
  for(int rr=0; rr<2; rr++){
    #pragma unroll
    for(int cc=0; cc<4; cc++){
      int colg = n0 + c0 + cc*16 + mrow;
      // per-column constants for xPos (MODE 0, Q/K range only)
      float log2bs=0.f, invf=0.f;
      if(MODE==0 && colg < 256){
        int i = (colg & 31) >> 1;
        log2bs = log2f(((float)i + 12.8f)*(1.f/44.8f));
        invf   = exp2f(-(float)i * (13.28771238f/16.f));  // 10000^(-i/16)
      }
      #pragma unroll
      for(int reg=0; reg<4; reg++){
        int rowg = tok0 + r0 + rr*16 + quad*4 + reg;
        float v = acc[rr][cc][reg];
        if(MODE==0){
          if(colg < 256){
            bool isK = colg >= 128;
            int qc = colg & 127;
            int n = qc>>5, d = qc&31;
            int l = rowg & 511, b = rowg >> 9;
            float partner = __shfl_xor(v, 1);
            float e = log2bs * (float)l * (1.f/512.f);
            float sc = exp2f(isK ? -e : e);
            float ang = (float)l * invf;
            float cs = cosf(ang)*sc, sn = sinf(ang)*sc;
            float o = (d&1) ? (v*cs + partner*sn) : (v*cs - partner*sn);
            float* O = isK ? fo1 : fo0;
            O[((size_t)(b*4+n)*512 + l)*32 + d] = o;
          } else if(colg < 512){
            int c = colg-256, n = c>>6, j = c&63;
            int l = rowg & 511, b = rowg >> 9;
            fo2[((size_t)(b*4+n)*512 + l)*64 + j] = v;
          } else {
            uo[(size_t)rowg*256 + (colg-512)] = f2bf(v);
          }
        } else if(MODE==1){
          fo0[(size_t)rowg*128 + colg] = v + resid[(size_t)rowg*128 + colg];
        } else if(MODE==2){
          uo[(size_t)rowg*256 + colg] = f2bf(gelu_f(v + bias[colg]));
        } else {
          fo0[(size_t)rowg*128 + colg] = v + bias[colg] + resid[(size_t)rowg*128 + colg];
        }
      }
    }
  }
}

// ---------------- retention: per (b,n) pair, quadratic, tiled 64x64, fp32 ----------------
__global__ __launch_bounds__(256) void retention_kernel(
    const float* __restrict__ Q, const float* __restrict__ K,
    const float* __restrict__ V, float* __restrict__ R, float4 log2g)
{
  int bn = blockIdx.x >> 3, lt = blockIdx.x & 7;
  int n = bn & 3;
  float lg2g = (n==0)?log2g.x:(n==1)?log2g.y:(n==2)?log2g.z:log2g.w;
  __shared__ float sQ[64][33];
  __shared__ float sK[64][33];
  __shared__ float sV[64][65];
  __shared__ float sS[64][65];
  int t = threadIdx.x;
  size_t qbase = ((size_t)bn*512 + lt*64)*32;
  for(int i=t;i<2048;i+=256) sQ[i>>5][i&31] = Q[qbase + i];
  __syncthreads();
  int lrow = t>>2, j0 = (t&3)*16;
  float qreg[32];
  #pragma unroll
  for(int d=0;d<32;d++) qreg[d] = sQ[lrow][d];
  float acc[16];
  #pragma unroll
  for(int i=0;i<16;i++) acc[i]=0.f;
  int lglob = lt*64 + lrow;
  int m0 = (t&3)*16;
  for(int mt=0; mt<=lt; mt++){
    __syncthreads();
    size_t kbase = ((size_t)bn*512 + mt*64)*32;
    size_t vbase = ((size_t)bn*512 + mt*64)*64;
    for(int i=t;i<2048;i+=256) sK[i>>5][i&31] = K[kbase + i];
    for(int i=t;i<4096;i+=256) sV[i>>6][i&63] = V[vbase + i];
    __syncthreads();
    float sv[16];
    #pragma unroll
    for(int mm=0;mm<16;mm++){
      int m = m0+mm;
      float a=0.f;
      #pragma unroll
      for(int d=0;d<32;d++) a += qreg[d]*sK[m][d];
      int diff = lglob - (mt*64 + m);
      float wgt = (diff>=0) ? exp2f(lg2g*(float)diff) : 0.f;
      sv[mm] = a*wgt;
    }
    #pragma unroll
    for(int mm=0;mm<16;mm++) sS[lrow][m0+mm]=sv[mm];
    __syncthreads();
    for(int m=0;m<64;m++){
      float sc = sS[lrow][m];
      const float* vr = &sV[m][j0];
      #pragma unroll
      for(int jj=0;jj<16;jj++) acc[jj] += sc*vr[jj];
    }
  }
  size_t rbase = ((size_t)bn*512 + lt*64 + lrow)*64 + j0;
  #pragma unroll
  for(int jj=0;jj<16;jj+=4){
    float4 v4 = make_float4(acc[jj],acc[jj+1],acc[jj+2],acc[jj+3]);
    *(float4*)(R + rbase + jj) = v4;
  }
}

// ---------------- groupnorm(4x64) + affine + silu(G bf16) gate -> gated bf16 ----------------
__global__ __launch_bounds__(256) void gatenorm_kernel(
    const float* __restrict__ R, const u16* __restrict__ G,
    const float* __restrict__ gnw, const float* __restrict__ gnb,
    u16* __restrict__ out)
{
  int wv = threadIdx.x>>6, lane = threadIdx.x&63;
  int tok = blockIdx.x*4 + wv;
  int bb = tok>>9, l = tok&511;
  int n = lane>>4, v0 = (lane&15)*4;
  const float* rp = R + ((size_t)(bb*4+n)*512 + l)*64 + v0;
  float4 y = *(const float4*)rp;
  float yy[4] = {y.x,y.y,y.z,y.w};
  float s = yy[0]+yy[1]+yy[2]+yy[3];
  float sq = yy[0]*yy[0]+yy[1]*yy[1]+yy[2]*yy[2]+yy[3]*yy[3];
  #pragma unroll
  for(int m=1;m<16;m<<=1){ s += __shfl_xor(s,m); sq += __shfl_xor(sq,m); }
  float mu = s*(1.f/64.f);
  float var = sq*(1.f/64.f) - mu*mu;
  float r = rsqrtf(var + 1e-5f);
  int vb = n*64 + v0;
  u16 o[4];
  #pragma unroll
  for(int i=0;i<4;i++){
    float gg = bf2f(G[(size_t)tok*256 + vb + i]);
    float gate = gg/(1.f+expf(-gg));
    o[i] = f2bf(gate * ((yy[i]-mu)*r*gnw[vb+i] + gnb[vb+i]));
  }
  ushort4 pk; pk.x=o[0]; pk.y=o[1]; pk.z=o[2]; pk.w=o[3];
  *(ushort4*)(out + (size_t)tok*256 + vb) = pk;
}

// ---------------- decoder: gelu(X@w1+b1)@w2+b2 -> softmax(20) ----------------
__global__ __launch_bounds__(64) void dec_kernel(
    const float* __restrict__ X,
    const float* __restrict__ w1, const float* __restrict__ b1,
    const float* __restrict__ w2, const float* __restrict__ b2,
    float* __restrict__ out)
{
  __shared__ float sX[64][129];
  int t = threadIdx.x;
  int tok0 = blockIdx.x*64;
  for(int i=t;i<8192;i+=64){ sX[i>>7][i&127] = X[(size_t)tok0*128 + i]; }
  __syncthreads();
  float h[64];
  #pragma unroll
  for(int j=0;j<64;j++) h[j]=b1[j];
  for(int k=0;k<128;k++){
    float xv = sX[t][k];
    const float* wr = w1 + k*64;
    #pragma unroll
    for(int j=0;j<64;j++) h[j] += xv*wr[j];
  }
  #pragma unroll
  for(int j=0;j<64;j++) h[j]=gelu_f(h[j]);
  float lg[20];
  #pragma unroll
  for(int o=0;o<20;o++) lg[o]=b2[o];
  #pragma unroll
  for(int j=0;j<64;j++){
    float hv = h[j];
    const float* wr = w2 + j*20;
    #pragma unroll
    for(int o=0;o<20;o++) lg[o] += hv*wr[o];
  }
  float mx = -1e30f;
  #pragma unroll
  for(int o=0;o<20;o++) mx = fmaxf(mx, lg[o]);
  float sum = 0.f;
  #pragma unroll
  for(int o=0;o<20;o++){ lg[o]=expf(lg[o]-mx); sum += lg[o]; }
  float inv = 1.f/sum;
  int tok = tok0 + t;
  #pragma unroll
  for(int o=0;o<20;o++) out[(size_t)tok*20 + o] = lg[o]*inv;
}

extern "C" void kernel_launch(void* const* d_in, const int* in_sizes, int n_in,
                              void* d_out, int out_size, void* d_ws, size_t ws_size,
                              hipStream_t stream) {
  (void)in_sizes; (void)n_in; (void)out_size; (void)ws_size;
  const float* x      = (const float*)d_in[0];
  const float* rem_w1 = (const float*)d_in[1];
  const float* rem_b1 = (const float*)d_in[2];
  const float* rem_w2 = (const float*)d_in[3];
  const float* rem_b2 = (const float*)d_in[4];
  const float* rem_w3 = (const float*)d_in[5];
  const float* rem_b3 = (const float*)d_in[6];
  const float* wq     = (const float*)d_in[7];
  const float* wk     = (const float*)d_in[8];
  const float* wv     = (const float*)d_in[9];
  const float* wg     = (const float*)d_in[10];
  const float* wo     = (const float*)d_in[11];
  const float* gn_w   = (const float*)d_in[12];
  const float* gn_b   = (const float*)d_in[13];
  const float* ln1_w  = (const float*)d_in[14];
  const float* ln1_b  = (const float*)d_in[15];
  const float* ln2_w  = (const float*)d_in[16];
  const float* ln2_b  = (const float*)d_in[17];
  const float* ffn_w1 = (const float*)d_in[18];
  const float* ffn_b1 = (const float*)d_in[19];
  const float* ffn_w2 = (const float*)d_in[20];
  const float* ffn_b2 = (const float*)d_in[21];
  const float* dec_w1 = (const float*)d_in[22];
  const float* dec_b1 = (const float*)d_in[23];
  const float* dec_w2 = (const float*)d_in[24];
  const float* dec_b2 = (const float*)d_in[25];
  float* outp = (float*)d_out;

  const size_t S128 = (size_t)BT*128;
  const size_t S256 = (size_t)BT*256;
  float* ws = (float*)d_ws;
  float* Xb = ws;                  // residual X        (S128)
  float* Qb = Xb + S128;           // Q fp32 head-layout(S128)
  float* Kb = Qb + S128;           // K fp32            (S128)
  float* Yr = Kb + S128;           // residual Y        (S128)
  float* Vb = Yr + S128;           // V fp32 head-layout(S256)
  float* Rb = Vb + S256;           // retention out     (S256)
  u16*  XnBf    = (u16*)(Rb + S256);   // LN out bf16   (S128 u16)
  u16*  GBf     = XnBf + S128;         // G bf16        (S256 u16)
  u16*  GatedBf = GBf + S256;          // gated / H     (S256 u16)
  u16*  WtBf    = GatedBf + S256;      // bf16 weights  (4*196608 u16)

  double lgA = log(1.0/32.0), lgB = log(1.0/512.0);
  float4 l2g;
  {
    double g0 = 1.0 - exp(lgA + 0.0*(lgB-lgA)/3.0);
    double g1 = 1.0 - exp(lgA + 1.0*(lgB-lgA)/3.0);
    double g2 = 1.0 - exp(lgA + 2.0*(lgB-lgA)/3.0);
    double g3 = 1.0 - exp(lgA + 3.0*(lgB-lgA)/3.0);
    l2g.x = (float)(log(g0)/log(2.0));
    l2g.y = (float)(log(g1)/log(2.0));
    l2g.z = (float)(log(g2)/log(2.0));
    l2g.w = (float)(log(g3)/log(2.0));
  }

  wconv_kernel<<<3072, 256, 0, stream>>>(wq, wk, wv, wg, wo, ffn_w1, ffn_w2, WtBf);
  embed_kernel<<<BT/32, 256, 0, stream>>>(x, rem_w1, rem_b1, rem_w2, rem_b2, rem_w3, rem_b3, Xb);

  for(int li=0; li<4; li++){
    u16* Wt_l = WtBf + (size_t)li*196608;
    const float* gnw_l = gn_w + (size_t)li*VDIM;
    const float* gnb_l = gn_b + (size_t)li*VDIM;
    const float* l1w = ln1_w + (size_t)li*HID, *l1b = ln1_b + (size_t)li*HID;
    const float* l2w = ln2_w + (size_t)li*HID, *l2b = ln2_b + (size_t)li*HID;
    const float* f1b = ffn_b1 + (size_t)li*FFND;
    const float* f2b = ffn_b2 + (size_t)li*HID;

    ln_kernel<<<BT/4, 256, 0, stream>>>(Xb, l1w, l1b, XnBf);
    mgemm_kernel<128,0><<<dim3(BT/64,6), 256, 0, stream>>>(
        XnBf, Wt_l, nullptr, nullptr, Qb, Kb, Vb, GBf);
    retention_kernel<<<256*8, 256, 0, stream>>>(Qb, Kb, Vb, Rb, l2g);
    gatenorm_kernel<<<BT/4, 256, 0, stream>>>(Rb, GBf, gnw_l, gnb_l, GatedBf);
    mgemm_kernel<256,1><<<dim3(BT/64,1), 256, 0, stream>>>(
        GatedBf, Wt_l+98304, nullptr, Xb, Yr, nullptr, nullptr, nullptr);
    ln_kernel<<<BT/4, 256, 0, stream>>>(Yr, l2w, l2b, XnBf);
    mgemm_kernel<128,2><<<dim3(BT/64,2), 256, 0, stream>>>(
        XnBf, Wt_l+131072, f1b, nullptr, nullptr, nullptr, nullptr, GatedBf);
    mgemm_kernel<256,3><<<dim3(BT/64,1), 256, 0, stream>>>(
        GatedBf, Wt_l+163840, f2b, Yr, Xb, nullptr, nullptr, nullptr);
  }

  dec_kernel<<<BT/64, 64, 0, stream>>>(Xb, dec_w1, dec_b1, dec_w2, dec_b2, outp);
}

// Round 3
// 979.556 us; speedup vs baseline: 8.5688x; 3.4082x over previous
//
#include <hip/hip_runtime.h>
#include <math.h>
#include <cmath>

#define SEQ   512
#define NBATCH 64
#define BT    32768      // 64*512 tokens
#define HID   128
#define NHEAD 4
#define HD    32
#define VHD   64
#define VDIM  256
#define FFND  256

typedef __attribute__((ext_vector_type(8))) short bf16x8;
typedef __attribute__((ext_vector_type(4))) float f32x4;
typedef unsigned short u16;

__device__ __forceinline__ float gelu_f(float x){ return 0.5f*x*(1.f+erff(x*0.70710678118f)); }

__device__ __forceinline__ u16 f2bf(float f){
  union{float f; unsigned u;} v; v.f = f;
  unsigned r = v.u + 0x7FFF + ((v.u>>16)&1);
  return (u16)(r>>16);
}
__device__ __forceinline__ float bf2f(u16 u){
  union{unsigned u; float f;} v; v.u = ((unsigned)u)<<16; return v.f;
}

// ---------------- embed: x(BT,5) -> gelu chain -> X(BT,128) ----------------
__global__ __launch_bounds__(256) void embed_kernel(
    const float* __restrict__ x,
    const float* __restrict__ w1, const float* __restrict__ b1,
    const float* __restrict__ w2, const float* __restrict__ b2,
    const float* __restrict__ w3, const float* __restrict__ b3,
    float* __restrict__ X)
{
  __shared__ float sw1[5*32], sw2[32*64], sw3[64*128];
  __shared__ float sb1[32], sb2[64], sb3[128];
  __shared__ float sx[32][6], sh1[32][33], sh2[32][65];
  int t = threadIdx.x;
  for(int i=t;i<160;i+=256)  sw1[i]=w1[i];
  for(int i=t;i<2048;i+=256) sw2[i]=w2[i];
  for(int i=t;i<8192;i+=256) sw3[i]=w3[i];
  if(t<32)  sb1[t]=b1[t];
  if(t<64)  sb2[t]=b2[t];
  if(t<128) sb3[t]=b3[t];
  int tok0 = blockIdx.x*32;
  for(int i=t;i<160;i+=256) sx[i/5][i%5] = x[tok0*5+i];
  __syncthreads();
  for(int task=t; task<1024; task+=256){
    int j=task&31, tok=task>>5;
    float a=sb1[j];
    #pragma unroll
    for(int i=0;i<5;i++) a += sx[tok][i]*sw1[i*32+j];
    sh1[tok][j]=gelu_f(a);
  }
  __syncthreads();
  for(int task=t; task<2048; task+=256){
    int j=task&63, tok=task>>6;
    float a=sb2[j];
    for(int i=0;i<32;i++) a += sh1[tok][i]*sw2[i*64+j];
    sh2[tok][j]=gelu_f(a);
  }
  __syncthreads();
  for(int task=t; task<4096; task+=256){
    int j=task&127, tok=task>>7;
    float a=sb3[j];
    for(int i=0;i<64;i++) a += sh2[tok][i]*sw3[i*128+j];
    X[(tok0+tok)*128 + j]=gelu_f(a);
  }
}

// ---------------- layernorm over 128, wave per token, bf16 out ----------------
__global__ __launch_bounds__(256) void ln_kernel(
    const float* __restrict__ in, const float* __restrict__ w,
    const float* __restrict__ b, u16* __restrict__ out)
{
  int wv = threadIdx.x>>6, lane = threadIdx.x&63;
  int tok = blockIdx.x*4 + wv;
  const float* row = in + (size_t)tok*128;
  float x0 = row[lane], x1 = row[lane+64];
  float s = x0+x1, sq = x0*x0+x1*x1;
  #pragma unroll
  for(int off=32; off; off>>=1){ s += __shfl_down(s,off); sq += __shfl_down(sq,off); }
  s = __shfl(s,0); sq = __shfl(sq,0);
  float mu = s*(1.f/128.f);
  float var = sq*(1.f/128.f) - mu*mu;
  float r = rsqrtf(var + 1e-5f);
  out[(size_t)tok*128+lane]    = f2bf((x0-mu)*r*w[lane]    + b[lane]);
  out[(size_t)tok*128+lane+64] = f2bf((x1-mu)*r*w[lane+64] + b[lane+64]);
}

// ---------------- weight convert + transpose -> bf16 Wt[N][K], all 4 layers ----------------
// per-layer region (196608 u16): [0)qkvg 768x128  [98304)wo 128x256  [131072)f1 256x128  [163840)f2 128x256
__global__ __launch_bounds__(256) void wconv_kernel(
    const float* __restrict__ wq, const float* __restrict__ wk,
    const float* __restrict__ wv, const float* __restrict__ wg,
    const float* __restrict__ wo, const float* __restrict__ f1,
    const float* __restrict__ f2, u16* __restrict__ Wt)
{
  int idx = blockIdx.x*256 + threadIdx.x;   // 0..786431
  int layer = idx / 196608;
  int r = idx - layer*196608;
  u16* W = Wt + (size_t)layer*196608;
  const float* wq_l = wq + (size_t)layer*16384;
  const float* wk_l = wk + (size_t)layer*16384;
  const float* wv_l = wv + (size_t)layer*32768;
  const float* wg_l = wg + (size_t)layer*32768;
  const float* wo_l = wo + (size_t)layer*32768;
  const float* f1_l = f1 + (size_t)layer*32768;
  const float* f2_l = f2 + (size_t)layer*32768;
  float v;
  if(r < 98304){
    int col = r>>7, h = r&127;
    if(col<128){ int n=col>>5, d=col&31; v = wq_l[(n*128+h)*32+d]; }
    else if(col<256){ int c=col-128, n=c>>5, d=c&31; v = wk_l[(n*128+h)*32+d]; }
    else if(col<512){ int c=col-256, n=c>>6, j=c&63; v = wv_l[(n*128+h)*64+j]; }
    else { int p=col-512; v = wg_l[h*256+p]; }
    W[r] = f2bf(v);
  } else if(r < 131072){
    int q = r-98304; int col=q>>8, k=q&255;
    W[r] = f2bf(wo_l[k*128+col]);
  } else if(r < 163840){
    int q = r-131072; int col=q>>7, h=q&127;
    W[r] = f2bf(f1_l[h*256+col]);
  } else {
    int q = r-163840; int col=q>>8, k=q&255;
    W[r] = f2bf(f2_l[k*128+col]);
  }
}

// ---------------- MFMA GEMM: out = A(bf16, M x K) @ Wt^T(bf16, stored [N][K]) ----------------
// block: 64 rows x 128 cols; 4 waves, each 32 rows x 64 cols (2x4 mfma tiles)
// MODE 0: qkvg N=768 -> xPos Q/K bf16 head-layout, V bf16 transposed [bn][j][l], G bf16
// MODE 1: wo   N=128 -> fo0 = acc + resid (fp32)
// MODE 2: ffn1 N=256 -> uo3 = bf16(gelu(acc + bias))
// MODE 3: ffn2 N=128 -> fo0 = acc + bias + resid (fp32)
template<int K, int MODE>
__global__ __launch_bounds__(256) void mgemm_kernel(
    const u16* __restrict__ A, const u16* __restrict__ Wt,
    const float* __restrict__ bias, const float* __restrict__ resid,
    float* __restrict__ fo0,
    u16* __restrict__ uo0, u16* __restrict__ uo1,
    u16* __restrict__ uo2, u16* __restrict__ uo3)
{
  __shared__ u16 sA[64][136];
  __shared__ u16 sW[128][136];
  int t = threadIdx.x;
  int tok0 = blockIdx.x*64;
  int n0 = blockIdx.y*128;
  int lane = t&63, wid = t>>6;
  int r0 = (wid>>1)*32, c0 = (wid&1)*64;
  int mrow = lane&15, quad = lane>>4;

  f32x4 acc[2][4];
  #pragma unroll
  for(int rr=0;rr<2;rr++)
    #pragma unroll
    for(int cc=0;cc<4;cc++) acc[rr][cc] = (f32x4){0.f,0.f,0.f,0.f};

  #pragma unroll
  for(int kc=0; kc<K/128; kc++){
    if(kc) __syncthreads();
    for(int c=t; c<1024; c+=256){
      int row=c>>4, col8=(c&15)*8;
      *(uint4*)&sA[row][col8] = *(const uint4*)&A[(size_t)(tok0+row)*K + kc*128 + col8];
    }
    for(int c=t; c<2048; c+=256){
      int row=c>>4, col8=(c&15)*8;
      *(uint4*)&sW[row][col8] = *(const uint4*)&Wt[(size_t)(n0+row)*K + kc*128 + col8];
    }
    __syncthreads();
    #pragma unroll
    for(int ks=0; ks<4; ks++){
      int koff = ks*32 + quad*8;
      bf16x8 a0 = *(const bf16x8*)&sA[r0+mrow][koff];
      bf16x8 a1 = *(const bf16x8*)&sA[r0+16+mrow][koff];
      #pragma unroll
      for(int cc=0; cc<4; cc++){
        bf16x8 b = *(const bf16x8*)&sW[c0+cc*16+mrow][koff];
        acc[0][cc] = __builtin_amdgcn_mfma_f32_16x16x32_bf16(a0,b,acc[0][cc],0,0,0);
        acc[1][cc] = __builtin_amdgcn_mfma_f32_16x16x32_bf16(a1,b,acc[1][cc],0,0,0);
      }
    }
  }

  #pragma unroll
  for(int rr=0; rr<2; rr++){
    #pragma unroll
    for(int cc=0; cc<4; cc++){
      int colg = n0 + c0 + cc*16 + mrow;
      float log2bs=0.f, invf=0.f;
      if(MODE==0 && colg < 256){
        int i = (colg & 31) >> 1;
        log2bs = log2f(((float)i + 12.8f)*(1.f/44.8f));
        invf   = exp2f(-(float)i * (13.28771238f/16.f));  // 10000^(-i/16)
      }
      #pragma unroll
      for(int reg=0; reg<4; reg++){
        int rowg = tok0 + r0 + rr*16 + quad*4 + reg;
        float v = acc[rr][cc][reg];
        if(MODE==0){
          if(colg < 256){
            bool isK = colg >= 128;
            int qc = colg & 127;
            int n = qc>>5, d = qc&31;
            int l = rowg & 511, b = rowg >> 9;
            float partner = __shfl_xor(v, 1);
            float e = log2bs * (float)l * (1.f/512.f);
            float sc = exp2f(isK ? -e : e);
            float ang = (float)l * invf;
            float cs = cosf(ang)*sc, sn = sinf(ang)*sc;
            float o = (d&1) ? (v*cs + partner*sn) : (v*cs - partner*sn);
            u16* O = isK ? uo1 : uo0;
            O[((size_t)(b*4+n)*512 + l)*32 + d] = f2bf(o);
          } else if(colg < 512){
            int c = colg-256, n = c>>6, j = c&63;
            int l = rowg & 511, b = rowg >> 9;
            uo2[((size_t)(b*4+n)*64 + j)*512 + l] = f2bf(v);   // V transposed
          } else {
            uo3[(size_t)rowg*256 + (colg-512)] = f2bf(v);
          }
        } else if(MODE==1){
          fo0[(size_t)rowg*128 + colg] = v + resid[(size_t)rowg*128 + colg];
        } else if(MODE==2){
          uo3[(size_t)rowg*256 + colg] = f2bf(gelu_f(v + bias[colg]));
        } else {
          fo0[(size_t)rowg*128 + colg] = v + bias[colg] + resid[(size_t)rowg*128 + colg];
        }
      }
    }
  }
}

// ---------------- retention via MFMA: block = (bn, 64-row Q tile), 4 waves ----------------
// Q,K bf16 [bn][l][32]; Vt bf16 [bn][j][512]; R fp32 [bn][l][64]
__global__ __launch_bounds__(256) void retmfma_kernel(
    const u16* __restrict__ Q, const u16* __restrict__ K,
    const u16* __restrict__ Vt, float* __restrict__ R, float4 log2g)
{
  int bn = blockIdx.x >> 3, lt = blockIdx.x & 7;
  int n = bn & 3;
  float lg2g = (n==0)?log2g.x:(n==1)?log2g.y:(n==2)?log2g.z:log2g.w;
  __shared__ u16 sQ[64][40];
  __shared__ u16 sK[64][40];
  __shared__ u16 sVt[64][72];
  __shared__ u16 sS[64][72];
  int t = threadIdx.x, lane = t&63, wid = t>>6;
  int mrow = lane&15, quad = lane>>4;
  int r0 = wid*16;
  {
    int row = t>>2, c8 = (t&3)*8;
    *(uint4*)&sQ[row][c8] = *(const uint4*)&Q[((size_t)bn*512 + lt*64 + row)*32 + c8];
  }
  f32x4 oacc[4];
  #pragma unroll
  for(int cc=0;cc<4;cc++) oacc[cc] = (f32x4){0.f,0.f,0.f,0.f};
  // gamma^reg for reg=0..3
  float gp1 = exp2f(lg2g), gp2 = gp1*gp1, gp3 = gp2*gp1;
  float gpow[4] = {1.f, gp1, gp2, gp3};
  __syncthreads();
  bf16x8 qa = *(const bf16x8*)&sQ[r0+mrow][quad*8];
  int rowl0 = lt*64 + r0 + quad*4;

  for(int mt=0; mt<=lt; mt++){
    if(mt) __syncthreads();
    {
      int row = t>>2, c8 = (t&3)*8;
      *(uint4*)&sK[row][c8] = *(const uint4*)&K[((size_t)bn*512 + mt*64 + row)*32 + c8];
      int vrow = t>>3, vc8 = (t&7)*8;
      *(uint4*)&sVt[vrow][vc8]    = *(const uint4*)&Vt[((size_t)bn*64 + vrow)*512    + mt*64 + vc8];
      *(uint4*)&sVt[vrow+32][vc8] = *(const uint4*)&Vt[((size_t)bn*64 + vrow+32)*512 + mt*64 + vc8];
    }
    __syncthreads();
    // S = Q K^T (wave strip: 16 rows x 64 cols), K-dim 32 = one mfma step
    f32x4 sacc[4];
    #pragma unroll
    for(int cc=0;cc<4;cc++){
      bf16x8 b = *(const bf16x8*)&sK[cc*16+mrow][quad*8];
      sacc[cc] = __builtin_amdgcn_mfma_f32_16x16x32_bf16(qa,b,(f32x4){0.f,0.f,0.f,0.f},0,0,0);
    }
    // decay (exact in fp32) + store bf16 to sS in A-operand-friendly layout
    #pragma unroll
    for(int cc=0;cc<4;cc++){
      int colm = mt*64 + cc*16 + mrow;
      int d0 = rowl0 - colm;
      float w0 = exp2f(lg2g*(float)d0);
      #pragma unroll
      for(int reg=0;reg<4;reg++){
        float w = (d0+reg>=0) ? w0*gpow[reg] : 0.f;
        sS[r0+quad*4+reg][cc*16+mrow] = f2bf(sacc[cc][reg]*w);
      }
    }
    __syncthreads();
    // O += S V  (S strip 16x64, V tile 64x64)
    #pragma unroll
    for(int ks=0;ks<2;ks++){
      bf16x8 a = *(const bf16x8*)&sS[r0+mrow][ks*32+quad*8];
      #pragma unroll
      for(int cc=0;cc<4;cc++){
        bf16x8 b = *(const bf16x8*)&sVt[cc*16+mrow][ks*32+quad*8];
        oacc[cc] = __builtin_amdgcn_mfma_f32_16x16x32_bf16(a,b,oacc[cc],0,0,0);
      }
    }
  }
  #pragma unroll
  for(int cc=0;cc<4;cc++){
    #pragma unroll
    for(int reg=0;reg<4;reg++){
      int l = rowl0 - lt*64 + reg + lt*64; // = rowl0+reg
      R[((size_t)bn*512 + (rowl0+reg))*64 + cc*16 + mrow] = oacc[cc][reg];
    }
  }
}

// ---------------- groupnorm(4x64) + affine + silu(G bf16) gate -> gated bf16 ----------------
__global__ __launch_bounds__(256) void gatenorm_kernel(
    const float* __restrict__ R, const u16* __restrict__ G,
    const float* __restrict__ gnw, const float* __restrict__ gnb,
    u16* __restrict__ out)
{
  int wv = threadIdx.x>>6, lane = threadIdx.x&63;
  int tok = blockIdx.x*4 + wv;
  int bb = tok>>9, l = tok&511;
  int n = lane>>4, v0 = (lane&15)*4;
  const float* rp = R + ((size_t)(bb*4+n)*512 + l)*64 + v0;
  float4 y = *(const float4*)rp;
  float yy[4] = {y.x,y.y,y.z,y.w};
  float s = yy[0]+yy[1]+yy[2]+yy[3];
  float sq = yy[0]*yy[0]+yy[1]*yy[1]+yy[2]*yy[2]+yy[3]*yy[3];
  #pragma unroll
  for(int m=1;m<16;m<<=1){ s += __shfl_xor(s,m); sq += __shfl_xor(sq,m); }
  float mu = s*(1.f/64.f);
  float var = sq*(1.f/64.f) - mu*mu;
  float r = rsqrtf(var + 1e-5f);
  int vb = n*64 + v0;
  u16 o[4];
  #pragma unroll
  for(int i=0;i<4;i++){
    float gg = bf2f(G[(size_t)tok*256 + vb + i]);
    float gate = gg/(1.f+expf(-gg));
    o[i] = f2bf(gate * ((yy[i]-mu)*r*gnw[vb+i] + gnb[vb+i]));
  }
  ushort4 pk; pk.x=o[0]; pk.y=o[1]; pk.z=o[2]; pk.w=o[3];
  *(ushort4*)(out + (size_t)tok*256 + vb) = pk;
}

// ---------------- decoder: gelu(X@w1+b1)@w2+b2 -> softmax(20) ----------------
__global__ __launch_bounds__(64) void dec_kernel(
    const float* __restrict__ X,
    const float* __restrict__ w1, const float* __restrict__ b1,
    const float* __restrict__ w2, const float* __restrict__ b2,
    float* __restrict__ out)
{
  __shared__ float sX[64][129];
  int t = threadIdx.x;
  int tok0 = blockIdx.x*64;
  for(int i=t;i<8192;i+=64){ sX[i>>7][i&127] = X[(size_t)tok0*128 + i]; }
  __syncthreads();
  float h[64];
  #pragma unroll
  for(int j=0;j<64;j++) h[j]=b1[j];
  for(int k=0;k<128;k++){
    float xv = sX[t][k];
    const float* wr = w1 + k*64;
    #pragma unroll
    for(int j=0;j<64;j++) h[j] += xv*wr[j];
  }
  #pragma unroll
  for(int j=0;j<64;j++) h[j]=gelu_f(h[j]);
  float lg[20];
  #pragma unroll
  for(int o=0;o<20;o++) lg[o]=b2[o];
  #pragma unroll
  for(int j=0;j<64;j++){
    float hv = h[j];
    const float* wr = w2 + j*20;
    #pragma unroll
    for(int o=0;o<20;o++) lg[o] += hv*wr[o];
  }
  float mx = -1e30f;
  #pragma unroll
  for(int o=0;o<20;o++) mx = fmaxf(mx, lg[o]);
  float sum = 0.f;
  #pragma unroll
  for(int o=0;o<20;o++){ lg[o]=expf(lg[o]-mx); sum += lg[o]; }
  float inv = 1.f/sum;
  int tok = tok0 + t;
  #pragma unroll
  for(int o=0;o<20;o++) out[(size_t)tok*20 + o] = lg[o]*inv;
}

extern "C" void kernel_launch(void* const* d_in, const int* in_sizes, int n_in,
                              void* d_out, int out_size, void* d_ws, size_t ws_size,
                              hipStream_t stream) {
  (void)in_sizes; (void)n_in; (void)out_size; (void)ws_size;
  const float* x      = (const float*)d_in[0];
  const float* rem_w1 = (const float*)d_in[1];
  const float* rem_b1 = (const float*)d_in[2];
  const float* rem_w2 = (const float*)d_in[3];
  const float* rem_b2 = (const float*)d_in[4];
  const float* rem_w3 = (const float*)d_in[5];
  const float* rem_b3 = (const float*)d_in[6];
  const float* wq     = (const float*)d_in[7];
  const float* wk     = (const float*)d_in[8];
  const float* wv     = (const float*)d_in[9];
  const float* wg     = (const float*)d_in[10];
  const float* wo     = (const float*)d_in[11];
  const float* gn_w   = (const float*)d_in[12];
  const float* gn_b   = (const float*)d_in[13];
  const float* ln1_w  = (const float*)d_in[14];
  const float* ln1_b  = (const float*)d_in[15];
  const float* ln2_w  = (const float*)d_in[16];
  const float* ln2_b  = (const float*)d_in[17];
  const float* ffn_w1 = (const float*)d_in[18];
  const float* ffn_b1 = (const float*)d_in[19];
  const float* ffn_w2 = (const float*)d_in[20];
  const float* ffn_b2 = (const float*)d_in[21];
  const float* dec_w1 = (const float*)d_in[22];
  const float* dec_b1 = (const float*)d_in[23];
  const float* dec_w2 = (const float*)d_in[24];
  const float* dec_b2 = (const float*)d_in[25];
  float* outp = (float*)d_out;

  const size_t S128 = (size_t)BT*128;
  const size_t S256 = (size_t)BT*256;
  float* ws = (float*)d_ws;
  float* Xb = ws;                  // residual X        (S128 f32)
  float* Yr = Xb + S128;           // residual Y        (S128 f32)
  float* Rb = Yr + S128;           // retention out     (S256 f32)
  u16*  Qb16    = (u16*)(Rb + S256);   // Q bf16 head-layout (BT*32)
  u16*  Kb16    = Qb16 + (size_t)BT*32;
  u16*  Vt16    = Kb16 + (size_t)BT*32;  // V bf16 transposed [bn][j][l] (BT*64)
  u16*  XnBf    = Vt16 + (size_t)BT*64;  // LN out bf16   (S128)
  u16*  GBf     = XnBf + S128;           // G bf16        (S256)
  u16*  GatedBf = GBf + S256;            // gated / H     (S256)
  u16*  WtBf    = GatedBf + S256;        // bf16 weights  (4*196608)

  double lgA = log(1.0/32.0), lgB = log(1.0/512.0);
  float4 l2g;
  {
    double g0 = 1.0 - exp(lgA + 0.0*(lgB-lgA)/3.0);
    double g1 = 1.0 - exp(lgA + 1.0*(lgB-lgA)/3.0);
    double g2 = 1.0 - exp(lgA + 2.0*(lgB-lgA)/3.0);
    double g3 = 1.0 - exp(lgA + 3.0*(lgB-lgA)/3.0);
    l2g.x = (float)(log(g0)/log(2.0));
    l2g.y = (float)(log(g1)/log(2.0));
    l2g.z = (float)(log(g2)/log(2.0));
    l2g.w = (float)(log(g3)/log(2.0));
  }

  wconv_kernel<<<3072, 256, 0, stream>>>(wq, wk, wv, wg, wo, ffn_w1, ffn_w2, WtBf);
  embed_kernel<<<BT/32, 256, 0, stream>>>(x, rem_w1, rem_b1, rem_w2, rem_b2, rem_w3, rem_b3, Xb);

  for(int li=0; li<4; li++){
    u16* Wt_l = WtBf + (size_t)li*196608;
    const float* gnw_l = gn_w + (size_t)li*VDIM;
    const float* gnb_l = gn_b + (size_t)li*VDIM;
    const float* l1w = ln1_w + (size_t)li*HID, *l1b = ln1_b + (size_t)li*HID;
    const float* l2w = ln2_w + (size_t)li*HID, *l2b = ln2_b + (size_t)li*HID;
    const float* f1b = ffn_b1 + (size_t)li*FFND;
    const float* f2b = ffn_b2 + (size_t)li*HID;

    ln_kernel<<<BT/4, 256, 0, stream>>>(Xb, l1w, l1b, XnBf);
    mgemm_kernel<128,0><<<dim3(BT/64,6), 256, 0, stream>>>(
        XnBf, Wt_l, nullptr, nullptr, nullptr, Qb16, Kb16, Vt16, GBf);
    retmfma_kernel<<<256*8, 256, 0, stream>>>(Qb16, Kb16, Vt16, Rb, l2g);
    gatenorm_kernel<<<BT/4, 256, 0, stream>>>(Rb, GBf, gnw_l, gnb_l, GatedBf);
    mgemm_kernel<256,1><<<dim3(BT/64,1), 256, 0, stream>>>(
        GatedBf, Wt_l+98304, nullptr, Xb, Yr, nullptr, nullptr, nullptr, nullptr);
    ln_kernel<<<BT/4, 256, 0, stream>>>(Yr, l2w, l2b, XnBf);
    mgemm_kernel<128,2><<<dim3(BT/64,2), 256, 0, stream>>>(
        XnBf, Wt_l+131072, f1b, nullptr, nullptr, nullptr, nullptr, nullptr, GatedBf);
    mgemm_kernel<256,3><<<dim3(BT/64,1), 256, 0, stream>>>(
        GatedBf, Wt_l+163840, f2b, Yr, Xb, nullptr, nullptr, nullptr, nullptr);
  }

  dec_kernel<<<BT/64, 64, 0, stream>>>(Xb, dec_w1, dec_b1, dec_w2, dec_b2, outp);
}

// Round 4
// 720.875 us; speedup vs baseline: 11.6436x; 1.3588x over previous
//
#include <hip/hip_runtime.h>
#include <math.h>
#include <cmath>

#define SEQ   512
#define NBATCH 64
#define BT    32768      // 64*512 tokens
#define HID   128
#define NHEAD 4
#define HD    32
#define VHD   64
#define VDIM  256
#define FFND  256

typedef __attribute__((ext_vector_type(8))) short bf16x8;
typedef __attribute__((ext_vector_type(4))) float f32x4;
typedef unsigned short u16;

__device__ __forceinline__ float gelu_f(float x){ return 0.5f*x*(1.f+erff(x*0.70710678118f)); }

__device__ __forceinline__ u16 f2bf(float f){
  union{float f; unsigned u;} v; v.f = f;
  unsigned r = v.u + 0x7FFF + ((v.u>>16)&1);
  return (u16)(r>>16);
}
__device__ __forceinline__ float bf2f(u16 u){
  union{unsigned u; float f;} v; v.u = ((unsigned)u)<<16; return v.f;
}

// ---------------- embed: x(BT,5) -> gelu chain -> X(BT,128) ----------------
__global__ __launch_bounds__(256) void embed_kernel(
    const float* __restrict__ x,
    const float* __restrict__ w1, const float* __restrict__ b1,
    const float* __restrict__ w2, const float* __restrict__ b2,
    const float* __restrict__ w3, const float* __restrict__ b3,
    float* __restrict__ X)
{
  __shared__ float sw1[5*32], sw2[32*64], sw3[64*128];
  __shared__ float sb1[32], sb2[64], sb3[128];
  __shared__ float sx[32][6], sh1[32][33], sh2[32][65];
  int t = threadIdx.x;
  for(int i=t;i<160;i+=256)  sw1[i]=w1[i];
  for(int i=t;i<2048;i+=256) sw2[i]=w2[i];
  for(int i=t;i<8192;i+=256) sw3[i]=w3[i];
  if(t<32)  sb1[t]=b1[t];
  if(t<64)  sb2[t]=b2[t];
  if(t<128) sb3[t]=b3[t];
  int tok0 = blockIdx.x*32;
  for(int i=t;i<160;i+=256) sx[i/5][i%5] = x[tok0*5+i];
  __syncthreads();
  for(int task=t; task<1024; task+=256){
    int j=task&31, tok=task>>5;
    float a=sb1[j];
    #pragma unroll
    for(int i=0;i<5;i++) a += sx[tok][i]*sw1[i*32+j];
    sh1[tok][j]=gelu_f(a);
  }
  __syncthreads();
  for(int task=t; task<2048; task+=256){
    int j=task&63, tok=task>>6;
    float a=sb2[j];
    for(int i=0;i<32;i++) a += sh1[tok][i]*sw2[i*64+j];
    sh2[tok][j]=gelu_f(a);
  }
  __syncthreads();
  for(int task=t; task<4096; task+=256){
    int j=task&127, tok=task>>7;
    float a=sb3[j];
    for(int i=0;i<64;i++) a += sh2[tok][i]*sw3[i*128+j];
    X[(tok0+tok)*128 + j]=gelu_f(a);
  }
}

// ---------------- layernorm over 128, wave per token, bf16 out ----------------
__global__ __launch_bounds__(256) void ln_kernel(
    const float* __restrict__ in, const float* __restrict__ w,
    const float* __restrict__ b, u16* __restrict__ out)
{
  int wv = threadIdx.x>>6, lane = threadIdx.x&63;
  int tok = blockIdx.x*4 + wv;
  const float* row = in + (size_t)tok*128;
  float x0 = row[lane], x1 = row[lane+64];
  float s = x0+x1, sq = x0*x0+x1*x1;
  #pragma unroll
  for(int off=32; off; off>>=1){ s += __shfl_down(s,off); sq += __shfl_down(sq,off); }
  s = __shfl(s,0); sq = __shfl(sq,0);
  float mu = s*(1.f/128.f);
  float var = sq*(1.f/128.f) - mu*mu;
  float r = rsqrtf(var + 1e-5f);
  out[(size_t)tok*128+lane]    = f2bf((x0-mu)*r*w[lane]    + b[lane]);
  out[(size_t)tok*128+lane+64] = f2bf((x1-mu)*r*w[lane+64] + b[lane+64]);
}

// ---------------- weight convert + transpose -> bf16 Wt[N][K], all 4 layers ----------------
// per-layer region (196608 u16): [0)qkvg 768x128  [98304)wo 128x256  [131072)f1 256x128  [163840)f2 128x256
__global__ __launch_bounds__(256) void wconv_kernel(
    const float* __restrict__ wq, const float* __restrict__ wk,
    const float* __restrict__ wv, const float* __restrict__ wg,
    const float* __restrict__ wo, const float* __restrict__ f1,
    const float* __restrict__ f2, u16* __restrict__ Wt)
{
  int idx = blockIdx.x*256 + threadIdx.x;   // 0..786431
  int layer = idx / 196608;
  int r = idx - layer*196608;
  u16* W = Wt + (size_t)layer*196608;
  const float* wq_l = wq + (size_t)layer*16384;
  const float* wk_l = wk + (size_t)layer*16384;
  const float* wv_l = wv + (size_t)layer*32768;
  const float* wg_l = wg + (size_t)layer*32768;
  const float* wo_l = wo + (size_t)layer*32768;
  const float* f1_l = f1 + (size_t)layer*32768;
  const float* f2_l = f2 + (size_t)layer*32768;
  float v;
  if(r < 98304){
    int col = r>>7, h = r&127;
    if(col<128){ int n=col>>5, d=col&31; v = wq_l[(n*128+h)*32+d]; }
    else if(col<256){ int c=col-128, n=c>>5, d=c&31; v = wk_l[(n*128+h)*32+d]; }
    else if(col<512){ int c=col-256, n=c>>6, j=c&63; v = wv_l[(n*128+h)*64+j]; }
    else { int p=col-512; v = wg_l[h*256+p]; }
    W[r] = f2bf(v);
  } else if(r < 131072){
    int q = r-98304; int col=q>>8, k=q&255;
    W[r] = f2bf(wo_l[k*128+col]);
  } else if(r < 163840){
    int q = r-131072; int col=q>>7, h=q&127;
    W[r] = f2bf(f1_l[h*256+col]);
  } else {
    int q = r-163840; int col=q>>8, k=q&255;
    W[r] = f2bf(f2_l[k*128+col]);
  }
}

// ---------------- qkvg: block = 64 tokens, y-half x 3 chunks of 128 cols ----------------
// A staged once; all outputs LDS-staged -> full-line uint4 stores.
// Q,K bf16 [bn][l][32]; Vt bf16 [bn][j][512]; G bf16 [tok][256]
__global__ __launch_bounds__(256) void qkvg_kernel(
    const u16* __restrict__ A, const u16* __restrict__ Wt,
    u16* __restrict__ Q, u16* __restrict__ K,
    u16* __restrict__ Vt, u16* __restrict__ G)
{
  __shared__ u16 sA[64][136];
  __shared__ u16 sW[128][136];
  u16* stg = &sW[0][0];
  int t = threadIdx.x, lane = t&63, wid = t>>6;
  int mrow = lane&15, quad = lane>>4;
  int r0 = (wid>>1)*32, c0 = (wid&1)*64;
  int tok0 = blockIdx.x*64;
  int b = tok0>>9, l0 = tok0&511;   // all 64 tokens share b

  for(int c=t;c<1024;c+=256){ int row=c>>4, col8=(c&15)*8;
    *(uint4*)&sA[row][col8] = *(const uint4*)&A[(size_t)(tok0+row)*128 + col8]; }

  for(int ch=0; ch<3; ch++){
    int nc = blockIdx.y*3 + ch;   // 0..5
    int n0 = nc*128;
    __syncthreads();              // staging reads of prev iter done; sA ready gate below
    for(int c=t;c<2048;c+=256){ int row=c>>4, col8=(c&15)*8;
      *(uint4*)&sW[row][col8] = *(const uint4*)&Wt[(size_t)(n0+row)*128 + col8]; }
    __syncthreads();

    f32x4 acc[2][4];
    #pragma unroll
    for(int rr=0;rr<2;rr++)
      #pragma unroll
      for(int cc=0;cc<4;cc++) acc[rr][cc] = (f32x4){0.f,0.f,0.f,0.f};
    #pragma unroll
    for(int ks=0; ks<4; ks++){
      int koff = ks*32 + quad*8;
      bf16x8 a0 = *(const bf16x8*)&sA[r0+mrow][koff];
      bf16x8 a1 = *(const bf16x8*)&sA[r0+16+mrow][koff];
      #pragma unroll
      for(int cc=0; cc<4; cc++){
        bf16x8 bb = *(const bf16x8*)&sW[c0+cc*16+mrow][koff];
        acc[0][cc] = __builtin_amdgcn_mfma_f32_16x16x32_bf16(a0,bb,acc[0][cc],0,0,0);
        acc[1][cc] = __builtin_amdgcn_mfma_f32_16x16x32_bf16(a1,bb,acc[1][cc],0,0,0);
      }
    }
    __syncthreads();   // done reading sW -> reuse as staging

    if(nc < 2){
      // ---- Q or K with xPos; stage [row][136] then 64B-per-(n,l) coalesced write
      bool isK = (nc==1);
      #pragma unroll
      for(int cc=0;cc<4;cc++){
        int colc = c0 + cc*16 + mrow;   // 0..127
        int i = (colc&31)>>1;
        float log2bs = log2f(((float)i + 12.8f)*(1.f/44.8f));
        float invf   = exp2f(-(float)i * (13.28771238f/16.f));  // 10000^(-i/16)
        #pragma unroll
        for(int rr=0;rr<2;rr++){
          #pragma unroll
          for(int reg=0;reg<4;reg++){
            int rowl = r0 + rr*16 + quad*4 + reg;
            int l = l0 + rowl;
            float v = acc[rr][cc][reg];
            float partner = __shfl_xor(v, 1);
            float e  = log2bs * (float)l * (1.f/512.f);
            float sc = exp2f(isK ? -e : e);
            float ang = (float)l * invf;
            float cs = cosf(ang)*sc, sn = sinf(ang)*sc;
            float o = (colc&1) ? (v*cs + partner*sn) : (v*cs - partner*sn);
            stg[rowl*136 + colc] = f2bf(o);
          }
        }
      }
      __syncthreads();
      u16* O = isK ? K : Q;
      for(int th=t; th<1024; th+=256){
        int row=th>>4, n=(th>>2)&3, seg=th&3;
        *(uint4*)&O[(((size_t)(b*4+n)*512) + (l0+row))*32 + seg*8]
          = *(const uint4*)&stg[row*136 + n*32 + seg*8];
      }
    } else if(nc < 4){
      // ---- V: stage transposed [jj][72] then 128B-per-j coalesced write
      #pragma unroll
      for(int cc=0;cc<4;cc++){
        int colc = c0 + cc*16 + mrow;
        #pragma unroll
        for(int rr=0;rr<2;rr++){
          #pragma unroll
          for(int reg=0;reg<4;reg++){
            int rowl = r0 + rr*16 + quad*4 + reg;
            stg[colc*72 + rowl] = f2bf(acc[rr][cc][reg]);
          }
        }
      }
      __syncthreads();
      int jbase = (nc-2)*128;
      for(int th=t; th<1024; th+=256){
        int row=th>>3, seg=th&7;
        int jg = jbase + row; int n = jg>>6, j = jg&63;
        *(uint4*)&Vt[(((size_t)(b*4+n)*64) + j)*512 + l0 + seg*8]
          = *(const uint4*)&stg[row*72 + seg*8];
      }
    } else {
      // ---- G: stage [row][136] then 256B-per-token coalesced write
      #pragma unroll
      for(int cc=0;cc<4;cc++){
        int colc = c0 + cc*16 + mrow;
        #pragma unroll
        for(int rr=0;rr<2;rr++){
          #pragma unroll
          for(int reg=0;reg<4;reg++){
            int rowl = r0 + rr*16 + quad*4 + reg;
            stg[rowl*136 + colc] = f2bf(acc[rr][cc][reg]);
          }
        }
      }
      __syncthreads();
      int gc0 = (nc-4)*128;
      for(int th=t; th<1024; th+=256){
        int row=th>>4, seg=th&15;
        *(uint4*)&G[((size_t)(tok0+row))*256 + gc0 + seg*8]
          = *(const uint4*)&stg[row*136 + seg*8];
      }
    }
  }
}

// ---------------- MFMA GEMM for wo/ffn1/ffn2 ----------------
// MODE 1: wo   N=128 -> fo0 = acc + resid (fp32)
// MODE 2: ffn1 N=256 -> uo  = bf16(gelu(acc + bias)), LDS-staged stores
// MODE 3: ffn2 N=128 -> fo0 = acc + bias + resid (fp32)
template<int K, int MODE>
__global__ __launch_bounds__(256) void mgemm_kernel(
    const u16* __restrict__ A, const u16* __restrict__ Wt,
    const float* __restrict__ bias, const float* __restrict__ resid,
    float* __restrict__ fo0, u16* __restrict__ uo)
{
  __shared__ u16 sA[64][136];
  __shared__ u16 sW[128][136];
  int t = threadIdx.x;
  int tok0 = blockIdx.x*64;
  int n0 = blockIdx.y*128;
  int lane = t&63, wid = t>>6;
  int r0 = (wid>>1)*32, c0 = (wid&1)*64;
  int mrow = lane&15, quad = lane>>4;

  f32x4 acc[2][4];
  #pragma unroll
  for(int rr=0;rr<2;rr++)
    #pragma unroll
    for(int cc=0;cc<4;cc++) acc[rr][cc] = (f32x4){0.f,0.f,0.f,0.f};

  #pragma unroll
  for(int kc=0; kc<K/128; kc++){
    if(kc) __syncthreads();
    for(int c=t; c<1024; c+=256){
      int row=c>>4, col8=(c&15)*8;
      *(uint4*)&sA[row][col8] = *(const uint4*)&A[(size_t)(tok0+row)*K + kc*128 + col8];
    }
    for(int c=t; c<2048; c+=256){
      int row=c>>4, col8=(c&15)*8;
      *(uint4*)&sW[row][col8] = *(const uint4*)&Wt[(size_t)(n0+row)*K + kc*128 + col8];
    }
    __syncthreads();
    #pragma unroll
    for(int ks=0; ks<4; ks++){
      int koff = ks*32 + quad*8;
      bf16x8 a0 = *(const bf16x8*)&sA[r0+mrow][koff];
      bf16x8 a1 = *(const bf16x8*)&sA[r0+16+mrow][koff];
      #pragma unroll
      for(int cc=0; cc<4; cc++){
        bf16x8 b = *(const bf16x8*)&sW[c0+cc*16+mrow][koff];
        acc[0][cc] = __builtin_amdgcn_mfma_f32_16x16x32_bf16(a0,b,acc[0][cc],0,0,0);
        acc[1][cc] = __builtin_amdgcn_mfma_f32_16x16x32_bf16(a1,b,acc[1][cc],0,0,0);
      }
    }
  }

  if(MODE==2){
    u16* stg = &sW[0][0];
    __syncthreads();   // done reading sW
    #pragma unroll
    for(int cc=0;cc<4;cc++){
      int colc = c0 + cc*16 + mrow;
      float bs = bias[n0+colc];
      #pragma unroll
      for(int rr=0;rr<2;rr++){
        #pragma unroll
        for(int reg=0;reg<4;reg++){
          int rowl = r0 + rr*16 + quad*4 + reg;
          stg[rowl*136 + colc] = f2bf(gelu_f(acc[rr][cc][reg] + bs));
        }
      }
    }
    __syncthreads();
    for(int th=t; th<1024; th+=256){
      int row=th>>4, seg=th&15;
      *(uint4*)&uo[((size_t)(tok0+row))*256 + n0 + seg*8]
        = *(const uint4*)&stg[row*136 + seg*8];
    }
  } else {
    #pragma unroll
    for(int rr=0; rr<2; rr++){
      #pragma unroll
      for(int cc=0; cc<4; cc++){
        int colg = n0 + c0 + cc*16 + mrow;
        #pragma unroll
        for(int reg=0; reg<4; reg++){
          int rowg = tok0 + r0 + rr*16 + quad*4 + reg;
          float v = acc[rr][cc][reg];
          if(MODE==1){
            fo0[(size_t)rowg*128 + colg] = v + resid[(size_t)rowg*128 + colg];
          } else {
            fo0[(size_t)rowg*128 + colg] = v + bias[colg] + resid[(size_t)rowg*128 + colg];
          }
        }
      }
    }
  }
}

// ---------------- retention + groupnorm + silu gate, fused ----------------
// Q,K bf16 [bn][l][32]; Vt bf16 [bn][j][512]; G bf16 [tok][256]; Gated bf16 [tok][256]
__global__ __launch_bounds__(256) void retmfma_kernel(
    const u16* __restrict__ Q, const u16* __restrict__ K,
    const u16* __restrict__ Vt, const u16* __restrict__ G,
    const float* __restrict__ gnw, const float* __restrict__ gnb,
    u16* __restrict__ Gated, float4 log2g)
{
  // XCD swizzle: all 8 lt-blocks of one bn land on the same XCD (idx%8 preserved)
  int idx = blockIdx.x;
  int bn = ((idx>>6)<<3) | (idx&7);
  int lt = (idx>>3)&7;
  int n = bn & 3, b = bn >> 2;
  float lg2g = (n==0)?log2g.x:(n==1)?log2g.y:(n==2)?log2g.z:log2g.w;
  __shared__ u16 sQ[64][40];
  __shared__ u16 sK[64][40];
  __shared__ u16 sVt[64][72];
  __shared__ u16 sS[64][72];
  int t = threadIdx.x, lane = t&63, wid = t>>6;
  int mrow = lane&15, quad = lane>>4;
  int r0 = wid*16;
  {
    int row = t>>2, c8 = (t&3)*8;
    *(uint4*)&sQ[row][c8] = *(const uint4*)&Q[((size_t)bn*512 + lt*64 + row)*32 + c8];
  }
  f32x4 oacc[4];
  #pragma unroll
  for(int cc=0;cc<4;cc++) oacc[cc] = (f32x4){0.f,0.f,0.f,0.f};
  float gp1 = exp2f(lg2g), gp2 = gp1*gp1, gp3 = gp2*gp1;
  float gpow[4] = {1.f, gp1, gp2, gp3};
  float gw[4], gb[4];
  #pragma unroll
  for(int cc=0;cc<4;cc++){ gw[cc]=gnw[n*64+cc*16+mrow]; gb[cc]=gnb[n*64+cc*16+mrow]; }
  __syncthreads();
  bf16x8 qa = *(const bf16x8*)&sQ[r0+mrow][quad*8];
  int rowl0 = lt*64 + r0 + quad*4;

  for(int mt=0; mt<=lt; mt++){
    if(mt) __syncthreads();
    {
      int row = t>>2, c8 = (t&3)*8;
      *(uint4*)&sK[row][c8] = *(const uint4*)&K[((size_t)bn*512 + mt*64 + row)*32 + c8];
      int vrow = t>>3, vc8 = (t&7)*8;
      *(uint4*)&sVt[vrow][vc8]    = *(const uint4*)&Vt[((size_t)bn*64 + vrow)*512    + mt*64 + vc8];
      *(uint4*)&sVt[vrow+32][vc8] = *(const uint4*)&Vt[((size_t)bn*64 + vrow+32)*512 + mt*64 + vc8];
    }
    __syncthreads();
    f32x4 sacc[4];
    #pragma unroll
    for(int cc=0;cc<4;cc++){
      bf16x8 bb = *(const bf16x8*)&sK[cc*16+mrow][quad*8];
      sacc[cc] = __builtin_amdgcn_mfma_f32_16x16x32_bf16(qa,bb,(f32x4){0.f,0.f,0.f,0.f},0,0,0);
    }
    #pragma unroll
    for(int cc=0;cc<4;cc++){
      int colm = mt*64 + cc*16 + mrow;
      int d0 = rowl0 - colm;
      float w0 = exp2f(lg2g*(float)d0);
      #pragma unroll
      for(int reg=0;reg<4;reg++){
        float w = (d0+reg>=0) ? w0*gpow[reg] : 0.f;
        sS[r0+quad*4+reg][cc*16+mrow] = f2bf(sacc[cc][reg]*w);
      }
    }
    __syncthreads();
    #pragma unroll
    for(int ks=0;ks<2;ks++){
      bf16x8 a = *(const bf16x8*)&sS[r0+mrow][ks*32+quad*8];
      #pragma unroll
      for(int cc=0;cc<4;cc++){
        bf16x8 bb = *(const bf16x8*)&sVt[cc*16+mrow][ks*32+quad*8];
        oacc[cc] = __builtin_amdgcn_mfma_f32_16x16x32_bf16(a,bb,oacc[cc],0,0,0);
      }
    }
  }

  // ---- fused groupnorm(64) + affine + silu(G) gate; stage bf16 in sS, coalesced store
  __syncthreads();   // all waves done reading sS
  #pragma unroll
  for(int reg=0;reg<4;reg++){
    float s=0.f, sq=0.f;
    #pragma unroll
    for(int cc=0;cc<4;cc++){ float v=oacc[cc][reg]; s+=v; sq+=v*v; }
    #pragma unroll
    for(int m=1;m<16;m<<=1){ s+=__shfl_xor(s,m); sq+=__shfl_xor(sq,m); }
    float mu = s*(1.f/64.f);
    float var = sq*(1.f/64.f) - mu*mu;
    float rn = rsqrtf(var + 1e-5f);
    int rowl = r0 + quad*4 + reg;         // local row 0..63
    int l = lt*64 + rowl;
    size_t gbase = ((size_t)(b*512 + l))*256 + n*64;
    #pragma unroll
    for(int cc=0;cc<4;cc++){
      float gg = bf2f(G[gbase + cc*16+mrow]);
      float gate = gg/(1.f+expf(-gg));
      sS[rowl][cc*16+mrow] = f2bf(gate*((oacc[cc][reg]-mu)*rn*gw[cc] + gb[cc]));
    }
  }
  __syncthreads();
  for(int th=t; th<512; th+=256){
    int row=th>>3, seg=th&7;
    *(uint4*)&Gated[((size_t)(b*512 + lt*64 + row))*256 + n*64 + seg*8]
      = *(const uint4*)&sS[row][seg*8];
  }
}

// ---------------- decoder: gelu(X@w1+b1)@w2+b2 -> softmax(20) ----------------
__global__ __launch_bounds__(64) void dec_kernel(
    const float* __restrict__ X,
    const float* __restrict__ w1, const float* __restrict__ b1,
    const float* __restrict__ w2, const float* __restrict__ b2,
    float* __restrict__ out)
{
  __shared__ float sX[64][129];
  int t = threadIdx.x;
  int tok0 = blockIdx.x*64;
  for(int i=t;i<8192;i+=64){ sX[i>>7][i&127] = X[(size_t)tok0*128 + i]; }
  __syncthreads();
  float h[64];
  #pragma unroll
  for(int j=0;j<64;j++) h[j]=b1[j];
  for(int k=0;k<128;k++){
    float xv = sX[t][k];
    const float* wr = w1 + k*64;
    #pragma unroll
    for(int j=0;j<64;j++) h[j] += xv*wr[j];
  }
  #pragma unroll
  for(int j=0;j<64;j++) h[j]=gelu_f(h[j]);
  float lg[20];
  #pragma unroll
  for(int o=0;o<20;o++) lg[o]=b2[o];
  #pragma unroll
  for(int j=0;j<64;j++){
    float hv = h[j];
    const float* wr = w2 + j*20;
    #pragma unroll
    for(int o=0;o<20;o++) lg[o] += hv*wr[o];
  }
  float mx = -1e30f;
  #pragma unroll
  for(int o=0;o<20;o++) mx = fmaxf(mx, lg[o]);
  float sum = 0.f;
  #pragma unroll
  for(int o=0;o<20;o++){ lg[o]=expf(lg[o]-mx); sum += lg[o]; }
  float inv = 1.f/sum;
  int tok = tok0 + t;
  #pragma unroll
  for(int o=0;o<20;o++) out[(size_t)tok*20 + o] = lg[o]*inv;
}

extern "C" void kernel_launch(void* const* d_in, const int* in_sizes, int n_in,
                              void* d_out, int out_size, void* d_ws, size_t ws_size,
                              hipStream_t stream) {
  (void)in_sizes; (void)n_in; (void)out_size; (void)ws_size;
  const float* x      = (const float*)d_in[0];
  const float* rem_w1 = (const float*)d_in[1];
  const float* rem_b1 = (const float*)d_in[2];
  const float* rem_w2 = (const float*)d_in[3];
  const float* rem_b2 = (const float*)d_in[4];
  const float* rem_w3 = (const float*)d_in[5];
  const float* rem_b3 = (const float*)d_in[6];
  const float* wq     = (const float*)d_in[7];
  const float* wk     = (const float*)d_in[8];
  const float* wv     = (const float*)d_in[9];
  const float* wg     = (const float*)d_in[10];
  const float* wo     = (const float*)d_in[11];
  const float* gn_w   = (const float*)d_in[12];
  const float* gn_b   = (const float*)d_in[13];
  const float* ln1_w  = (const float*)d_in[14];
  const float* ln1_b  = (const float*)d_in[15];
  const float* ln2_w  = (const float*)d_in[16];
  const float* ln2_b  = (const float*)d_in[17];
  const float* ffn_w1 = (const float*)d_in[18];
  const float* ffn_b1 = (const float*)d_in[19];
  const float* ffn_w2 = (const float*)d_in[20];
  const float* ffn_b2 = (const float*)d_in[21];
  const float* dec_w1 = (const float*)d_in[22];
  const float* dec_b1 = (const float*)d_in[23];
  const float* dec_w2 = (const float*)d_in[24];
  const float* dec_b2 = (const float*)d_in[25];
  float* outp = (float*)d_out;

  const size_t S128 = (size_t)BT*128;
  const size_t S256 = (size_t)BT*256;
  float* ws = (float*)d_ws;
  float* Xb = ws;                  // residual X        (S128 f32)
  float* Yr = Xb + S128;           // residual Y        (S128 f32)
  u16*  Qb16    = (u16*)(Yr + S128);     // Q bf16 head-layout (BT*32)
  u16*  Kb16    = Qb16 + (size_t)BT*32;
  u16*  Vt16    = Kb16 + (size_t)BT*32;  // V bf16 transposed [bn][j][l] (BT*64)
  u16*  XnBf    = Vt16 + (size_t)BT*64;  // LN out bf16   (S128)
  u16*  GBf     = XnBf + S128;           // G bf16        (S256)
  u16*  GatedBf = GBf + S256;            // gated / H     (S256)
  u16*  WtBf    = GatedBf + S256;        // bf16 weights  (4*196608)

  double lgA = log(1.0/32.0), lgB = log(1.0/512.0);
  float4 l2g;
  {
    double g0 = 1.0 - exp(lgA + 0.0*(lgB-lgA)/3.0);
    double g1 = 1.0 - exp(lgA + 1.0*(lgB-lgA)/3.0);
    double g2 = 1.0 - exp(lgA + 2.0*(lgB-lgA)/3.0);
    double g3 = 1.0 - exp(lgA + 3.0*(lgB-lgA)/3.0);
    l2g.x = (float)(log(g0)/log(2.0));
    l2g.y = (float)(log(g1)/log(2.0));
    l2g.z = (float)(log(g2)/log(2.0));
    l2g.w = (float)(log(g3)/log(2.0));
  }

  wconv_kernel<<<3072, 256, 0, stream>>>(wq, wk, wv, wg, wo, ffn_w1, ffn_w2, WtBf);
  embed_kernel<<<BT/32, 256, 0, stream>>>(x, rem_w1, rem_b1, rem_w2, rem_b2, rem_w3, rem_b3, Xb);

  for(int li=0; li<4; li++){
    u16* Wt_l = WtBf + (size_t)li*196608;
    const float* gnw_l = gn_w + (size_t)li*VDIM;
    const float* gnb_l = gn_b + (size_t)li*VDIM;
    const float* l1w = ln1_w + (size_t)li*HID, *l1b = ln1_b + (size_t)li*HID;
    const float* l2w = ln2_w + (size_t)li*HID, *l2b = ln2_b + (size_t)li*HID;
    const float* f1b = ffn_b1 + (size_t)li*FFND;
    const float* f2b = ffn_b2 + (size_t)li*HID;

    ln_kernel<<<BT/4, 256, 0, stream>>>(Xb, l1w, l1b, XnBf);
    qkvg_kernel<<<dim3(BT/64,2), 256, 0, stream>>>(XnBf, Wt_l, Qb16, Kb16, Vt16, GBf);
    retmfma_kernel<<<2048, 256, 0, stream>>>(Qb16, Kb16, Vt16, GBf, gnw_l, gnb_l, GatedBf, l2g);
    mgemm_kernel<256,1><<<dim3(BT/64,1), 256, 0, stream>>>(
        GatedBf, Wt_l+98304, nullptr, Xb, Yr, nullptr);
    ln_kernel<<<BT/4, 256, 0, stream>>>(Yr, l2w, l2b, XnBf);
    mgemm_kernel<128,2><<<dim3(BT/64,2), 256, 0, stream>>>(
        XnBf, Wt_l+131072, f1b, nullptr, nullptr, GatedBf);
    mgemm_kernel<256,3><<<dim3(BT/64,1), 256, 0, stream>>>(
        GatedBf, Wt_l+163840, f2b, Yr, Xb, nullptr);
  }

  dec_kernel<<<BT/64, 64, 0, stream>>>(Xb, dec_w1, dec_b1, dec_w2, dec_b2, outp);
}

// Round 6
// 654.378 us; speedup vs baseline: 12.8268x; 1.1016x over previous
//
#include <hip/hip_runtime.h>
#include <math.h>
#include <cmath>

#define SEQ   512
#define NBATCH 64
#define BT    32768      // 64*512 tokens
#define HID   128
#define NHEAD 4
#define HD    32
#define VHD   64
#define VDIM  256
#define FFND  256

typedef __attribute__((ext_vector_type(8))) short bf16x8;
typedef __attribute__((ext_vector_type(4))) float f32x4;
typedef unsigned short u16;

__device__ __forceinline__ float gelu_f(float x){ return 0.5f*x*(1.f+erff(x*0.70710678118f)); }

__device__ __forceinline__ u16 f2bf(float f){
  union{float f; unsigned u;} v; v.f = f;
  unsigned r = v.u + 0x7FFF + ((v.u>>16)&1);
  return (u16)(r>>16);
}
__device__ __forceinline__ float bf2f(u16 u){
  union{unsigned u; float f;} v; v.u = ((unsigned)u)<<16; return v.f;
}

// ---------------- embed: x(BT,5) -> gelu chain -> X(BT,128) ----------------
__global__ __launch_bounds__(256) void embed_kernel(
    const float* __restrict__ x,
    const float* __restrict__ w1, const float* __restrict__ b1,
    const float* __restrict__ w2, const float* __restrict__ b2,
    const float* __restrict__ w3, const float* __restrict__ b3,
    float* __restrict__ X)
{
  __shared__ float sw1[5*32], sw2[32*64], sw3[64*128];
  __shared__ float sb1[32], sb2[64], sb3[128];
  __shared__ float sx[32][6], sh1[32][33], sh2[32][65];
  int t = threadIdx.x;
  for(int i=t;i<160;i+=256)  sw1[i]=w1[i];
  for(int i=t;i<2048;i+=256) sw2[i]=w2[i];
  for(int i=t;i<8192;i+=256) sw3[i]=w3[i];
  if(t<32)  sb1[t]=b1[t];
  if(t<64)  sb2[t]=b2[t];
  if(t<128) sb3[t]=b3[t];
  int tok0 = blockIdx.x*32;
  for(int i=t;i<160;i+=256) sx[i/5][i%5] = x[tok0*5+i];
  __syncthreads();
  for(int task=t; task<1024; task+=256){
    int j=task&31, tok=task>>5;
    float a=sb1[j];
    #pragma unroll
    for(int i=0;i<5;i++) a += sx[tok][i]*sw1[i*32+j];
    sh1[tok][j]=gelu_f(a);
  }
  __syncthreads();
  for(int task=t; task<2048; task+=256){
    int j=task&63, tok=task>>6;
    float a=sb2[j];
    for(int i=0;i<32;i++) a += sh1[tok][i]*sw2[i*64+j];
    sh2[tok][j]=gelu_f(a);
  }
  __syncthreads();
  for(int task=t; task<4096; task+=256){
    int j=task&127, tok=task>>7;
    float a=sb3[j];
    for(int i=0;i<64;i++) a += sh2[tok][i]*sw3[i*128+j];
    X[(tok0+tok)*128 + j]=gelu_f(a);
  }
}

// ---------------- layernorm over 128, wave per token, bf16 out (layer-0 entry only) ----------------
__global__ __launch_bounds__(256) void ln_kernel(
    const float* __restrict__ in, const float* __restrict__ w,
    const float* __restrict__ b, u16* __restrict__ out)
{
  int wv = threadIdx.x>>6, lane = threadIdx.x&63;
  int tok = blockIdx.x*4 + wv;
  const float* row = in + (size_t)tok*128;
  float x0 = row[lane], x1 = row[lane+64];
  float s = x0+x1, sq = x0*x0+x1*x1;
  #pragma unroll
  for(int off=32; off; off>>=1){ s += __shfl_down(s,off); sq += __shfl_down(sq,off); }
  s = __shfl(s,0); sq = __shfl(sq,0);
  float mu = s*(1.f/128.f);
  float var = sq*(1.f/128.f) - mu*mu;
  float r = rsqrtf(var + 1e-5f);
  out[(size_t)tok*128+lane]    = f2bf((x0-mu)*r*w[lane]    + b[lane]);
  out[(size_t)tok*128+lane+64] = f2bf((x1-mu)*r*w[lane+64] + b[lane+64]);
}

// ---------------- weight convert + transpose -> bf16 Wt[N][K] ----------------
// per-layer region (196608 u16): [0)qkvg 768x128  [98304)wo 128x256  [131072)f1 256x128  [163840)f2 128x256
// global tail at 786432: dec_w1t 64x128
__global__ __launch_bounds__(256) void wconv_kernel(
    const float* __restrict__ wq, const float* __restrict__ wk,
    const float* __restrict__ wv, const float* __restrict__ wg,
    const float* __restrict__ wo, const float* __restrict__ f1,
    const float* __restrict__ f2, const float* __restrict__ dw1,
    u16* __restrict__ Wt)
{
  int idx = blockIdx.x*256 + threadIdx.x;   // 0..794623
  if(idx >= 786432){
    int q = idx - 786432; int col = q>>7, h = q&127;
    Wt[idx] = f2bf(dw1[h*64 + col]);
    return;
  }
  int layer = idx / 196608;
  int r = idx - layer*196608;
  u16* W = Wt + (size_t)layer*196608;
  const float* wq_l = wq + (size_t)layer*16384;
  const float* wk_l = wk + (size_t)layer*16384;
  const float* wv_l = wv + (size_t)layer*32768;
  const float* wg_l = wg + (size_t)layer*32768;
  const float* wo_l = wo + (size_t)layer*32768;
  const float* f1_l = f1 + (size_t)layer*32768;
  const float* f2_l = f2 + (size_t)layer*32768;
  float v;
  if(r < 98304){
    int col = r>>7, h = r&127;
    if(col<128){ int n=col>>5, d=col&31; v = wq_l[(n*128+h)*32+d]; }
    else if(col<256){ int c=col-128, n=c>>5, d=c&31; v = wk_l[(n*128+h)*32+d]; }
    else if(col<512){ int c=col-256, n=c>>6, j=c&63; v = wv_l[(n*128+h)*64+j]; }
    else { int p=col-512; v = wg_l[h*256+p]; }
    W[r] = f2bf(v);
  } else if(r < 131072){
    int q = r-98304; int col=q>>8, k=q&255;
    W[r] = f2bf(wo_l[k*128+col]);
  } else if(r < 163840){
    int q = r-131072; int col=q>>7, h=q&127;
    W[r] = f2bf(f1_l[h*256+col]);
  } else {
    int q = r-163840; int col=q>>8, k=q&255;
    W[r] = f2bf(f2_l[k*128+col]);
  }
}

// ---------------- qkvg: block = 64 tokens, y-half x 3 chunks of 128 cols ----------------
__global__ __launch_bounds__(256) void qkvg_kernel(
    const u16* __restrict__ A, const u16* __restrict__ Wt,
    u16* __restrict__ Q, u16* __restrict__ K,
    u16* __restrict__ Vt, u16* __restrict__ G)
{
  __shared__ u16 sA[64][136];
  __shared__ u16 sW[128][136];
  u16* stg = &sW[0][0];
  int t = threadIdx.x, lane = t&63, wid = t>>6;
  int mrow = lane&15, quad = lane>>4;
  int r0 = (wid>>1)*32, c0 = (wid&1)*64;
  int tok0 = blockIdx.x*64;
  int b = tok0>>9, l0 = tok0&511;

  for(int c=t;c<1024;c+=256){ int row=c>>4, col8=(c&15)*8;
    *(uint4*)&sA[row][col8] = *(const uint4*)&A[(size_t)(tok0+row)*128 + col8]; }

  for(int ch=0; ch<3; ch++){
    int nc = blockIdx.y*3 + ch;   // 0..5
    int n0 = nc*128;
    __syncthreads();
    for(int c=t;c<2048;c+=256){ int row=c>>4, col8=(c&15)*8;
      *(uint4*)&sW[row][col8] = *(const uint4*)&Wt[(size_t)(n0+row)*128 + col8]; }
    __syncthreads();

    f32x4 acc[2][4];
    #pragma unroll
    for(int rr=0;rr<2;rr++)
      #pragma unroll
      for(int cc=0;cc<4;cc++) acc[rr][cc] = (f32x4){0.f,0.f,0.f,0.f};
    #pragma unroll
    for(int ks=0; ks<4; ks++){
      int koff = ks*32 + quad*8;
      bf16x8 a0 = *(const bf16x8*)&sA[r0+mrow][koff];
      bf16x8 a1 = *(const bf16x8*)&sA[r0+16+mrow][koff];
      #pragma unroll
      for(int cc=0; cc<4; cc++){
        bf16x8 bb = *(const bf16x8*)&sW[c0+cc*16+mrow][koff];
        acc[0][cc] = __builtin_amdgcn_mfma_f32_16x16x32_bf16(a0,bb,acc[0][cc],0,0,0);
        acc[1][cc] = __builtin_amdgcn_mfma_f32_16x16x32_bf16(a1,bb,acc[1][cc],0,0,0);
      }
    }
    __syncthreads();

    if(nc < 2){
      bool isK = (nc==1);
      #pragma unroll
      for(int cc=0;cc<4;cc++){
        int colc = c0 + cc*16 + mrow;
        int i = (colc&31)>>1;
        float log2bs = log2f(((float)i + 12.8f)*(1.f/44.8f));
        float invf   = exp2f(-(float)i * (13.28771238f/16.f));
        #pragma unroll
        for(int rr=0;rr<2;rr++){
          #pragma unroll
          for(int reg=0;reg<4;reg++){
            int rowl = r0 + rr*16 + quad*4 + reg;
            int l = l0 + rowl;
            float v = acc[rr][cc][reg];
            float partner = __shfl_xor(v, 1);
            float e  = log2bs * (float)l * (1.f/512.f);
            float sc = exp2f(isK ? -e : e);
            float ang = (float)l * invf;
            float cs = cosf(ang)*sc, sn = sinf(ang)*sc;
            float o = (colc&1) ? (v*cs + partner*sn) : (v*cs - partner*sn);
            stg[rowl*136 + colc] = f2bf(o);
          }
        }
      }
      __syncthreads();
      u16* O = isK ? K : Q;
      for(int th=t; th<1024; th+=256){
        int row=th>>4, n=(th>>2)&3, seg=th&3;
        *(uint4*)&O[(((size_t)(b*4+n)*512) + (l0+row))*32 + seg*8]
          = *(const uint4*)&stg[row*136 + n*32 + seg*8];
      }
    } else if(nc < 4){
      #pragma unroll
      for(int cc=0;cc<4;cc++){
        int colc = c0 + cc*16 + mrow;
        #pragma unroll
        for(int rr=0;rr<2;rr++){
          #pragma unroll
          for(int reg=0;reg<4;reg++){
            int rowl = r0 + rr*16 + quad*4 + reg;
            stg[colc*72 + rowl] = f2bf(acc[rr][cc][reg]);
          }
        }
      }
      __syncthreads();
      int jbase = (nc-2)*128;
      for(int th=t; th<1024; th+=256){
        int row=th>>3, seg=th&7;
        int jg = jbase + row; int n = jg>>6, j = jg&63;
        *(uint4*)&Vt[(((size_t)(b*4+n)*64) + j)*512 + l0 + seg*8]
          = *(const uint4*)&stg[row*72 + seg*8];
      }
    } else {
      #pragma unroll
      for(int cc=0;cc<4;cc++){
        int colc = c0 + cc*16 + mrow;
        #pragma unroll
        for(int rr=0;rr<2;rr++){
          #pragma unroll
          for(int reg=0;reg<4;reg++){
            int rowl = r0 + rr*16 + quad*4 + reg;
            stg[rowl*136 + colc] = f2bf(acc[rr][cc][reg]);
          }
        }
      }
      __syncthreads();
      int gc0 = (nc-4)*128;
      for(int th=t; th<1024; th+=256){
        int row=th>>4, seg=th&15;
        *(uint4*)&G[((size_t)(tok0+row))*256 + gc0 + seg*8]
          = *(const uint4*)&stg[row*136 + seg*8];
      }
    }
  }
}

// ---------------- MFMA GEMM for wo/ffn1/ffn2, LN fused where applicable ----------------
// MODE 1: wo   N=128: Y = acc + resid -> fo0 (fp32), then LN(lnw,lnb) -> xn (bf16)
// MODE 2: ffn1 N=256: uo = bf16(gelu(acc + bias)), LDS-staged stores
// MODE 3: ffn2 N=128: X = acc + bias + resid -> fo0 (fp32), then LN -> xn (bf16)
template<int K, int MODE>
__global__ __launch_bounds__(256) void mgemm_kernel(
    const u16* __restrict__ A, const u16* __restrict__ Wt,
    const float* __restrict__ bias, const float* __restrict__ resid,
    float* __restrict__ fo0, u16* __restrict__ uo,
    const float* __restrict__ lnw, const float* __restrict__ lnb,
    u16* __restrict__ xn)
{
  __shared__ u16 sA[64][136];
  __shared__ u16 sW[128][136];
  int t = threadIdx.x;
  int tok0 = blockIdx.x*64;
  int n0 = blockIdx.y*128;
  int lane = t&63, wid = t>>6;
  int r0 = (wid>>1)*32, c0 = (wid&1)*64;
  int mrow = lane&15, quad = lane>>4;

  f32x4 acc[2][4];
  #pragma unroll
  for(int rr=0;rr<2;rr++)
    #pragma unroll
    for(int cc=0;cc<4;cc++) acc[rr][cc] = (f32x4){0.f,0.f,0.f,0.f};

  #pragma unroll
  for(int kc=0; kc<K/128; kc++){
    if(kc) __syncthreads();
    for(int c=t; c<1024; c+=256){
      int row=c>>4, col8=(c&15)*8;
      *(uint4*)&sA[row][col8] = *(const uint4*)&A[(size_t)(tok0+row)*K + kc*128 + col8];
    }
    for(int c=t; c<2048; c+=256){
      int row=c>>4, col8=(c&15)*8;
      *(uint4*)&sW[row][col8] = *(const uint4*)&Wt[(size_t)(n0+row)*K + kc*128 + col8];
    }
    __syncthreads();
    #pragma unroll
    for(int ks=0; ks<4; ks++){
      int koff = ks*32 + quad*8;
      bf16x8 a0 = *(const bf16x8*)&sA[r0+mrow][koff];
      bf16x8 a1 = *(const bf16x8*)&sA[r0+16+mrow][koff];
      #pragma unroll
      for(int cc=0; cc<4; cc++){
        bf16x8 b = *(const bf16x8*)&sW[c0+cc*16+mrow][koff];
        acc[0][cc] = __builtin_amdgcn_mfma_f32_16x16x32_bf16(a0,b,acc[0][cc],0,0,0);
        acc[1][cc] = __builtin_amdgcn_mfma_f32_16x16x32_bf16(a1,b,acc[1][cc],0,0,0);
      }
    }
  }

  if(MODE==2){
    u16* stg = &sW[0][0];
    __syncthreads();
    #pragma unroll
    for(int cc=0;cc<4;cc++){
      int colc = c0 + cc*16 + mrow;
      float bs = bias[n0+colc];
      #pragma unroll
      for(int rr=0;rr<2;rr++){
        #pragma unroll
        for(int reg=0;reg<4;reg++){
          int rowl = r0 + rr*16 + quad*4 + reg;
          stg[rowl*136 + colc] = f2bf(gelu_f(acc[rr][cc][reg] + bs));
        }
      }
    }
    __syncthreads();
    for(int th=t; th<1024; th+=256){
      int row=th>>4, seg=th&15;
      *(uint4*)&uo[((size_t)(tok0+row))*256 + n0 + seg*8]
        = *(const uint4*)&stg[row*136 + seg*8];
    }
  } else {
    // MODE 1/3: full 128-col rows in this block -> fuse LN
    float* fst = (float*)&sW[0][0];   // [64][132]
    __syncthreads();                  // all waves done reading sW
    #pragma unroll
    for(int cc=0; cc<4; cc++){
      int colc = c0 + cc*16 + mrow;
      float bs = (MODE==3) ? bias[colc] : 0.f;
      #pragma unroll
      for(int rr=0; rr<2; rr++){
        #pragma unroll
        for(int reg=0; reg<4; reg++){
          int rowl = r0 + rr*16 + quad*4 + reg;
          int rowg = tok0 + rowl;
          fst[rowl*132 + colc] = acc[rr][cc][reg] + bs + resid[(size_t)rowg*128 + colc];
        }
      }
    }
    __syncthreads();
    // residual store, coalesced float4
    for(int th=t; th<2048; th+=256){
      int row=th>>5, c4=(th&31)*4;
      *(float4*)&fo0[(size_t)(tok0+row)*128 + c4] = *(const float4*)&fst[row*132 + c4];
    }
    // LN: 4 threads per row, 32 cols each -> stage bf16 in sA
    {
      int row = t>>2, q = t&3;
      const float* fr = &fst[row*132 + q*32];
      float s=0.f, sq=0.f;
      #pragma unroll
      for(int i=0;i<32;i+=4){
        float4 v = *(const float4*)&fr[i];
        s += v.x+v.y+v.z+v.w;
        sq += v.x*v.x+v.y*v.y+v.z*v.z+v.w*v.w;
      }
      s += __shfl_xor(s,1); sq += __shfl_xor(sq,1);
      s += __shfl_xor(s,2); sq += __shfl_xor(sq,2);
      float mu = s*(1.f/128.f);
      float var = sq*(1.f/128.f) - mu*mu;
      float rstd = rsqrtf(var + 1e-5f);
      #pragma unroll
      for(int i=0;i<32;i++){
        int col = q*32 + i;
        sA[row][col] = f2bf((fr[i]-mu)*rstd*lnw[col] + lnb[col]);
      }
    }
    __syncthreads();
    for(int th=t; th<1024; th+=256){
      int row=th>>4, seg=th&15;
      *(uint4*)&xn[((size_t)(tok0+row))*128 + seg*8]
        = *(const uint4*)&sA[row][seg*8];
    }
  }
}

// ---------------- retention + groupnorm + silu gate, fused ----------------
__global__ __launch_bounds__(256) void retmfma_kernel(
    const u16* __restrict__ Q, const u16* __restrict__ K,
    const u16* __restrict__ Vt, const u16* __restrict__ G,
    const float* __restrict__ gnw, const float* __restrict__ gnb,
    u16* __restrict__ Gated, float4 log2g)
{
  int idx = blockIdx.x;
  int bn = ((idx>>6)<<3) | (idx&7);
  int lt = (idx>>3)&7;
  int n = bn & 3, b = bn >> 2;
  float lg2g = (n==0)?log2g.x:(n==1)?log2g.y:(n==2)?log2g.z:log2g.w;
  __shared__ u16 sQ[64][40];
  __shared__ u16 sK[64][40];
  __shared__ u16 sVt[64][72];
  __shared__ u16 sS[64][72];
  int t = threadIdx.x, lane = t&63, wid = t>>6;
  int mrow = lane&15, quad = lane>>4;
  int r0 = wid*16;
  {
    int row = t>>2, c8 = (t&3)*8;
    *(uint4*)&sQ[row][c8] = *(const uint4*)&Q[((size_t)bn*512 + lt*64 + row)*32 + c8];
  }
  f32x4 oacc[4];
  #pragma unroll
  for(int cc=0;cc<4;cc++) oacc[cc] = (f32x4){0.f,0.f,0.f,0.f};
  float gp1 = exp2f(lg2g), gp2 = gp1*gp1, gp3 = gp2*gp1;
  float gpow[4] = {1.f, gp1, gp2, gp3};
  float gw[4], gb[4];
  #pragma unroll
  for(int cc=0;cc<4;cc++){ gw[cc]=gnw[n*64+cc*16+mrow]; gb[cc]=gnb[n*64+cc*16+mrow]; }
  __syncthreads();
  bf16x8 qa = *(const bf16x8*)&sQ[r0+mrow][quad*8];
  int rowl0 = lt*64 + r0 + quad*4;

  for(int mt=0; mt<=lt; mt++){
    if(mt) __syncthreads();
    {
      int row = t>>2, c8 = (t&3)*8;
      *(uint4*)&sK[row][c8] = *(const uint4*)&K[((size_t)bn*512 + mt*64 + row)*32 + c8];
      int vrow = t>>3, vc8 = (t&7)*8;
      *(uint4*)&sVt[vrow][vc8]    = *(const uint4*)&Vt[((size_t)bn*64 + vrow)*512    + mt*64 + vc8];
      *(uint4*)&sVt[vrow+32][vc8] = *(const uint4*)&Vt[((size_t)bn*64 + vrow+32)*512 + mt*64 + vc8];
    }
    __syncthreads();
    f32x4 sacc[4];
    #pragma unroll
    for(int cc=0;cc<4;cc++){
      bf16x8 bb = *(const bf16x8*)&sK[cc*16+mrow][quad*8];
      sacc[cc] = __builtin_amdgcn_mfma_f32_16x16x32_bf16(qa,bb,(f32x4){0.f,0.f,0.f,0.f},0,0,0);
    }
    #pragma unroll
    for(int cc=0;cc<4;cc++){
      int colm = mt*64 + cc*16 + mrow;
      int d0 = rowl0 - colm;
      float w0 = exp2f(lg2g*(float)d0);
      #pragma unroll
      for(int reg=0;reg<4;reg++){
        float w = (d0+reg>=0) ? w0*gpow[reg] : 0.f;
        sS[r0+quad*4+reg][cc*16+mrow] = f2bf(sacc[cc][reg]*w);
      }
    }
    __syncthreads();
    #pragma unroll
    for(int ks=0;ks<2;ks++){
      bf16x8 a = *(const bf16x8*)&sS[r0+mrow][ks*32+quad*8];
      #pragma unroll
      for(int cc=0;cc<4;cc++){
        bf16x8 bb = *(const bf16x8*)&sVt[cc*16+mrow][ks*32+quad*8];
        oacc[cc] = __builtin_amdgcn_mfma_f32_16x16x32_bf16(a,bb,oacc[cc],0,0,0);
      }
    }
  }

  __syncthreads();
  #pragma unroll
  for(int reg=0;reg<4;reg++){
    float s=0.f, sq=0.f;
    #pragma unroll
    for(int cc=0;cc<4;cc++){ float v=oacc[cc][reg]; s+=v; sq+=v*v; }
    #pragma unroll
    for(int m=1;m<16;m<<=1){ s+=__shfl_xor(s,m); sq+=__shfl_xor(sq,m); }
    float mu = s*(1.f/64.f);
    float var = sq*(1.f/64.f) - mu*mu;
    float rn = rsqrtf(var + 1e-5f);
    int rowl = r0 + quad*4 + reg;
    int l = lt*64 + rowl;
    size_t gbase = ((size_t)(b*512 + l))*256 + n*64;
    #pragma unroll
    for(int cc=0;cc<4;cc++){
      float gg = bf2f(G[gbase + cc*16+mrow]);
      float gate = gg/(1.f+expf(-gg));
      sS[rowl][cc*16+mrow] = f2bf(gate*((oacc[cc][reg]-mu)*rn*gw[cc] + gb[cc]));
    }
  }
  __syncthreads();
  for(int th=t; th<512; th+=256){
    int row=th>>3, seg=th&7;
    *(uint4*)&Gated[((size_t)(b*512 + lt*64 + row))*256 + n*64 + seg*8]
      = *(const uint4*)&sS[row][seg*8];
  }
}

// ---------------- decoder (MFMA): softmax(gelu(X@w1+b1)@w2+b2) ----------------
__global__ __launch_bounds__(256) void dec_kernel(
    const float* __restrict__ X, const u16* __restrict__ W1t,
    const float* __restrict__ b1, const float* __restrict__ w2,
    const float* __restrict__ b2, float* __restrict__ out)
{
  __shared__ u16 sA[64][136];
  __shared__ u16 sW[64][136];
  __shared__ float sH[64][68];
  __shared__ float sL[64*20];
  __shared__ float sw2[64*20];
  __shared__ float sb2[20];
  int t = threadIdx.x, lane = t&63, wid = t>>6;
  int mrow = lane&15, quad = lane>>4;
  int tok0 = blockIdx.x*64;

  for(int th=t; th<2048; th+=256){
    int row=th>>5, c4=(th&31)*4;
    float4 v = *(const float4*)&X[(size_t)(tok0+row)*128 + c4];
    ushort4 p; p.x=f2bf(v.x); p.y=f2bf(v.y); p.z=f2bf(v.z); p.w=f2bf(v.w);
    *(ushort4*)&sA[row][c4] = p;
  }
  for(int th=t; th<1024; th+=256){
    int row=th>>4, c8=(th&15)*8;
    *(uint4*)&sW[row][c8] = *(const uint4*)&W1t[(size_t)row*128 + c8];
  }
  for(int i=t;i<1280;i+=256) sw2[i]=w2[i];
  if(t<20) sb2[t]=b2[t];
  __syncthreads();

  int r0 = wid*16;
  f32x4 acc[4];
  #pragma unroll
  for(int cc=0;cc<4;cc++) acc[cc] = (f32x4){0.f,0.f,0.f,0.f};
  #pragma unroll
  for(int ks=0; ks<4; ks++){
    int koff = ks*32 + quad*8;
    bf16x8 a = *(const bf16x8*)&sA[r0+mrow][koff];
    #pragma unroll
    for(int cc=0; cc<4; cc++){
      bf16x8 b = *(const bf16x8*)&sW[cc*16+mrow][koff];
      acc[cc] = __builtin_amdgcn_mfma_f32_16x16x32_bf16(a,b,acc[cc],0,0,0);
    }
  }
  #pragma unroll
  for(int cc=0;cc<4;cc++){
    int col = cc*16 + mrow;
    float bb = b1[col];
    #pragma unroll
    for(int reg=0;reg<4;reg++){
      sH[r0 + quad*4 + reg][col] = gelu_f(acc[cc][reg] + bb);
    }
  }
  __syncthreads();

  for(int task=t; task<1280; task+=256){
    int tk = task/20, o = task - tk*20;
    float a = sb2[o];
    for(int k=0;k<64;k++) a += sH[tk][k]*sw2[k*20+o];
    sL[tk*20+o] = a;
  }
  __syncthreads();
  if(t < 64){
    float mx = -1e30f;
    #pragma unroll
    for(int o=0;o<20;o++) mx = fmaxf(mx, sL[t*20+o]);
    float sum = 0.f;
    float e[20];
    #pragma unroll
    for(int o=0;o<20;o++){ e[o]=expf(sL[t*20+o]-mx); sum += e[o]; }
    float inv = 1.f/sum;
    #pragma unroll
    for(int o=0;o<20;o++) sL[t*20+o] = e[o]*inv;
  }
  __syncthreads();
  for(int th=t; th<1280; th+=256){
    out[(size_t)tok0*20 + th] = sL[th];
  }
}

extern "C" void kernel_launch(void* const* d_in, const int* in_sizes, int n_in,
                              void* d_out, int out_size, void* d_ws, size_t ws_size,
                              hipStream_t stream) {
  (void)in_sizes; (void)n_in; (void)out_size; (void)ws_size;
  const float* x      = (const float*)d_in[0];
  const float* rem_w1 = (const float*)d_in[1];
  const float* rem_b1 = (const float*)d_in[2];
  const float* rem_w2 = (const float*)d_in[3];
  const float* rem_b2 = (const float*)d_in[4];
  const float* rem_w3 = (const float*)d_in[5];
  const float* rem_b3 = (const float*)d_in[6];
  const float* wq     = (const float*)d_in[7];
  const float* wk     = (const float*)d_in[8];
  const float* wv     = (const float*)d_in[9];
  const float* wg     = (const float*)d_in[10];
  const float* wo     = (const float*)d_in[11];
  const float* gn_w   = (const float*)d_in[12];
  const float* gn_b   = (const float*)d_in[13];
  const float* ln1_w  = (const float*)d_in[14];
  const float* ln1_b  = (const float*)d_in[15];
  const float* ln2_w  = (const float*)d_in[16];
  const float* ln2_b  = (const float*)d_in[17];
  const float* ffn_w1 = (const float*)d_in[18];
  const float* ffn_b1 = (const float*)d_in[19];
  const float* ffn_w2 = (const float*)d_in[20];
  const float* ffn_b2 = (const float*)d_in[21];
  const float* dec_w1 = (const float*)d_in[22];
  const float* dec_b1 = (const float*)d_in[23];
  const float* dec_w2 = (const float*)d_in[24];
  const float* dec_b2 = (const float*)d_in[25];
  float* outp = (float*)d_out;

  const size_t S128 = (size_t)BT*128;
  const size_t S256 = (size_t)BT*256;
  float* ws = (float*)d_ws;
  float* Xb = ws;                  // residual X        (S128 f32)
  float* Yr = Xb + S128;           // residual Y        (S128 f32)
  u16*  Qb16    = (u16*)(Yr + S128);     // Q bf16 head-layout (BT*32)
  u16*  Kb16    = Qb16 + (size_t)BT*32;
  u16*  Vt16    = Kb16 + (size_t)BT*32;  // V bf16 transposed (BT*64)
  u16*  XnBf    = Vt16 + (size_t)BT*64;  // LN out bf16   (S128)
  u16*  GBf     = XnBf + S128;           // G bf16        (S256)
  u16*  GatedBf = GBf + S256;            // gated / H     (S256)
  u16*  WtBf    = GatedBf + S256;        // bf16 weights  (4*196608 + 8192)

  double lgA = log(1.0/32.0), lgB = log(1.0/512.0);
  float4 l2g;
  {
    double g0 = 1.0 - exp(lgA + 0.0*(lgB-lgA)/3.0);
    double g1 = 1.0 - exp(lgA + 1.0*(lgB-lgA)/3.0);
    double g2 = 1.0 - exp(lgA + 2.0*(lgB-lgA)/3.0);
    double g3 = 1.0 - exp(lgA + 3.0*(lgB-lgA)/3.0);
    l2g.x = (float)(log(g0)/log(2.0));
    l2g.y = (float)(log(g1)/log(2.0));
    l2g.z = (float)(log(g2)/log(2.0));
    l2g.w = (float)(log(g3)/log(2.0));
  }

  wconv_kernel<<<3104, 256, 0, stream>>>(wq, wk, wv, wg, wo, ffn_w1, ffn_w2, dec_w1, WtBf);
  embed_kernel<<<BT/32, 256, 0, stream>>>(x, rem_w1, rem_b1, rem_w2, rem_b2, rem_w3, rem_b3, Xb);
  ln_kernel<<<BT/4, 256, 0, stream>>>(Xb, ln1_w, ln1_b, XnBf);   // layer 0 LN1

  for(int li=0; li<4; li++){
    u16* Wt_l = WtBf + (size_t)li*196608;
    const float* gnw_l = gn_w + (size_t)li*VDIM;
    const float* gnb_l = gn_b + (size_t)li*VDIM;
    const float* l2w = ln2_w + (size_t)li*HID, *l2b = ln2_b + (size_t)li*HID;
    const float* f1b = ffn_b1 + (size_t)li*FFND;
    const float* f2b = ffn_b2 + (size_t)li*HID;
    int nli = (li+1)&3;  // LN1 weights for next layer (unused result at li==3)
    const float* n1w = ln1_w + (size_t)nli*HID, *n1b = ln1_b + (size_t)nli*HID;

    qkvg_kernel<<<dim3(BT/64,2), 256, 0, stream>>>(XnBf, Wt_l, Qb16, Kb16, Vt16, GBf);
    retmfma_kernel<<<2048, 256, 0, stream>>>(Qb16, Kb16, Vt16, GBf, gnw_l, gnb_l, GatedBf, l2g);
    mgemm_kernel<256,1><<<dim3(BT/64,1), 256, 0, stream>>>(
        GatedBf, Wt_l+98304, nullptr, Xb, Yr, nullptr, l2w, l2b, XnBf);      // Y + LN2
    mgemm_kernel<128,2><<<dim3(BT/64,2), 256, 0, stream>>>(
        XnBf, Wt_l+131072, f1b, nullptr, nullptr, GatedBf, nullptr, nullptr, nullptr);
    mgemm_kernel<256,3><<<dim3(BT/64,1), 256, 0, stream>>>(
        GatedBf, Wt_l+163840, f2b, Yr, Xb, nullptr, n1w, n1b, XnBf);         // X + LN1(next)
  }

  dec_kernel<<<BT/64, 256, 0, stream>>>(Xb, WtBf+786432, dec_b1, dec_w2, dec_b2, outp);
}

// Round 7
// 613.890 us; speedup vs baseline: 13.6728x; 1.0660x over previous
//
#include <hip/hip_runtime.h>
#include <math.h>
#include <cmath>

#define SEQ   512
#define NBATCH 64
#define BT    32768      // 64*512 tokens
#define HID   128
#define NHEAD 4
#define HD    32
#define VHD   64
#define VDIM  256
#define FFND  256

typedef __attribute__((ext_vector_type(8))) short bf16x8;
typedef __attribute__((ext_vector_type(4))) float f32x4;
typedef unsigned short u16;

__device__ __forceinline__ float gelu_f(float x){ return 0.5f*x*(1.f+erff(x*0.70710678118f)); }

__device__ __forceinline__ u16 f2bf(float f){
  union{float f; unsigned u;} v; v.f = f;
  unsigned r = v.u + 0x7FFF + ((v.u>>16)&1);
  return (u16)(r>>16);
}
__device__ __forceinline__ float bf2f(u16 u){
  union{unsigned u; float f;} v; v.u = ((unsigned)u)<<16; return v.f;
}

// ---------------- weight convert + transpose -> bf16 Wt[N][K] ----------------
// per-layer region (196608 u16): [0)qkvg 768x128  [98304)wo 128x256  [131072)f1 256x128  [163840)f2 128x256
// tail: 786432 dec_w1t 64x128 (8192); 794624 rem_w2t 64x32 (2048); 796672 rem_w3t 128x64 (8192). total 804864
__global__ __launch_bounds__(256) void wconv_kernel(
    const float* __restrict__ wq, const float* __restrict__ wk,
    const float* __restrict__ wv, const float* __restrict__ wg,
    const float* __restrict__ wo, const float* __restrict__ f1,
    const float* __restrict__ f2, const float* __restrict__ dw1,
    const float* __restrict__ w2e, const float* __restrict__ w3e,
    u16* __restrict__ Wt)
{
  int idx = blockIdx.x*256 + threadIdx.x;   // 0..804863
  if(idx >= 786432){
    int q = idx - 786432;
    if(q < 8192){ int col=q>>7, h=q&127; Wt[idx]=f2bf(dw1[h*64+col]); }
    else if(q < 10240){ int p=q-8192; int row=p>>5, col=p&31; Wt[idx]=f2bf(w2e[col*64+row]); }
    else { int p=q-10240; int row=p>>6, col=p&63; Wt[idx]=f2bf(w3e[col*128+row]); }
    return;
  }
  int layer = idx / 196608;
  int r = idx - layer*196608;
  u16* W = Wt + (size_t)layer*196608;
  const float* wq_l = wq + (size_t)layer*16384;
  const float* wk_l = wk + (size_t)layer*16384;
  const float* wv_l = wv + (size_t)layer*32768;
  const float* wg_l = wg + (size_t)layer*32768;
  const float* wo_l = wo + (size_t)layer*32768;
  const float* f1_l = f1 + (size_t)layer*32768;
  const float* f2_l = f2 + (size_t)layer*32768;
  float v;
  if(r < 98304){
    int col = r>>7, h = r&127;
    if(col<128){ int n=col>>5, d=col&31; v = wq_l[(n*128+h)*32+d]; }
    else if(col<256){ int c=col-128, n=c>>5, d=c&31; v = wk_l[(n*128+h)*32+d]; }
    else if(col<512){ int c=col-256, n=c>>6, j=c&63; v = wv_l[(n*128+h)*64+j]; }
    else { int p=col-512; v = wg_l[h*256+p]; }
    W[r] = f2bf(v);
  } else if(r < 131072){
    int q = r-98304; int col=q>>8, k=q&255;
    W[r] = f2bf(wo_l[k*128+col]);
  } else if(r < 163840){
    int q = r-131072; int col=q>>7, h=q&127;
    W[r] = f2bf(f1_l[h*256+col]);
  } else {
    int q = r-163840; int col=q>>8, k=q&255;
    W[r] = f2bf(f2_l[k*128+col]);
  }
}

// ---------------- embed (MFMA) + fused layer-0 LN1 ----------------
// x(64tok,5) -> h1(32) scalar -> h2(64) mfma -> X(128) mfma -> Xb fp32 + LN1 -> xn bf16
__global__ __launch_bounds__(256) void embed_kernel(
    const float* __restrict__ x,
    const float* __restrict__ w1, const float* __restrict__ b1,
    const float* __restrict__ b2, const float* __restrict__ b3,
    const u16* __restrict__ W23t,     // w2t[64][32] at 0, w3t[128][64] at 2048
    const float* __restrict__ lnw, const float* __restrict__ lnb,
    float* __restrict__ X, u16* __restrict__ xn)
{
  __shared__ float sx[64][6];
  __shared__ float sw1[160], sb1[32], sb2[64], sb3[128];
  __shared__ u16 big[18944];
  // offsets (u16): sh1=0 (64 x s40); w2t=2560 (64 x s40); sh2=5120 (64 x s72); w3t=9728 (128 x s72)
  int t=threadIdx.x, lane=t&63, wid=t>>6, mrow=lane&15, quad=lane>>4, r0=wid*16;
  int tok0=blockIdx.x*64;

  for(int i=t;i<320;i+=256) sx[i/5][i%5]=x[(size_t)tok0*5+i];
  for(int i=t;i<160;i+=256) sw1[i]=w1[i];
  if(t<32) sb1[t]=b1[t];
  if(t<64) sb2[t]=b2[t];
  if(t<128) sb3[t]=b3[t];
  for(int c=t;c<256;c+=256){ int row=c>>2, c8=(c&3)*8;
    *(uint4*)&big[2560+row*40+c8]=*(const uint4*)&W23t[row*32+c8]; }
  for(int c=t;c<1024;c+=256){ int row=c>>3, c8=(c&7)*8;
    *(uint4*)&big[9728+row*72+c8]=*(const uint4*)&W23t[2048+row*64+c8]; }
  __syncthreads();

  // phase1 scalar: h1 bf16 -> big[0..2560)
  for(int task=t; task<2048; task+=256){
    int tok=task>>5, j=task&31;
    float a=sb1[j];
    #pragma unroll
    for(int i=0;i<5;i++) a+=sx[tok][i]*sw1[i*32+j];
    big[tok*40+j]=f2bf(gelu_f(a));
  }
  __syncthreads();

  // phase2 mfma: 64 tok x 64 out, K=32
  f32x4 h2[4];
  #pragma unroll
  for(int cc=0;cc<4;cc++) h2[cc]=(f32x4){0.f,0.f,0.f,0.f};
  {
    bf16x8 a=*(const bf16x8*)&big[(r0+mrow)*40+quad*8];
    #pragma unroll
    for(int cc=0;cc<4;cc++){
      bf16x8 b=*(const bf16x8*)&big[2560+(cc*16+mrow)*40+quad*8];
      h2[cc]=__builtin_amdgcn_mfma_f32_16x16x32_bf16(a,b,h2[cc],0,0,0);
    }
  }
  #pragma unroll
  for(int cc=0;cc<4;cc++){
    float bs=sb2[cc*16+mrow];
    #pragma unroll
    for(int reg=0;reg<4;reg++)
      big[5120+(r0+quad*4+reg)*72+cc*16+mrow]=f2bf(gelu_f(h2[cc][reg]+bs));
  }
  __syncthreads();

  // phase3 mfma: 64 tok x 128 out, K=64
  f32x4 xac[8];
  #pragma unroll
  for(int cc=0;cc<8;cc++) xac[cc]=(f32x4){0.f,0.f,0.f,0.f};
  #pragma unroll
  for(int ks=0;ks<2;ks++){
    bf16x8 a=*(const bf16x8*)&big[5120+(r0+mrow)*72+ks*32+quad*8];
    #pragma unroll
    for(int cc=0;cc<8;cc++){
      bf16x8 b=*(const bf16x8*)&big[9728+(cc*16+mrow)*72+ks*32+quad*8];
      xac[cc]=__builtin_amdgcn_mfma_f32_16x16x32_bf16(a,b,xac[cc],0,0,0);
    }
  }
  __syncthreads();   // all MFMAs done; big[0..8704) reusable as xn stage

  #pragma unroll
  for(int reg=0;reg<4;reg++){
    int rowl=r0+quad*4+reg, rowg=tok0+rowl;
    float xv[8], s=0.f, sq=0.f;
    #pragma unroll
    for(int cc=0;cc<8;cc++){
      float v=gelu_f(xac[cc][reg]+sb3[cc*16+mrow]);
      xv[cc]=v; s+=v; sq+=v*v;
    }
    #pragma unroll
    for(int m=1;m<16;m<<=1){ s+=__shfl_xor(s,m); sq+=__shfl_xor(sq,m); }
    float mu=s*(1.f/128.f);
    float var=sq*(1.f/128.f)-mu*mu;
    float rstd=rsqrtf(var+1e-5f);
    #pragma unroll
    for(int cc=0;cc<8;cc++){
      int col=cc*16+mrow;
      X[(size_t)rowg*128+col]=xv[cc];
      big[rowl*136+col]=f2bf((xv[cc]-mu)*rstd*lnw[col]+lnb[col]);
    }
  }
  __syncthreads();
  for(int th=t; th<1024; th+=256){
    int row=th>>4, seg=th&15;
    *(uint4*)&xn[(size_t)(tok0+row)*128+seg*8]=*(const uint4*)&big[row*136+seg*8];
  }
}

// ---------------- qkvg: block = 64 tokens, y-half x 3 chunks of 128 cols ----------------
__global__ __launch_bounds__(256) void qkvg_kernel(
    const u16* __restrict__ A, const u16* __restrict__ Wt,
    u16* __restrict__ Q, u16* __restrict__ K,
    u16* __restrict__ Vt, u16* __restrict__ G)
{
  __shared__ u16 sA[64][136];
  __shared__ u16 sW[128][136];
  u16* stg = &sW[0][0];
  int t = threadIdx.x, lane = t&63, wid = t>>6;
  int mrow = lane&15, quad = lane>>4;
  int r0 = (wid>>1)*32, c0 = (wid&1)*64;
  int tok0 = blockIdx.x*64;
  int b = tok0>>9, l0 = tok0&511;

  for(int c=t;c<1024;c+=256){ int row=c>>4, col8=(c&15)*8;
    *(uint4*)&sA[row][col8] = *(const uint4*)&A[(size_t)(tok0+row)*128 + col8]; }

  for(int ch=0; ch<3; ch++){
    int nc = blockIdx.y*3 + ch;   // 0..5
    int n0 = nc*128;
    __syncthreads();
    for(int c=t;c<2048;c+=256){ int row=c>>4, col8=(c&15)*8;
      *(uint4*)&sW[row][col8] = *(const uint4*)&Wt[(size_t)(n0+row)*128 + col8]; }
    __syncthreads();

    f32x4 acc[2][4];
    #pragma unroll
    for(int rr=0;rr<2;rr++)
      #pragma unroll
      for(int cc=0;cc<4;cc++) acc[rr][cc] = (f32x4){0.f,0.f,0.f,0.f};
    #pragma unroll
    for(int ks=0; ks<4; ks++){
      int koff = ks*32 + quad*8;
      bf16x8 a0 = *(const bf16x8*)&sA[r0+mrow][koff];
      bf16x8 a1 = *(const bf16x8*)&sA[r0+16+mrow][koff];
      #pragma unroll
      for(int cc=0; cc<4; cc++){
        bf16x8 bb = *(const bf16x8*)&sW[c0+cc*16+mrow][koff];
        acc[0][cc] = __builtin_amdgcn_mfma_f32_16x16x32_bf16(a0,bb,acc[0][cc],0,0,0);
        acc[1][cc] = __builtin_amdgcn_mfma_f32_16x16x32_bf16(a1,bb,acc[1][cc],0,0,0);
      }
    }
    __syncthreads();

    if(nc < 2){
      bool isK = (nc==1);
      #pragma unroll
      for(int cc=0;cc<4;cc++){
        int colc = c0 + cc*16 + mrow;
        int i = (colc&31)>>1;
        float log2bs = log2f(((float)i + 12.8f)*(1.f/44.8f));
        float invf   = exp2f(-(float)i * (13.28771238f/16.f));
        #pragma unroll
        for(int rr=0;rr<2;rr++){
          #pragma unroll
          for(int reg=0;reg<4;reg++){
            int rowl = r0 + rr*16 + quad*4 + reg;
            int l = l0 + rowl;
            float v = acc[rr][cc][reg];
            float partner = __shfl_xor(v, 1);
            float e  = log2bs * (float)l * (1.f/512.f);
            float sc = exp2f(isK ? -e : e);
            float ang = (float)l * invf;
            float cs = cosf(ang)*sc, sn = sinf(ang)*sc;
            float o = (colc&1) ? (v*cs + partner*sn) : (v*cs - partner*sn);
            stg[rowl*136 + colc] = f2bf(o);
          }
        }
      }
      __syncthreads();
      u16* O = isK ? K : Q;
      for(int th=t; th<1024; th+=256){
        int row=th>>4, n=(th>>2)&3, seg=th&3;
        *(uint4*)&O[(((size_t)(b*4+n)*512) + (l0+row))*32 + seg*8]
          = *(const uint4*)&stg[row*136 + n*32 + seg*8];
      }
    } else if(nc < 4){
      #pragma unroll
      for(int cc=0;cc<4;cc++){
        int colc = c0 + cc*16 + mrow;
        #pragma unroll
        for(int rr=0;rr<2;rr++){
          #pragma unroll
          for(int reg=0;reg<4;reg++){
            int rowl = r0 + rr*16 + quad*4 + reg;
            stg[colc*72 + rowl] = f2bf(acc[rr][cc][reg]);
          }
        }
      }
      __syncthreads();
      int jbase = (nc-2)*128;
      for(int th=t; th<1024; th+=256){
        int row=th>>3, seg=th&7;
        int jg = jbase + row; int n = jg>>6, j = jg&63;
        *(uint4*)&Vt[(((size_t)(b*4+n)*64) + j)*512 + l0 + seg*8]
          = *(const uint4*)&stg[row*72 + seg*8];
      }
    } else {
      #pragma unroll
      for(int cc=0;cc<4;cc++){
        int colc = c0 + cc*16 + mrow;
        #pragma unroll
        for(int rr=0;rr<2;rr++){
          #pragma unroll
          for(int reg=0;reg<4;reg++){
            int rowl = r0 + rr*16 + quad*4 + reg;
            stg[rowl*136 + colc] = f2bf(acc[rr][cc][reg]);
          }
        }
      }
      __syncthreads();
      int gc0 = (nc-4)*128;
      for(int th=t; th<1024; th+=256){
        int row=th>>4, seg=th&15;
        *(uint4*)&G[((size_t)(tok0+row))*256 + gc0 + seg*8]
          = *(const uint4*)&stg[row*136 + seg*8];
      }
    }
  }
}

// ---------------- wo GEMM (K=256,N=128) + resid -> Yr fp32 + fused LN2 -> xn bf16 ----------------
template<int K, int MODE>
__global__ __launch_bounds__(256) void mgemm_kernel(
    const u16* __restrict__ A, const u16* __restrict__ Wt,
    const float* __restrict__ bias, const float* __restrict__ resid,
    float* __restrict__ fo0, u16* __restrict__ uo,
    const float* __restrict__ lnw, const float* __restrict__ lnb,
    u16* __restrict__ xn)
{
  __shared__ u16 sA[64][136];
  __shared__ u16 sW[128][136];
  int t = threadIdx.x;
  int tok0 = blockIdx.x*64;
  int n0 = blockIdx.y*128;
  int lane = t&63, wid = t>>6;
  int r0 = (wid>>1)*32, c0 = (wid&1)*64;
  int mrow = lane&15, quad = lane>>4;

  f32x4 acc[2][4];
  #pragma unroll
  for(int rr=0;rr<2;rr++)
    #pragma unroll
    for(int cc=0;cc<4;cc++) acc[rr][cc] = (f32x4){0.f,0.f,0.f,0.f};

  #pragma unroll
  for(int kc=0; kc<K/128; kc++){
    if(kc) __syncthreads();
    for(int c=t; c<1024; c+=256){
      int row=c>>4, col8=(c&15)*8;
      *(uint4*)&sA[row][col8] = *(const uint4*)&A[(size_t)(tok0+row)*K + kc*128 + col8];
    }
    for(int c=t; c<2048; c+=256){
      int row=c>>4, col8=(c&15)*8;
      *(uint4*)&sW[row][col8] = *(const uint4*)&Wt[(size_t)(n0+row)*K + kc*128 + col8];
    }
    __syncthreads();
    #pragma unroll
    for(int ks=0; ks<4; ks++){
      int koff = ks*32 + quad*8;
      bf16x8 a0 = *(const bf16x8*)&sA[r0+mrow][koff];
      bf16x8 a1 = *(const bf16x8*)&sA[r0+16+mrow][koff];
      #pragma unroll
      for(int cc=0; cc<4; cc++){
        bf16x8 b = *(const bf16x8*)&sW[c0+cc*16+mrow][koff];
        acc[0][cc] = __builtin_amdgcn_mfma_f32_16x16x32_bf16(a0,b,acc[0][cc],0,0,0);
        acc[1][cc] = __builtin_amdgcn_mfma_f32_16x16x32_bf16(a1,b,acc[1][cc],0,0,0);
      }
    }
  }

  // MODE 1: full 128-col rows -> resid add + LN fusion
  float* fst = (float*)&sW[0][0];   // [64][132]
  __syncthreads();
  #pragma unroll
  for(int cc=0; cc<4; cc++){
    int colc = c0 + cc*16 + mrow;
    float bs = (MODE==3) ? bias[colc] : 0.f;
    #pragma unroll
    for(int rr=0; rr<2; rr++){
      #pragma unroll
      for(int reg=0; reg<4; reg++){
        int rowl = r0 + rr*16 + quad*4 + reg;
        int rowg = tok0 + rowl;
        fst[rowl*132 + colc] = acc[rr][cc][reg] + bs + resid[(size_t)rowg*128 + colc];
      }
    }
  }
  __syncthreads();
  for(int th=t; th<2048; th+=256){
    int row=th>>5, c4=(th&31)*4;
    *(float4*)&fo0[(size_t)(tok0+row)*128 + c4] = *(const float4*)&fst[row*132 + c4];
  }
  {
    int row = t>>2, q = t&3;
    const float* fr = &fst[row*132 + q*32];
    float s=0.f, sq=0.f;
    #pragma unroll
    for(int i=0;i<32;i+=4){
      float4 v = *(const float4*)&fr[i];
      s += v.x+v.y+v.z+v.w;
      sq += v.x*v.x+v.y*v.y+v.z*v.z+v.w*v.w;
    }
    s += __shfl_xor(s,1); sq += __shfl_xor(sq,1);
    s += __shfl_xor(s,2); sq += __shfl_xor(sq,2);
    float mu = s*(1.f/128.f);
    float var = sq*(1.f/128.f) - mu*mu;
    float rstd = rsqrtf(var + 1e-5f);
    #pragma unroll
    for(int i=0;i<32;i++){
      int col = q*32 + i;
      sA[row][col] = f2bf((fr[i]-mu)*rstd*lnw[col] + lnb[col]);
    }
  }
  __syncthreads();
  for(int th=t; th<1024; th+=256){
    int row=th>>4, seg=th&15;
    *(uint4*)&xn[((size_t)(tok0+row))*128 + seg*8]
      = *(const uint4*)&sA[row][seg*8];
  }
}

// ---------------- fused FFN: Z -> H=gelu(Z@w1+b1) in LDS -> X=H@w2+b2+resid -> Xb fp32 + LN1(next) -> xn ----------------
__global__ __launch_bounds__(256) void ffn_kernel(
    const u16* __restrict__ Z, const u16* __restrict__ W1t, const float* __restrict__ b1,
    const u16* __restrict__ W2t, const float* __restrict__ b2,
    const float* __restrict__ resid, float* __restrict__ Xout,
    const float* __restrict__ lnw, const float* __restrict__ lnb,
    u16* __restrict__ xn)
{
  __shared__ u16 sZ[64][136];    // 17.4 KB: Z, later xn stage
  __shared__ u16 sH[64][264];    // 33.8 KB: H
  __shared__ u16 sW[4352];       //  8.7 KB: weight chunks (f1: 32x136 ; f2: 16x264)
  int t=threadIdx.x, lane=t&63, wid=t>>6, mrow=lane&15, quad=lane>>4, r0=wid*16;
  int tok0=blockIdx.x*64;

  for(int c=t;c<1024;c+=256){ int row=c>>4, c8=(c&15)*8;
    *(uint4*)&sZ[row][c8]=*(const uint4*)&Z[(size_t)(tok0+row)*128+c8]; }

  // ffn1: 8 chunks of 32 out cols (K=128)
  #pragma unroll
  for(int ch=0; ch<8; ch++){
    __syncthreads();
    for(int c=t;c<512;c+=256){ int row=c>>4, c8=(c&15)*8;
      *(uint4*)&sW[row*136+c8]=*(const uint4*)&W1t[(size_t)(ch*32+row)*128+c8]; }
    __syncthreads();
    f32x4 h0=(f32x4){0.f,0.f,0.f,0.f}, h1=(f32x4){0.f,0.f,0.f,0.f};
    #pragma unroll
    for(int ks=0;ks<4;ks++){
      bf16x8 a=*(const bf16x8*)&sZ[r0+mrow][ks*32+quad*8];
      bf16x8 bb0=*(const bf16x8*)&sW[mrow*136+ks*32+quad*8];
      bf16x8 bb1=*(const bf16x8*)&sW[(16+mrow)*136+ks*32+quad*8];
      h0=__builtin_amdgcn_mfma_f32_16x16x32_bf16(a,bb0,h0,0,0,0);
      h1=__builtin_amdgcn_mfma_f32_16x16x32_bf16(a,bb1,h1,0,0,0);
    }
    float bs0=b1[ch*32+mrow], bs1=b1[ch*32+16+mrow];
    #pragma unroll
    for(int reg=0;reg<4;reg++){
      sH[r0+quad*4+reg][ch*32+mrow]    = f2bf(gelu_f(h0[reg]+bs0));
      sH[r0+quad*4+reg][ch*32+16+mrow] = f2bf(gelu_f(h1[reg]+bs1));
    }
  }
  __syncthreads();

  // hoist ffn2 A-fragments (wave reads only its own H strip)
  bf16x8 afrag[8];
  #pragma unroll
  for(int ks=0;ks<8;ks++) afrag[ks]=*(const bf16x8*)&sH[r0+mrow][ks*32+quad*8];

  f32x4 xac[8];
  #pragma unroll
  for(int i=0;i<8;i++) xac[i]=(f32x4){0.f,0.f,0.f,0.f};

  // ffn2: 8 chunks of 16 out cols (K=256)
  #pragma unroll
  for(int ch=0; ch<8; ch++){
    __syncthreads();
    for(int c=t;c<512;c+=256){ int row=c>>5, c8=(c&31)*8;
      *(uint4*)&sW[row*264+c8]=*(const uint4*)&W2t[(size_t)(ch*16+row)*256+c8]; }
    __syncthreads();
    #pragma unroll
    for(int ks=0;ks<8;ks++){
      bf16x8 b=*(const bf16x8*)&sW[mrow*264+ks*32+quad*8];
      xac[ch]=__builtin_amdgcn_mfma_f32_16x16x32_bf16(afrag[ks],b,xac[ch],0,0,0);
    }
  }

  // epilogue: +b2 +resid, row stats via quad shfl, X fp32 out, LN -> xn bf16
  #pragma unroll
  for(int reg=0;reg<4;reg++){
    int rowl=r0+quad*4+reg, rowg=tok0+rowl;
    float xv[8], s=0.f, sq=0.f;
    #pragma unroll
    for(int ch=0;ch<8;ch++){
      float v=xac[ch][reg]+b2[ch*16+mrow]+resid[(size_t)rowg*128+ch*16+mrow];
      xv[ch]=v; s+=v; sq+=v*v;
    }
    #pragma unroll
    for(int m=1;m<16;m<<=1){ s+=__shfl_xor(s,m); sq+=__shfl_xor(sq,m); }
    float mu=s*(1.f/128.f);
    float var=sq*(1.f/128.f)-mu*mu;
    float rstd=rsqrtf(var+1e-5f);
    #pragma unroll
    for(int ch=0;ch<8;ch++){
      int col=ch*16+mrow;
      Xout[(size_t)rowg*128+col]=xv[ch];
      sZ[rowl][col]=f2bf((xv[ch]-mu)*rstd*lnw[col]+lnb[col]);
    }
  }
  __syncthreads();
  for(int th=t;th<1024;th+=256){ int row=th>>4, seg=th&15;
    *(uint4*)&xn[(size_t)(tok0+row)*128+seg*8]=*(const uint4*)&sZ[row][seg*8]; }
}

// ---------------- retention + groupnorm + silu gate, fused ----------------
__global__ __launch_bounds__(256) void retmfma_kernel(
    const u16* __restrict__ Q, const u16* __restrict__ K,
    const u16* __restrict__ Vt, const u16* __restrict__ G,
    const float* __restrict__ gnw, const float* __restrict__ gnb,
    u16* __restrict__ Gated, float4 log2g)
{
  int idx = blockIdx.x;
  int bn = ((idx>>6)<<3) | (idx&7);
  int lt = (idx>>3)&7;
  int n = bn & 3, b = bn >> 2;
  float lg2g = (n==0)?log2g.x:(n==1)?log2g.y:(n==2)?log2g.z:log2g.w;
  __shared__ u16 sQ[64][40];
  __shared__ u16 sK[64][40];
  __shared__ u16 sVt[64][72];
  __shared__ u16 sS[64][72];
  int t = threadIdx.x, lane = t&63, wid = t>>6;
  int mrow = lane&15, quad = lane>>4;
  int r0 = wid*16;
  {
    int row = t>>2, c8 = (t&3)*8;
    *(uint4*)&sQ[row][c8] = *(const uint4*)&Q[((size_t)bn*512 + lt*64 + row)*32 + c8];
  }
  f32x4 oacc[4];
  #pragma unroll
  for(int cc=0;cc<4;cc++) oacc[cc] = (f32x4){0.f,0.f,0.f,0.f};
  float gp1 = exp2f(lg2g), gp2 = gp1*gp1, gp3 = gp2*gp1;
  float gpow[4] = {1.f, gp1, gp2, gp3};
  float gw[4], gb[4];
  #pragma unroll
  for(int cc=0;cc<4;cc++){ gw[cc]=gnw[n*64+cc*16+mrow]; gb[cc]=gnb[n*64+cc*16+mrow]; }
  __syncthreads();
  bf16x8 qa = *(const bf16x8*)&sQ[r0+mrow][quad*8];
  int rowl0 = lt*64 + r0 + quad*4;

  for(int mt=0; mt<=lt; mt++){
    if(mt) __syncthreads();
    {
      int row = t>>2, c8 = (t&3)*8;
      *(uint4*)&sK[row][c8] = *(const uint4*)&K[((size_t)bn*512 + mt*64 + row)*32 + c8];
      int vrow = t>>3, vc8 = (t&7)*8;
      *(uint4*)&sVt[vrow][vc8]    = *(const uint4*)&Vt[((size_t)bn*64 + vrow)*512    + mt*64 + vc8];
      *(uint4*)&sVt[vrow+32][vc8] = *(const uint4*)&Vt[((size_t)bn*64 + vrow+32)*512 + mt*64 + vc8];
    }
    __syncthreads();
    f32x4 sacc[4];
    #pragma unroll
    for(int cc=0;cc<4;cc++){
      bf16x8 bb = *(const bf16x8*)&sK[cc*16+mrow][quad*8];
      sacc[cc] = __builtin_amdgcn_mfma_f32_16x16x32_bf16(qa,bb,(f32x4){0.f,0.f,0.f,0.f},0,0,0);
    }
    #pragma unroll
    for(int cc=0;cc<4;cc++){
      int colm = mt*64 + cc*16 + mrow;
      int d0 = rowl0 - colm;
      float w0 = exp2f(lg2g*(float)d0);
      #pragma unroll
      for(int reg=0;reg<4;reg++){
        float w = (d0+reg>=0) ? w0*gpow[reg] : 0.f;
        sS[r0+quad*4+reg][cc*16+mrow] = f2bf(sacc[cc][reg]*w);
      }
    }
    __syncthreads();
    #pragma unroll
    for(int ks=0;ks<2;ks++){
      bf16x8 a = *(const bf16x8*)&sS[r0+mrow][ks*32+quad*8];
      #pragma unroll
      for(int cc=0;cc<4;cc++){
        bf16x8 bb = *(const bf16x8*)&sVt[cc*16+mrow][ks*32+quad*8];
        oacc[cc] = __builtin_amdgcn_mfma_f32_16x16x32_bf16(a,bb,oacc[cc],0,0,0);
      }
    }
  }

  __syncthreads();
  #pragma unroll
  for(int reg=0;reg<4;reg++){
    float s=0.f, sq=0.f;
    #pragma unroll
    for(int cc=0;cc<4;cc++){ float v=oacc[cc][reg]; s+=v; sq+=v*v; }
    #pragma unroll
    for(int m=1;m<16;m<<=1){ s+=__shfl_xor(s,m); sq+=__shfl_xor(sq,m); }
    float mu = s*(1.f/64.f);
    float var = sq*(1.f/64.f) - mu*mu;
    float rn = rsqrtf(var + 1e-5f);
    int rowl = r0 + quad*4 + reg;
    int l = lt*64 + rowl;
    size_t gbase = ((size_t)(b*512 + l))*256 + n*64;
    #pragma unroll
    for(int cc=0;cc<4;cc++){
      float gg = bf2f(G[gbase + cc*16+mrow]);
      float gate = gg/(1.f+expf(-gg));
      sS[rowl][cc*16+mrow] = f2bf(gate*((oacc[cc][reg]-mu)*rn*gw[cc] + gb[cc]));
    }
  }
  __syncthreads();
  for(int th=t; th<512; th+=256){
    int row=th>>3, seg=th&7;
    *(uint4*)&Gated[((size_t)(b*512 + lt*64 + row))*256 + n*64 + seg*8]
      = *(const uint4*)&sS[row][seg*8];
  }
}

// ---------------- decoder (MFMA): softmax(gelu(X@w1+b1)@w2+b2) ----------------
__global__ __launch_bounds__(256) void dec_kernel(
    const float* __restrict__ X, const u16* __restrict__ W1t,
    const float* __restrict__ b1, const float* __restrict__ w2,
    const float* __restrict__ b2, float* __restrict__ out)
{
  __shared__ u16 sA[64][136];
  __shared__ u16 sW[64][136];
  __shared__ float sH[64][68];
  __shared__ float sL[64*20];
  __shared__ float sw2[64*20];
  __shared__ float sb2[20];
  int t = threadIdx.x, lane = t&63, wid = t>>6;
  int mrow = lane&15, quad = lane>>4;
  int tok0 = blockIdx.x*64;

  for(int th=t; th<2048; th+=256){
    int row=th>>5, c4=(th&31)*4;
    float4 v = *(const float4*)&X[(size_t)(tok0+row)*128 + c4];
    ushort4 p; p.x=f2bf(v.x); p.y=f2bf(v.y); p.z=f2bf(v.z); p.w=f2bf(v.w);
    *(ushort4*)&sA[row][c4] = p;
  }
  for(int th=t; th<1024; th+=256){
    int row=th>>4, c8=(th&15)*8;
    *(uint4*)&sW[row][c8] = *(const uint4*)&W1t[(size_t)row*128 + c8];
  }
  for(int i=t;i<1280;i+=256) sw2[i]=w2[i];
  if(t<20) sb2[t]=b2[t];
  __syncthreads();

  int r0 = wid*16;
  f32x4 acc[4];
  #pragma unroll
  for(int cc=0;cc<4;cc++) acc[cc] = (f32x4){0.f,0.f,0.f,0.f};
  #pragma unroll
  for(int ks=0; ks<4; ks++){
    int koff = ks*32 + quad*8;
    bf16x8 a = *(const bf16x8*)&sA[r0+mrow][koff];
    #pragma unroll
    for(int cc=0; cc<4; cc++){
      bf16x8 b = *(const bf16x8*)&sW[cc*16+mrow][koff];
      acc[cc] = __builtin_amdgcn_mfma_f32_16x16x32_bf16(a,b,acc[cc],0,0,0);
    }
  }
  #pragma unroll
  for(int cc=0;cc<4;cc++){
    int col = cc*16 + mrow;
    float bb = b1[col];
    #pragma unroll
    for(int reg=0;reg<4;reg++){
      sH[r0 + quad*4 + reg][col] = gelu_f(acc[cc][reg] + bb);
    }
  }
  __syncthreads();

  for(int task=t; task<1280; task+=256){
    int tk = task/20, o = task - tk*20;
    float a = sb2[o];
    for(int k=0;k<64;k++) a += sH[tk][k]*sw2[k*20+o];
    sL[tk*20+o] = a;
  }
  __syncthreads();
  if(t < 64){
    float mx = -1e30f;
    #pragma unroll
    for(int o=0;o<20;o++) mx = fmaxf(mx, sL[t*20+o]);
    float sum = 0.f;
    float e[20];
    #pragma unroll
    for(int o=0;o<20;o++){ e[o]=expf(sL[t*20+o]-mx); sum += e[o]; }
    float inv = 1.f/sum;
    #pragma unroll
    for(int o=0;o<20;o++) sL[t*20+o] = e[o]*inv;
  }
  __syncthreads();
  for(int th=t; th<1280; th+=256){
    out[(size_t)tok0*20 + th] = sL[th];
  }
}

extern "C" void kernel_launch(void* const* d_in, const int* in_sizes, int n_in,
                              void* d_out, int out_size, void* d_ws, size_t ws_size,
                              hipStream_t stream) {
  (void)in_sizes; (void)n_in; (void)out_size; (void)ws_size;
  const float* x      = (const float*)d_in[0];
  const float* rem_w1 = (const float*)d_in[1];
  const float* rem_b1 = (const float*)d_in[2];
  const float* rem_w2 = (const float*)d_in[3];
  const float* rem_b2 = (const float*)d_in[4];
  const float* rem_w3 = (const float*)d_in[5];
  const float* rem_b3 = (const float*)d_in[6];
  const float* wq     = (const float*)d_in[7];
  const float* wk     = (const float*)d_in[8];
  const float* wv     = (const float*)d_in[9];
  const float* wg     = (const float*)d_in[10];
  const float* wo     = (const float*)d_in[11];
  const float* gn_w   = (const float*)d_in[12];
  const float* gn_b   = (const float*)d_in[13];
  const float* ln1_w  = (const float*)d_in[14];
  const float* ln1_b  = (const float*)d_in[15];
  const float* ln2_w  = (const float*)d_in[16];
  const float* ln2_b  = (const float*)d_in[17];
  const float* ffn_w1 = (const float*)d_in[18];
  const float* ffn_b1 = (const float*)d_in[19];
  const float* ffn_w2 = (const float*)d_in[20];
  const float* ffn_b2 = (const float*)d_in[21];
  const float* dec_w1 = (const float*)d_in[22];
  const float* dec_b1 = (const float*)d_in[23];
  const float* dec_w2 = (const float*)d_in[24];
  const float* dec_b2 = (const float*)d_in[25];
  float* outp = (float*)d_out;

  const size_t S128 = (size_t)BT*128;
  const size_t S256 = (size_t)BT*256;
  float* ws = (float*)d_ws;
  float* Xb = ws;                  // residual X        (S128 f32)
  float* Yr = Xb + S128;           // residual Y        (S128 f32)
  u16*  Qb16    = (u16*)(Yr + S128);     // Q bf16 head-layout (BT*32)
  u16*  Kb16    = Qb16 + (size_t)BT*32;
  u16*  Vt16    = Kb16 + (size_t)BT*32;  // V bf16 transposed (BT*64)
  u16*  XnBf    = Vt16 + (size_t)BT*64;  // LN out bf16   (S128)
  u16*  GBf     = XnBf + S128;           // G bf16        (S256)
  u16*  GatedBf = GBf + S256;            // gated        (S256)
  u16*  WtBf    = GatedBf + S256;        // bf16 weights  (804864 u16)

  double lgA = log(1.0/32.0), lgB = log(1.0/512.0);
  float4 l2g;
  {
    double g0 = 1.0 - exp(lgA + 0.0*(lgB-lgA)/3.0);
    double g1 = 1.0 - exp(lgA + 1.0*(lgB-lgA)/3.0);
    double g2 = 1.0 - exp(lgA + 2.0*(lgB-lgA)/3.0);
    double g3 = 1.0 - exp(lgA + 3.0*(lgB-lgA)/3.0);
    l2g.x = (float)(log(g0)/log(2.0));
    l2g.y = (float)(log(g1)/log(2.0));
    l2g.z = (float)(log(g2)/log(2.0));
    l2g.w = (float)(log(g3)/log(2.0));
  }

  wconv_kernel<<<3144, 256, 0, stream>>>(wq, wk, wv, wg, wo, ffn_w1, ffn_w2, dec_w1,
                                         rem_w2, rem_w3, WtBf);
  embed_kernel<<<BT/64, 256, 0, stream>>>(x, rem_w1, rem_b1, rem_b2, rem_b3,
                                          WtBf+794624, ln1_w, ln1_b, Xb, XnBf);

  for(int li=0; li<4; li++){
    u16* Wt_l = WtBf + (size_t)li*196608;
    const float* gnw_l = gn_w + (size_t)li*VDIM;
    const float* gnb_l = gn_b + (size_t)li*VDIM;
    const float* l2w = ln2_w + (size_t)li*HID, *l2b = ln2_b + (size_t)li*HID;
    const float* f1b = ffn_b1 + (size_t)li*FFND;
    const float* f2b = ffn_b2 + (size_t)li*HID;
    int nli = (li+1)&3;  // LN1 weights for next layer (unused result at li==3)
    const float* n1w = ln1_w + (size_t)nli*HID, *n1b = ln1_b + (size_t)nli*HID;

    qkvg_kernel<<<dim3(BT/64,2), 256, 0, stream>>>(XnBf, Wt_l, Qb16, Kb16, Vt16, GBf);
    retmfma_kernel<<<2048, 256, 0, stream>>>(Qb16, Kb16, Vt16, GBf, gnw_l, gnb_l, GatedBf, l2g);
    mgemm_kernel<256,1><<<dim3(BT/64,1), 256, 0, stream>>>(
        GatedBf, Wt_l+98304, nullptr, Xb, Yr, nullptr, l2w, l2b, XnBf);      // Y + LN2
    ffn_kernel<<<BT/64, 256, 0, stream>>>(
        XnBf, Wt_l+131072, f1b, Wt_l+163840, f2b, Yr, Xb, n1w, n1b, XnBf);   // X + LN1(next)
  }

  dec_kernel<<<BT/64, 256, 0, stream>>>(Xb, WtBf+786432, dec_b1, dec_w2, dec_b2, outp);
}

// Round 8
// 579.537 us; speedup vs baseline: 14.4833x; 1.0593x over previous
//
#include <hip/hip_runtime.h>
#include <math.h>
#include <cmath>

#define SEQ   512
#define NBATCH 64
#define BT    32768      // 64*512 tokens
#define HID   128
#define NHEAD 4
#define HD    32
#define VHD   64
#define VDIM  256
#define FFND  256

typedef __attribute__((ext_vector_type(8))) short bf16x8;
typedef __attribute__((ext_vector_type(4))) float f32x4;
typedef unsigned short u16;

__device__ __forceinline__ float gelu_f(float x){ return 0.5f*x*(1.f+erff(x*0.70710678118f)); }

__device__ __forceinline__ u16 f2bf(float f){
  union{float f; unsigned u;} v; v.f = f;
  unsigned r = v.u + 0x7FFF + ((v.u>>16)&1);
  return (u16)(r>>16);
}
__device__ __forceinline__ float bf2f(u16 u){
  union{unsigned u; float f;} v; v.u = ((unsigned)u)<<16; return v.f;
}

// ---------------- weight convert + transpose -> bf16 Wt[N][K] ----------------
// per-layer region (196608 u16): [0)qkvg 768x128  [98304)wo 128x256  [131072)f1 256x128  [163840)f2 128x256
// tail: 786432 dec_w1t 64x128 (8192); 794624 rem_w2t 64x32 (2048); 796672 rem_w3t 128x64 (8192). total 804864
__global__ __launch_bounds__(256) void wconv_kernel(
    const float* __restrict__ wq, const float* __restrict__ wk,
    const float* __restrict__ wv, const float* __restrict__ wg,
    const float* __restrict__ wo, const float* __restrict__ f1,
    const float* __restrict__ f2, const float* __restrict__ dw1,
    const float* __restrict__ w2e, const float* __restrict__ w3e,
    u16* __restrict__ Wt)
{
  int idx = blockIdx.x*256 + threadIdx.x;   // 0..804863
  if(idx >= 786432){
    int q = idx - 786432;
    if(q < 8192){ int col=q>>7, h=q&127; Wt[idx]=f2bf(dw1[h*64+col]); }
    else if(q < 10240){ int p=q-8192; int row=p>>5, col=p&31; Wt[idx]=f2bf(w2e[col*64+row]); }
    else { int p=q-10240; int row=p>>6, col=p&63; Wt[idx]=f2bf(w3e[col*128+row]); }
    return;
  }
  int layer = idx / 196608;
  int r = idx - layer*196608;
  u16* W = Wt + (size_t)layer*196608;
  const float* wq_l = wq + (size_t)layer*16384;
  const float* wk_l = wk + (size_t)layer*16384;
  const float* wv_l = wv + (size_t)layer*32768;
  const float* wg_l = wg + (size_t)layer*32768;
  const float* wo_l = wo + (size_t)layer*32768;
  const float* f1_l = f1 + (size_t)layer*32768;
  const float* f2_l = f2 + (size_t)layer*32768;
  float v;
  if(r < 98304){
    int col = r>>7, h = r&127;
    if(col<128){ int n=col>>5, d=col&31; v = wq_l[(n*128+h)*32+d]; }
    else if(col<256){ int c=col-128, n=c>>5, d=c&31; v = wk_l[(n*128+h)*32+d]; }
    else if(col<512){ int c=col-256, n=c>>6, j=c&63; v = wv_l[(n*128+h)*64+j]; }
    else { int p=col-512; v = wg_l[h*256+p]; }
    W[r] = f2bf(v);
  } else if(r < 131072){
    int q = r-98304; int col=q>>8, k=q&255;
    W[r] = f2bf(wo_l[k*128+col]);
  } else if(r < 163840){
    int q = r-131072; int col=q>>7, h=q&127;
    W[r] = f2bf(f1_l[h*256+col]);
  } else {
    int q = r-163840; int col=q>>8, k=q&255;
    W[r] = f2bf(f2_l[k*128+col]);
  }
}

// ---------------- embed (MFMA) + fused layer-0 LN1 ----------------
__global__ __launch_bounds__(256) void embed_kernel(
    const float* __restrict__ x,
    const float* __restrict__ w1, const float* __restrict__ b1,
    const float* __restrict__ b2, const float* __restrict__ b3,
    const u16* __restrict__ W23t,     // w2t[64][32] at 0, w3t[128][64] at 2048
    const float* __restrict__ lnw, const float* __restrict__ lnb,
    float* __restrict__ X, u16* __restrict__ xn)
{
  __shared__ float sx[64][6];
  __shared__ float sw1[160], sb1[32], sb2[64], sb3[128];
  __shared__ u16 big[18944];
  int t=threadIdx.x, lane=t&63, wid=t>>6, mrow=lane&15, quad=lane>>4, r0=wid*16;
  int tok0=blockIdx.x*64;

  for(int i=t;i<320;i+=256) sx[i/5][i%5]=x[(size_t)tok0*5+i];
  for(int i=t;i<160;i+=256) sw1[i]=w1[i];
  if(t<32) sb1[t]=b1[t];
  if(t<64) sb2[t]=b2[t];
  if(t<128) sb3[t]=b3[t];
  for(int c=t;c<256;c+=256){ int row=c>>2, c8=(c&3)*8;
    *(uint4*)&big[2560+row*40+c8]=*(const uint4*)&W23t[row*32+c8]; }
  for(int c=t;c<1024;c+=256){ int row=c>>3, c8=(c&7)*8;
    *(uint4*)&big[9728+row*72+c8]=*(const uint4*)&W23t[2048+row*64+c8]; }
  __syncthreads();

  for(int task=t; task<2048; task+=256){
    int tok=task>>5, j=task&31;
    float a=sb1[j];
    #pragma unroll
    for(int i=0;i<5;i++) a+=sx[tok][i]*sw1[i*32+j];
    big[tok*40+j]=f2bf(gelu_f(a));
  }
  __syncthreads();

  f32x4 h2[4];
  #pragma unroll
  for(int cc=0;cc<4;cc++) h2[cc]=(f32x4){0.f,0.f,0.f,0.f};
  {
    bf16x8 a=*(const bf16x8*)&big[(r0+mrow)*40+quad*8];
    #pragma unroll
    for(int cc=0;cc<4;cc++){
      bf16x8 b=*(const bf16x8*)&big[2560+(cc*16+mrow)*40+quad*8];
      h2[cc]=__builtin_amdgcn_mfma_f32_16x16x32_bf16(a,b,h2[cc],0,0,0);
    }
  }
  #pragma unroll
  for(int cc=0;cc<4;cc++){
    float bs=sb2[cc*16+mrow];
    #pragma unroll
    for(int reg=0;reg<4;reg++)
      big[5120+(r0+quad*4+reg)*72+cc*16+mrow]=f2bf(gelu_f(h2[cc][reg]+bs));
  }
  __syncthreads();

  f32x4 xac[8];
  #pragma unroll
  for(int cc=0;cc<8;cc++) xac[cc]=(f32x4){0.f,0.f,0.f,0.f};
  #pragma unroll
  for(int ks=0;ks<2;ks++){
    bf16x8 a=*(const bf16x8*)&big[5120+(r0+mrow)*72+ks*32+quad*8];
    #pragma unroll
    for(int cc=0;cc<8;cc++){
      bf16x8 b=*(const bf16x8*)&big[9728+(cc*16+mrow)*72+ks*32+quad*8];
      xac[cc]=__builtin_amdgcn_mfma_f32_16x16x32_bf16(a,b,xac[cc],0,0,0);
    }
  }
  __syncthreads();

  #pragma unroll
  for(int reg=0;reg<4;reg++){
    int rowl=r0+quad*4+reg, rowg=tok0+rowl;
    float xv[8], s=0.f, sq=0.f;
    #pragma unroll
    for(int cc=0;cc<8;cc++){
      float v=gelu_f(xac[cc][reg]+sb3[cc*16+mrow]);
      xv[cc]=v; s+=v; sq+=v*v;
    }
    #pragma unroll
    for(int m=1;m<16;m<<=1){ s+=__shfl_xor(s,m); sq+=__shfl_xor(sq,m); }
    float mu=s*(1.f/128.f);
    float var=sq*(1.f/128.f)-mu*mu;
    float rstd=rsqrtf(var+1e-5f);
    #pragma unroll
    for(int cc=0;cc<8;cc++){
      int col=cc*16+mrow;
      X[(size_t)rowg*128+col]=xv[cc];
      big[rowl*136+col]=f2bf((xv[cc]-mu)*rstd*lnw[col]+lnb[col]);
    }
  }
  __syncthreads();
  for(int th=t; th<1024; th+=256){
    int row=th>>4, seg=th&15;
    *(uint4*)&xn[(size_t)(tok0+row)*128+seg*8]=*(const uint4*)&big[row*136+seg*8];
  }
}

// ---------------- qkvg: block = 64 tokens, y-half x 3 chunks of 128 cols ----------------
__global__ __launch_bounds__(256) void qkvg_kernel(
    const u16* __restrict__ A, const u16* __restrict__ Wt,
    u16* __restrict__ Q, u16* __restrict__ K,
    u16* __restrict__ Vt, u16* __restrict__ G)
{
  __shared__ u16 sA[64][136];
  __shared__ u16 sW[128][136];
  u16* stg = &sW[0][0];
  int t = threadIdx.x, lane = t&63, wid = t>>6;
  int mrow = lane&15, quad = lane>>4;
  int r0 = (wid>>1)*32, c0 = (wid&1)*64;
  int tok0 = blockIdx.x*64;
  int b = tok0>>9, l0 = tok0&511;

  for(int c=t;c<1024;c+=256){ int row=c>>4, col8=(c&15)*8;
    *(uint4*)&sA[row][col8] = *(const uint4*)&A[(size_t)(tok0+row)*128 + col8]; }

  for(int ch=0; ch<3; ch++){
    int nc = blockIdx.y*3 + ch;   // 0..5
    int n0 = nc*128;
    __syncthreads();
    for(int c=t;c<2048;c+=256){ int row=c>>4, col8=(c&15)*8;
      *(uint4*)&sW[row][col8] = *(const uint4*)&Wt[(size_t)(n0+row)*128 + col8]; }
    __syncthreads();

    f32x4 acc[2][4];
    #pragma unroll
    for(int rr=0;rr<2;rr++)
      #pragma unroll
      for(int cc=0;cc<4;cc++) acc[rr][cc] = (f32x4){0.f,0.f,0.f,0.f};
    #pragma unroll
    for(int ks=0; ks<4; ks++){
      int koff = ks*32 + quad*8;
      bf16x8 a0 = *(const bf16x8*)&sA[r0+mrow][koff];
      bf16x8 a1 = *(const bf16x8*)&sA[r0+16+mrow][koff];
      #pragma unroll
      for(int cc=0; cc<4; cc++){
        bf16x8 bb = *(const bf16x8*)&sW[c0+cc*16+mrow][koff];
        acc[0][cc] = __builtin_amdgcn_mfma_f32_16x16x32_bf16(a0,bb,acc[0][cc],0,0,0);
        acc[1][cc] = __builtin_amdgcn_mfma_f32_16x16x32_bf16(a1,bb,acc[1][cc],0,0,0);
      }
    }
    __syncthreads();

    if(nc < 2){
      bool isK = (nc==1);
      #pragma unroll
      for(int cc=0;cc<4;cc++){
        int colc = c0 + cc*16 + mrow;
        int i = (colc&31)>>1;
        float log2bs = log2f(((float)i + 12.8f)*(1.f/44.8f));
        float invf   = exp2f(-(float)i * (13.28771238f/16.f));
        #pragma unroll
        for(int rr=0;rr<2;rr++){
          #pragma unroll
          for(int reg=0;reg<4;reg++){
            int rowl = r0 + rr*16 + quad*4 + reg;
            int l = l0 + rowl;
            float v = acc[rr][cc][reg];
            float partner = __shfl_xor(v, 1);
            float e  = log2bs * (float)l * (1.f/512.f);
            float sc = exp2f(isK ? -e : e);
            float ang = (float)l * invf;
            float cs = cosf(ang)*sc, sn = sinf(ang)*sc;
            float o = (colc&1) ? (v*cs + partner*sn) : (v*cs - partner*sn);
            stg[rowl*136 + colc] = f2bf(o);
          }
        }
      }
      __syncthreads();
      u16* O = isK ? K : Q;
      for(int th=t; th<1024; th+=256){
        int row=th>>4, n=(th>>2)&3, seg=th&3;
        *(uint4*)&O[(((size_t)(b*4+n)*512) + (l0+row))*32 + seg*8]
          = *(const uint4*)&stg[row*136 + n*32 + seg*8];
      }
    } else if(nc < 4){
      #pragma unroll
      for(int cc=0;cc<4;cc++){
        int colc = c0 + cc*16 + mrow;
        #pragma unroll
        for(int rr=0;rr<2;rr++){
          #pragma unroll
          for(int reg=0;reg<4;reg++){
            int rowl = r0 + rr*16 + quad*4 + reg;
            stg[colc*72 + rowl] = f2bf(acc[rr][cc][reg]);
          }
        }
      }
      __syncthreads();
      int jbase = (nc-2)*128;
      for(int th=t; th<1024; th+=256){
        int row=th>>3, seg=th&7;
        int jg = jbase + row; int n = jg>>6, j = jg&63;
        *(uint4*)&Vt[(((size_t)(b*4+n)*64) + j)*512 + l0 + seg*8]
          = *(const uint4*)&stg[row*72 + seg*8];
      }
    } else {
      #pragma unroll
      for(int cc=0;cc<4;cc++){
        int colc = c0 + cc*16 + mrow;
        #pragma unroll
        for(int rr=0;rr<2;rr++){
          #pragma unroll
          for(int reg=0;reg<4;reg++){
            int rowl = r0 + rr*16 + quad*4 + reg;
            stg[rowl*136 + colc] = f2bf(acc[rr][cc][reg]);
          }
        }
      }
      __syncthreads();
      int gc0 = (nc-4)*128;
      for(int th=t; th<1024; th+=256){
        int row=th>>4, seg=th&15;
        *(uint4*)&G[((size_t)(tok0+row))*256 + gc0 + seg*8]
          = *(const uint4*)&stg[row*136 + seg*8];
      }
    }
  }
}

// ---------------- fused MLP: Gated -> wo+resid -> Y(regs) -> LN2 -> Z -> ffn1 -> H -> ffn2+Y -> X + LN1(next) ----------------
// Wo[128][256], W1t[256][128], W2t[128][256] bf16. One block = 64 tokens.
__global__ __launch_bounds__(256) void mlp_kernel(
    const u16* __restrict__ Gated, const u16* __restrict__ Wo,
    const u16* __restrict__ W1t, const float* __restrict__ b1,
    const u16* __restrict__ W2t, const float* __restrict__ b2,
    const float* __restrict__ Xin,
    const float* __restrict__ ln2w, const float* __restrict__ ln2b,
    const float* __restrict__ ln1w, const float* __restrict__ ln1b,
    float* __restrict__ Xout, u16* __restrict__ xn)
{
  __shared__ u16 sG[64*264];     // 33.8 KB: Gated; then H; then X-f32 staging (as float[64*132])
  __shared__ u16 sZ[64*136];     // 17.4 KB: Z bf16; then xn stage
  __shared__ u16 sW[2][4352];    // 17.4 KB: double-buffered weight chunks
  int t=threadIdx.x, lane=t&63, wid=t>>6, mrow=lane&15, quad=lane>>4, r0=wid*16;
  int tok0=blockIdx.x*64;

  // stage Gated + preload wo chunk 0
  for(int c=t;c<2048;c+=256){ int row=c>>5, c8=(c&31)*8;
    *(uint4*)&sG[row*264+c8]=*(const uint4*)&Gated[(size_t)(tok0+row)*256+c8]; }
  for(int c=t;c<512;c+=256){ int row=c>>5, c8=(c&31)*8;
    *(uint4*)&sW[0][row*264+c8]=*(const uint4*)&Wo[(size_t)row*256+c8]; }
  __syncthreads();

  bf16x8 gfrag[8];
  #pragma unroll
  for(int ks=0;ks<8;ks++) gfrag[ks]=*(const bf16x8*)&sG[(r0+mrow)*264+ks*32+quad*8];

  // ---- wo GEMM: K=256, N=128 in 8 chunks of 16 cols, double-buffered
  f32x4 yac[8];
  #pragma unroll
  for(int ch=0;ch<8;ch++) yac[ch]=(f32x4){0.f,0.f,0.f,0.f};
  #pragma unroll
  for(int ch=0; ch<8; ch++){
    if(ch) __syncthreads();
    if(ch<7){
      for(int c=t;c<512;c+=256){ int row=c>>5, c8=(c&31)*8;
        *(uint4*)&sW[(ch+1)&1][row*264+c8]=*(const uint4*)&Wo[(size_t)((ch+1)*16+row)*256+c8]; }
    }
    const u16* wb = sW[ch&1];
    #pragma unroll
    for(int ks=0;ks<8;ks++){
      bf16x8 b=*(const bf16x8*)&wb[mrow*264+ks*32+quad*8];
      yac[ch]=__builtin_amdgcn_mfma_f32_16x16x32_bf16(gfrag[ks],b,yac[ch],0,0,0);
    }
  }

  // ---- Y = yac + Xin (kept in regs); LN2 -> Z bf16 in sZ
  float yv[8][4];
  #pragma unroll
  for(int reg=0;reg<4;reg++){
    int rowl=r0+quad*4+reg, rowg=tok0+rowl;
    float s=0.f, sq=0.f;
    #pragma unroll
    for(int ch=0;ch<8;ch++){
      float v=yac[ch][reg]+Xin[(size_t)rowg*128+ch*16+mrow];
      yv[ch][reg]=v; s+=v; sq+=v*v;
    }
    #pragma unroll
    for(int m=1;m<16;m<<=1){ s+=__shfl_xor(s,m); sq+=__shfl_xor(sq,m); }
    float mu=s*(1.f/128.f);
    float var=sq*(1.f/128.f)-mu*mu;
    float rstd=rsqrtf(var+1e-5f);
    #pragma unroll
    for(int ch=0;ch<8;ch++){
      int col=ch*16+mrow;
      sZ[rowl*136+col]=f2bf((yv[ch][reg]-mu)*rstd*ln2w[col]+ln2b[col]);
    }
  }
  __syncthreads();

  // hoist Z A-frags (own strip rows)
  bf16x8 az[4];
  #pragma unroll
  for(int ks=0;ks<4;ks++) az[ks]=*(const bf16x8*)&sZ[(r0+mrow)*136+ks*32+quad*8];

  // preload ffn1 chunk 0
  for(int c=t;c<512;c+=256){ int row=c>>4, c8=(c&15)*8;
    *(uint4*)&sW[0][row*136+c8]=*(const uint4*)&W1t[(size_t)row*128+c8]; }
  __syncthreads();

  // ---- ffn1: K=128, N=256 in 8 chunks of 32 cols; H -> sG region
  #pragma unroll
  for(int ch=0; ch<8; ch++){
    if(ch) __syncthreads();
    if(ch<7){
      for(int c=t;c<512;c+=256){ int row=c>>4, c8=(c&15)*8;
        *(uint4*)&sW[(ch+1)&1][row*136+c8]=*(const uint4*)&W1t[(size_t)((ch+1)*32+row)*128+c8]; }
    }
    const u16* wb = sW[ch&1];
    f32x4 h0=(f32x4){0.f,0.f,0.f,0.f}, h1=(f32x4){0.f,0.f,0.f,0.f};
    #pragma unroll
    for(int ks=0;ks<4;ks++){
      bf16x8 bb0=*(const bf16x8*)&wb[mrow*136+ks*32+quad*8];
      bf16x8 bb1=*(const bf16x8*)&wb[(16+mrow)*136+ks*32+quad*8];
      h0=__builtin_amdgcn_mfma_f32_16x16x32_bf16(az[ks],bb0,h0,0,0,0);
      h1=__builtin_amdgcn_mfma_f32_16x16x32_bf16(az[ks],bb1,h1,0,0,0);
    }
    float bs0=b1[ch*32+mrow], bs1=b1[ch*32+16+mrow];
    #pragma unroll
    for(int reg=0;reg<4;reg++){
      int rowl=r0+quad*4+reg;
      sG[rowl*264+ch*32+mrow]    = f2bf(gelu_f(h0[reg]+bs0));
      sG[rowl*264+ch*32+16+mrow] = f2bf(gelu_f(h1[reg]+bs1));
    }
  }
  __syncthreads();

  // hoist H A-frags
  bf16x8 hfrag[8];
  #pragma unroll
  for(int ks=0;ks<8;ks++) hfrag[ks]=*(const bf16x8*)&sG[(r0+mrow)*264+ks*32+quad*8];

  // preload ffn2 chunk 0
  for(int c=t;c<512;c+=256){ int row=c>>5, c8=(c&31)*8;
    *(uint4*)&sW[0][row*264+c8]=*(const uint4*)&W2t[(size_t)row*256+c8]; }
  __syncthreads();

  // ---- ffn2: K=256, N=128 in 8 chunks of 16 cols
  f32x4 xac[8];
  #pragma unroll
  for(int ch=0;ch<8;ch++) xac[ch]=(f32x4){0.f,0.f,0.f,0.f};
  #pragma unroll
  for(int ch=0; ch<8; ch++){
    if(ch) __syncthreads();
    if(ch<7){
      for(int c=t;c<512;c+=256){ int row=c>>5, c8=(c&31)*8;
        *(uint4*)&sW[(ch+1)&1][row*264+c8]=*(const uint4*)&W2t[(size_t)((ch+1)*16+row)*256+c8]; }
    }
    const u16* wb = sW[ch&1];
    #pragma unroll
    for(int ks=0;ks<8;ks++){
      bf16x8 b=*(const bf16x8*)&wb[mrow*264+ks*32+quad*8];
      xac[ch]=__builtin_amdgcn_mfma_f32_16x16x32_bf16(hfrag[ks],b,xac[ch],0,0,0);
    }
  }
  __syncthreads();   // all mfma done; sG reusable as fp32 staging

  // ---- epilogue: X = xac + b2 + Y; LN1(next) -> xn
  float* fst = (float*)sG;   // [64][132]
  #pragma unroll
  for(int reg=0;reg<4;reg++){
    int rowl=r0+quad*4+reg;
    float xv[8], s=0.f, sq=0.f;
    #pragma unroll
    for(int ch=0;ch<8;ch++){
      float v=xac[ch][reg]+b2[ch*16+mrow]+yv[ch][reg];
      xv[ch]=v; s+=v; sq+=v*v;
    }
    #pragma unroll
    for(int m=1;m<16;m<<=1){ s+=__shfl_xor(s,m); sq+=__shfl_xor(sq,m); }
    float mu=s*(1.f/128.f);
    float var=sq*(1.f/128.f)-mu*mu;
    float rstd=rsqrtf(var+1e-5f);
    #pragma unroll
    for(int ch=0;ch<8;ch++){
      int col=ch*16+mrow;
      fst[rowl*132+col]=xv[ch];
      sZ[rowl*136+col]=f2bf((xv[ch]-mu)*rstd*ln1w[col]+ln1b[col]);
    }
  }
  __syncthreads();
  for(int th=t; th<2048; th+=256){
    int row=th>>5, c4=(th&31)*4;
    *(float4*)&Xout[(size_t)(tok0+row)*128+c4]=*(const float4*)&fst[row*132+c4];
  }
  for(int th=t; th<1024; th+=256){
    int row=th>>4, seg=th&15;
    *(uint4*)&xn[(size_t)(tok0+row)*128+seg*8]=*(const uint4*)&sZ[row*136+seg*8];
  }
}

// ---------------- retention + groupnorm + silu gate, fused ----------------
__global__ __launch_bounds__(256) void retmfma_kernel(
    const u16* __restrict__ Q, const u16* __restrict__ K,
    const u16* __restrict__ Vt, const u16* __restrict__ G,
    const float* __restrict__ gnw, const float* __restrict__ gnb,
    u16* __restrict__ Gated, float4 log2g)
{
  int idx = blockIdx.x;
  int bn = ((idx>>6)<<3) | (idx&7);
  int lt = (idx>>3)&7;
  int n = bn & 3, b = bn >> 2;
  float lg2g = (n==0)?log2g.x:(n==1)?log2g.y:(n==2)?log2g.z:log2g.w;
  __shared__ u16 sQ[64][40];
  __shared__ u16 sK[64][40];
  __shared__ u16 sVt[64][72];
  __shared__ u16 sS[64][72];
  int t = threadIdx.x, lane = t&63, wid = t>>6;
  int mrow = lane&15, quad = lane>>4;
  int r0 = wid*16;
  {
    int row = t>>2, c8 = (t&3)*8;
    *(uint4*)&sQ[row][c8] = *(const uint4*)&Q[((size_t)bn*512 + lt*64 + row)*32 + c8];
  }
  f32x4 oacc[4];
  #pragma unroll
  for(int cc=0;cc<4;cc++) oacc[cc] = (f32x4){0.f,0.f,0.f,0.f};
  float gp1 = exp2f(lg2g), gp2 = gp1*gp1, gp3 = gp2*gp1;
  float gpow[4] = {1.f, gp1, gp2, gp3};
  float gw[4], gb[4];
  #pragma unroll
  for(int cc=0;cc<4;cc++){ gw[cc]=gnw[n*64+cc*16+mrow]; gb[cc]=gnb[n*64+cc*16+mrow]; }
  __syncthreads();
  bf16x8 qa = *(const bf16x8*)&sQ[r0+mrow][quad*8];
  int rowl0 = lt*64 + r0 + quad*4;

  for(int mt=0; mt<=lt; mt++){
    if(mt) __syncthreads();
    {
      int row = t>>2, c8 = (t&3)*8;
      *(uint4*)&sK[row][c8] = *(const uint4*)&K[((size_t)bn*512 + mt*64 + row)*32 + c8];
      int vrow = t>>3, vc8 = (t&7)*8;
      *(uint4*)&sVt[vrow][vc8]    = *(const uint4*)&Vt[((size_t)bn*64 + vrow)*512    + mt*64 + vc8];
      *(uint4*)&sVt[vrow+32][vc8] = *(const uint4*)&Vt[((size_t)bn*64 + vrow+32)*512 + mt*64 + vc8];
    }
    __syncthreads();
    f32x4 sacc[4];
    #pragma unroll
    for(int cc=0;cc<4;cc++){
      bf16x8 bb = *(const bf16x8*)&sK[cc*16+mrow][quad*8];
      sacc[cc] = __builtin_amdgcn_mfma_f32_16x16x32_bf16(qa,bb,(f32x4){0.f,0.f,0.f,0.f},0,0,0);
    }
    #pragma unroll
    for(int cc=0;cc<4;cc++){
      int colm = mt*64 + cc*16 + mrow;
      int d0 = rowl0 - colm;
      float w0 = exp2f(lg2g*(float)d0);
      #pragma unroll
      for(int reg=0;reg<4;reg++){
        float w = (d0+reg>=0) ? w0*gpow[reg] : 0.f;
        sS[r0+quad*4+reg][cc*16+mrow] = f2bf(sacc[cc][reg]*w);
      }
    }
    __syncthreads();
    #pragma unroll
    for(int ks=0;ks<2;ks++){
      bf16x8 a = *(const bf16x8*)&sS[r0+mrow][ks*32+quad*8];
      #pragma unroll
      for(int cc=0;cc<4;cc++){
        bf16x8 bb = *(const bf16x8*)&sVt[cc*16+mrow][ks*32+quad*8];
        oacc[cc] = __builtin_amdgcn_mfma_f32_16x16x32_bf16(a,bb,oacc[cc],0,0,0);
      }
    }
  }

  __syncthreads();
  #pragma unroll
  for(int reg=0;reg<4;reg++){
    float s=0.f, sq=0.f;
    #pragma unroll
    for(int cc=0;cc<4;cc++){ float v=oacc[cc][reg]; s+=v; sq+=v*v; }
    #pragma unroll
    for(int m=1;m<16;m<<=1){ s+=__shfl_xor(s,m); sq+=__shfl_xor(sq,m); }
    float mu = s*(1.f/64.f);
    float var = sq*(1.f/64.f) - mu*mu;
    float rn = rsqrtf(var + 1e-5f);
    int rowl = r0 + quad*4 + reg;
    int l = lt*64 + rowl;
    size_t gbase = ((size_t)(b*512 + l))*256 + n*64;
    #pragma unroll
    for(int cc=0;cc<4;cc++){
      float gg = bf2f(G[gbase + cc*16+mrow]);
      float gate = gg/(1.f+expf(-gg));
      sS[rowl][cc*16+mrow] = f2bf(gate*((oacc[cc][reg]-mu)*rn*gw[cc] + gb[cc]));
    }
  }
  __syncthreads();
  for(int th=t; th<512; th+=256){
    int row=th>>3, seg=th&7;
    *(uint4*)&Gated[((size_t)(b*512 + lt*64 + row))*256 + n*64 + seg*8]
      = *(const uint4*)&sS[row][seg*8];
  }
}

// ---------------- decoder (MFMA): softmax(gelu(X@w1+b1)@w2+b2) ----------------
__global__ __launch_bounds__(256) void dec_kernel(
    const float* __restrict__ X, const u16* __restrict__ W1t,
    const float* __restrict__ b1, const float* __restrict__ w2,
    const float* __restrict__ b2, float* __restrict__ out)
{
  __shared__ u16 sA[64][136];
  __shared__ u16 sW[64][136];
  __shared__ float sH[64][68];
  __shared__ float sL[64*20];
  __shared__ float sw2[64*20];
  __shared__ float sb2[20];
  int t = threadIdx.x, lane = t&63, wid = t>>6;
  int mrow = lane&15, quad = lane>>4;
  int tok0 = blockIdx.x*64;

  for(int th=t; th<2048; th+=256){
    int row=th>>5, c4=(th&31)*4;
    float4 v = *(const float4*)&X[(size_t)(tok0+row)*128 + c4];
    ushort4 p; p.x=f2bf(v.x); p.y=f2bf(v.y); p.z=f2bf(v.z); p.w=f2bf(v.w);
    *(ushort4*)&sA[row][c4] = p;
  }
  for(int th=t; th<1024; th+=256){
    int row=th>>4, c8=(th&15)*8;
    *(uint4*)&sW[row][c8] = *(const uint4*)&W1t[(size_t)row*128 + c8];
  }
  for(int i=t;i<1280;i+=256) sw2[i]=w2[i];
  if(t<20) sb2[t]=b2[t];
  __syncthreads();

  int r0 = wid*16;
  f32x4 acc[4];
  #pragma unroll
  for(int cc=0;cc<4;cc++) acc[cc] = (f32x4){0.f,0.f,0.f,0.f};
  #pragma unroll
  for(int ks=0; ks<4; ks++){
    int koff = ks*32 + quad*8;
    bf16x8 a = *(const bf16x8*)&sA[r0+mrow][koff];
    #pragma unroll
    for(int cc=0; cc<4; cc++){
      bf16x8 b = *(const bf16x8*)&sW[cc*16+mrow][koff];
      acc[cc] = __builtin_amdgcn_mfma_f32_16x16x32_bf16(a,b,acc[cc],0,0,0);
    }
  }
  #pragma unroll
  for(int cc=0;cc<4;cc++){
    int col = cc*16 + mrow;
    float bb = b1[col];
    #pragma unroll
    for(int reg=0;reg<4;reg++){
      sH[r0 + quad*4 + reg][col] = gelu_f(acc[cc][reg] + bb);
    }
  }
  __syncthreads();

  for(int task=t; task<1280; task+=256){
    int tk = task/20, o = task - tk*20;
    float a = sb2[o];
    for(int k=0;k<64;k++) a += sH[tk][k]*sw2[k*20+o];
    sL[tk*20+o] = a;
  }
  __syncthreads();
  if(t < 64){
    float mx = -1e30f;
    #pragma unroll
    for(int o=0;o<20;o++) mx = fmaxf(mx, sL[t*20+o]);
    float sum = 0.f;
    float e[20];
    #pragma unroll
    for(int o=0;o<20;o++){ e[o]=expf(sL[t*20+o]-mx); sum += e[o]; }
    float inv = 1.f/sum;
    #pragma unroll
    for(int o=0;o<20;o++) sL[t*20+o] = e[o]*inv;
  }
  __syncthreads();
  for(int th=t; th<1280; th+=256){
    out[(size_t)tok0*20 + th] = sL[th];
  }
}

extern "C" void kernel_launch(void* const* d_in, const int* in_sizes, int n_in,
                              void* d_out, int out_size, void* d_ws, size_t ws_size,
                              hipStream_t stream) {
  (void)in_sizes; (void)n_in; (void)out_size; (void)ws_size;
  const float* x      = (const float*)d_in[0];
  const float* rem_w1 = (const float*)d_in[1];
  const float* rem_b1 = (const float*)d_in[2];
  const float* rem_w2 = (const float*)d_in[3];
  const float* rem_b2 = (const float*)d_in[4];
  const float* rem_w3 = (const float*)d_in[5];
  const float* rem_b3 = (const float*)d_in[6];
  const float* wq     = (const float*)d_in[7];
  const float* wk     = (const float*)d_in[8];
  const float* wv     = (const float*)d_in[9];
  const float* wg     = (const float*)d_in[10];
  const float* wo     = (const float*)d_in[11];
  const float* gn_w   = (const float*)d_in[12];
  const float* gn_b   = (const float*)d_in[13];
  const float* ln1_w  = (const float*)d_in[14];
  const float* ln1_b  = (const float*)d_in[15];
  const float* ln2_w  = (const float*)d_in[16];
  const float* ln2_b  = (const float*)d_in[17];
  const float* ffn_w1 = (const float*)d_in[18];
  const float* ffn_b1 = (const float*)d_in[19];
  const float* ffn_w2 = (const float*)d_in[20];
  const float* ffn_b2 = (const float*)d_in[21];
  const float* dec_w1 = (const float*)d_in[22];
  const float* dec_b1 = (const float*)d_in[23];
  const float* dec_w2 = (const float*)d_in[24];
  const float* dec_b2 = (const float*)d_in[25];
  float* outp = (float*)d_out;

  const size_t S128 = (size_t)BT*128;
  const size_t S256 = (size_t)BT*256;
  float* ws = (float*)d_ws;
  float* Xb = ws;                  // residual X        (S128 f32)
  u16*  Qb16    = (u16*)(Xb + S128);     // Q bf16 head-layout (BT*32)
  u16*  Kb16    = Qb16 + (size_t)BT*32;
  u16*  Vt16    = Kb16 + (size_t)BT*32;  // V bf16 transposed (BT*64)
  u16*  XnBf    = Vt16 + (size_t)BT*64;  // LN out bf16   (S128)
  u16*  GBf     = XnBf + S128;           // G bf16        (S256)
  u16*  GatedBf = GBf + S256;            // gated        (S256)
  u16*  WtBf    = GatedBf + S256;        // bf16 weights  (804864 u16)

  double lgA = log(1.0/32.0), lgB = log(1.0/512.0);
  float4 l2g;
  {
    double g0 = 1.0 - exp(lgA + 0.0*(lgB-lgA)/3.0);
    double g1 = 1.0 - exp(lgA + 1.0*(lgB-lgA)/3.0);
    double g2 = 1.0 - exp(lgA + 2.0*(lgB-lgA)/3.0);
    double g3 = 1.0 - exp(lgA + 3.0*(lgB-lgA)/3.0);
    l2g.x = (float)(log(g0)/log(2.0));
    l2g.y = (float)(log(g1)/log(2.0));
    l2g.z = (float)(log(g2)/log(2.0));
    l2g.w = (float)(log(g3)/log(2.0));
  }

  wconv_kernel<<<3144, 256, 0, stream>>>(wq, wk, wv, wg, wo, ffn_w1, ffn_w2, dec_w1,
                                         rem_w2, rem_w3, WtBf);
  embed_kernel<<<BT/64, 256, 0, stream>>>(x, rem_w1, rem_b1, rem_b2, rem_b3,
                                          WtBf+794624, ln1_w, ln1_b, Xb, XnBf);

  for(int li=0; li<4; li++){
    u16* Wt_l = WtBf + (size_t)li*196608;
    const float* gnw_l = gn_w + (size_t)li*VDIM;
    const float* gnb_l = gn_b + (size_t)li*VDIM;
    const float* l2w = ln2_w + (size_t)li*HID, *l2b = ln2_b + (size_t)li*HID;
    const float* f1b = ffn_b1 + (size_t)li*FFND;
    const float* f2b = ffn_b2 + (size_t)li*HID;
    int nli = (li+1)&3;  // LN1 weights for next layer (unused result at li==3)
    const float* n1w = ln1_w + (size_t)nli*HID, *n1b = ln1_b + (size_t)nli*HID;

    qkvg_kernel<<<dim3(BT/64,2), 256, 0, stream>>>(XnBf, Wt_l, Qb16, Kb16, Vt16, GBf);
    retmfma_kernel<<<2048, 256, 0, stream>>>(Qb16, Kb16, Vt16, GBf, gnw_l, gnb_l, GatedBf, l2g);
    mlp_kernel<<<BT/64, 256, 0, stream>>>(
        GatedBf, Wt_l+98304, Wt_l+131072, f1b, Wt_l+163840, f2b,
        Xb, l2w, l2b, n1w, n1b, Xb, XnBf);
  }

  dec_kernel<<<BT/64, 256, 0, stream>>>(Xb, WtBf+786432, dec_b1, dec_w2, dec_b2, outp);
}

// Round 9
// 558.884 us; speedup vs baseline: 15.0185x; 1.0370x over previous
//
#include <hip/hip_runtime.h>
#include <math.h>
#include <cmath>

#define SEQ   512
#define NBATCH 64
#define BT    32768      // 64*512 tokens
#define HID   128
#define NHEAD 4
#define HD    32
#define VHD   64
#define VDIM  256
#define FFND  256

typedef __attribute__((ext_vector_type(8))) short bf16x8;
typedef __attribute__((ext_vector_type(4))) float f32x4;
typedef unsigned short u16;

__device__ __forceinline__ float gelu_f(float x){ return 0.5f*x*(1.f+erff(x*0.70710678118f)); }

__device__ __forceinline__ u16 f2bf(float f){
  union{float f; unsigned u;} v; v.f = f;
  unsigned r = v.u + 0x7FFF + ((v.u>>16)&1);
  return (u16)(r>>16);
}
__device__ __forceinline__ float bf2f(u16 u){
  union{unsigned u; float f;} v; v.u = ((unsigned)u)<<16; return v.f;
}

// ---------------- weight convert + transpose -> bf16 Wt[N][K] ----------------
// per-layer region (196608 u16): [0)qkvg 768x128  [98304)wo 128x256  [131072)f1 256x128  [163840)f2 128x256
// tail: 786432 dec_w1t 64x128 (8192); 794624 rem_w2t 64x32 (2048); 796672 rem_w3t 128x64 (8192). total 804864
__global__ __launch_bounds__(256) void wconv_kernel(
    const float* __restrict__ wq, const float* __restrict__ wk,
    const float* __restrict__ wv, const float* __restrict__ wg,
    const float* __restrict__ wo, const float* __restrict__ f1,
    const float* __restrict__ f2, const float* __restrict__ dw1,
    const float* __restrict__ w2e, const float* __restrict__ w3e,
    u16* __restrict__ Wt)
{
  int idx = blockIdx.x*256 + threadIdx.x;   // 0..804863
  if(idx >= 786432){
    int q = idx - 786432;
    if(q < 8192){ int col=q>>7, h=q&127; Wt[idx]=f2bf(dw1[h*64+col]); }
    else if(q < 10240){ int p=q-8192; int row=p>>5, col=p&31; Wt[idx]=f2bf(w2e[col*64+row]); }
    else { int p=q-10240; int row=p>>6, col=p&63; Wt[idx]=f2bf(w3e[col*128+row]); }
    return;
  }
  int layer = idx / 196608;
  int r = idx - layer*196608;
  u16* W = Wt + (size_t)layer*196608;
  const float* wq_l = wq + (size_t)layer*16384;
  const float* wk_l = wk + (size_t)layer*16384;
  const float* wv_l = wv + (size_t)layer*32768;
  const float* wg_l = wg + (size_t)layer*32768;
  const float* wo_l = wo + (size_t)layer*32768;
  const float* f1_l = f1 + (size_t)layer*32768;
  const float* f2_l = f2 + (size_t)layer*32768;
  float v;
  if(r < 98304){
    int col = r>>7, h = r&127;
    if(col<128){ int n=col>>5, d=col&31; v = wq_l[(n*128+h)*32+d]; }
    else if(col<256){ int c=col-128, n=c>>5, d=c&31; v = wk_l[(n*128+h)*32+d]; }
    else if(col<512){ int c=col-256, n=c>>6, j=c&63; v = wv_l[(n*128+h)*64+j]; }
    else { int p=col-512; v = wg_l[h*256+p]; }
    W[r] = f2bf(v);
  } else if(r < 131072){
    int q = r-98304; int col=q>>8, k=q&255;
    W[r] = f2bf(wo_l[k*128+col]);
  } else if(r < 163840){
    int q = r-131072; int col=q>>7, h=q&127;
    W[r] = f2bf(f1_l[h*256+col]);
  } else {
    int q = r-163840; int col=q>>8, k=q&255;
    W[r] = f2bf(f2_l[k*128+col]);
  }
}

// ---------------- embed (MFMA) + fused layer-0 LN1 ----------------
__global__ __launch_bounds__(256) void embed_kernel(
    const float* __restrict__ x,
    const float* __restrict__ w1, const float* __restrict__ b1,
    const float* __restrict__ b2, const float* __restrict__ b3,
    const u16* __restrict__ W23t,     // w2t[64][32] at 0, w3t[128][64] at 2048
    const float* __restrict__ lnw, const float* __restrict__ lnb,
    float* __restrict__ X, u16* __restrict__ xn)
{
  __shared__ float sx[64][6];
  __shared__ float sw1[160], sb1[32], sb2[64], sb3[128];
  __shared__ u16 big[18944];
  int t=threadIdx.x, lane=t&63, wid=t>>6, mrow=lane&15, quad=lane>>4, r0=wid*16;
  int tok0=blockIdx.x*64;

  for(int i=t;i<320;i+=256) sx[i/5][i%5]=x[(size_t)tok0*5+i];
  for(int i=t;i<160;i+=256) sw1[i]=w1[i];
  if(t<32) sb1[t]=b1[t];
  if(t<64) sb2[t]=b2[t];
  if(t<128) sb3[t]=b3[t];
  for(int c=t;c<256;c+=256){ int row=c>>2, c8=(c&3)*8;
    *(uint4*)&big[2560+row*40+c8]=*(const uint4*)&W23t[row*32+c8]; }
  for(int c=t;c<1024;c+=256){ int row=c>>3, c8=(c&7)*8;
    *(uint4*)&big[9728+row*72+c8]=*(const uint4*)&W23t[2048+row*64+c8]; }
  __syncthreads();

  for(int task=t; task<2048; task+=256){
    int tok=task>>5, j=task&31;
    float a=sb1[j];
    #pragma unroll
    for(int i=0;i<5;i++) a+=sx[tok][i]*sw1[i*32+j];
    big[tok*40+j]=f2bf(gelu_f(a));
  }
  __syncthreads();

  f32x4 h2[4];
  #pragma unroll
  for(int cc=0;cc<4;cc++) h2[cc]=(f32x4){0.f,0.f,0.f,0.f};
  {
    bf16x8 a=*(const bf16x8*)&big[(r0+mrow)*40+quad*8];
    #pragma unroll
    for(int cc=0;cc<4;cc++){
      bf16x8 b=*(const bf16x8*)&big[2560+(cc*16+mrow)*40+quad*8];
      h2[cc]=__builtin_amdgcn_mfma_f32_16x16x32_bf16(a,b,h2[cc],0,0,0);
    }
  }
  #pragma unroll
  for(int cc=0;cc<4;cc++){
    float bs=sb2[cc*16+mrow];
    #pragma unroll
    for(int reg=0;reg<4;reg++)
      big[5120+(r0+quad*4+reg)*72+cc*16+mrow]=f2bf(gelu_f(h2[cc][reg]+bs));
  }
  __syncthreads();

  f32x4 xac[8];
  #pragma unroll
  for(int cc=0;cc<8;cc++) xac[cc]=(f32x4){0.f,0.f,0.f,0.f};
  #pragma unroll
  for(int ks=0;ks<2;ks++){
    bf16x8 a=*(const bf16x8*)&big[5120+(r0+mrow)*72+ks*32+quad*8];
    #pragma unroll
    for(int cc=0;cc<8;cc++){
      bf16x8 b=*(const bf16x8*)&big[9728+(cc*16+mrow)*72+ks*32+quad*8];
      xac[cc]=__builtin_amdgcn_mfma_f32_16x16x32_bf16(a,b,xac[cc],0,0,0);
    }
  }
  __syncthreads();

  #pragma unroll
  for(int reg=0;reg<4;reg++){
    int rowl=r0+quad*4+reg, rowg=tok0+rowl;
    float xv[8], s=0.f, sq=0.f;
    #pragma unroll
    for(int cc=0;cc<8;cc++){
      float v=gelu_f(xac[cc][reg]+sb3[cc*16+mrow]);
      xv[cc]=v; s+=v; sq+=v*v;
    }
    #pragma unroll
    for(int m=1;m<16;m<<=1){ s+=__shfl_xor(s,m); sq+=__shfl_xor(sq,m); }
    float mu=s*(1.f/128.f);
    float var=sq*(1.f/128.f)-mu*mu;
    float rstd=rsqrtf(var+1e-5f);
    #pragma unroll
    for(int cc=0;cc<8;cc++){
      int col=cc*16+mrow;
      X[(size_t)rowg*128+col]=xv[cc];
      big[rowl*136+col]=f2bf((xv[cc]-mu)*rstd*lnw[col]+lnb[col]);
    }
  }
  __syncthreads();
  for(int th=t; th<1024; th+=256){
    int row=th>>4, seg=th&15;
    *(uint4*)&xn[(size_t)(tok0+row)*128+seg*8]=*(const uint4*)&big[row*136+seg*8];
  }
}

// ---------------- qkvg v2: A-frags hoisted from global; only weights in LDS ----------------
__global__ __launch_bounds__(256) void qkvg_kernel(
    const u16* __restrict__ A, const u16* __restrict__ Wt,
    u16* __restrict__ Q, u16* __restrict__ K,
    u16* __restrict__ Vt, u16* __restrict__ G)
{
  __shared__ u16 sW[128][136];     // 34.8 KB; reused as epilogue staging
  u16* stg = &sW[0][0];
  int t = threadIdx.x, lane = t&63, wid = t>>6;
  int mrow = lane&15, quad = lane>>4;
  int r0 = (wid>>1)*32, c0 = (wid&1)*64;
  int tok0 = blockIdx.x*64;
  int b = tok0>>9, l0 = tok0&511;

  // hoist A fragments (own rows; coalesced 16 rows x 64B per load)
  bf16x8 a0f[4], a1f[4];
  #pragma unroll
  for(int ks=0; ks<4; ks++){
    a0f[ks] = *(const bf16x8*)&A[(size_t)(tok0+r0+mrow)*128 + ks*32+quad*8];
    a1f[ks] = *(const bf16x8*)&A[(size_t)(tok0+r0+16+mrow)*128 + ks*32+quad*8];
  }

  for(int ch=0; ch<3; ch++){
    int nc = blockIdx.y*3 + ch;   // 0..5
    int n0 = nc*128;
    if(ch) __syncthreads();       // prev epilogue stores done before restage
    for(int c=t;c<2048;c+=256){ int row=c>>4, col8=(c&15)*8;
      *(uint4*)&sW[row][col8] = *(const uint4*)&Wt[(size_t)(n0+row)*128 + col8]; }
    __syncthreads();

    f32x4 acc[2][4];
    #pragma unroll
    for(int rr=0;rr<2;rr++)
      #pragma unroll
      for(int cc=0;cc<4;cc++) acc[rr][cc] = (f32x4){0.f,0.f,0.f,0.f};
    #pragma unroll
    for(int ks=0; ks<4; ks++){
      int koff = ks*32 + quad*8;
      #pragma unroll
      for(int cc=0; cc<4; cc++){
        bf16x8 bb = *(const bf16x8*)&sW[c0+cc*16+mrow][koff];
        acc[0][cc] = __builtin_amdgcn_mfma_f32_16x16x32_bf16(a0f[ks],bb,acc[0][cc],0,0,0);
        acc[1][cc] = __builtin_amdgcn_mfma_f32_16x16x32_bf16(a1f[ks],bb,acc[1][cc],0,0,0);
      }
    }
    __syncthreads();   // done reading sW -> reuse as staging

    if(nc < 2){
      bool isK = (nc==1);
      #pragma unroll
      for(int cc=0;cc<4;cc++){
        int colc = c0 + cc*16 + mrow;
        int i = (colc&31)>>1;
        float log2bs = log2f(((float)i + 12.8f)*(1.f/44.8f));
        float invf   = exp2f(-(float)i * (13.28771238f/16.f));
        #pragma unroll
        for(int rr=0;rr<2;rr++){
          #pragma unroll
          for(int reg=0;reg<4;reg++){
            int rowl = r0 + rr*16 + quad*4 + reg;
            int l = l0 + rowl;
            float v = acc[rr][cc][reg];
            float partner = __shfl_xor(v, 1);
            float e  = log2bs * (float)l * (1.f/512.f);
            float sc = exp2f(isK ? -e : e);
            float ang = (float)l * invf;
            float cs = cosf(ang)*sc, sn = sinf(ang)*sc;
            float o = (colc&1) ? (v*cs + partner*sn) : (v*cs - partner*sn);
            stg[rowl*136 + colc] = f2bf(o);
          }
        }
      }
      __syncthreads();
      u16* O = isK ? K : Q;
      for(int th=t; th<1024; th+=256){
        int row=th>>4, n=(th>>2)&3, seg=th&3;
        *(uint4*)&O[(((size_t)(b*4+n)*512) + (l0+row))*32 + seg*8]
          = *(const uint4*)&stg[row*136 + n*32 + seg*8];
      }
    } else if(nc < 4){
      #pragma unroll
      for(int cc=0;cc<4;cc++){
        int colc = c0 + cc*16 + mrow;
        #pragma unroll
        for(int rr=0;rr<2;rr++){
          #pragma unroll
          for(int reg=0;reg<4;reg++){
            int rowl = r0 + rr*16 + quad*4 + reg;
            stg[colc*72 + rowl] = f2bf(acc[rr][cc][reg]);
          }
        }
      }
      __syncthreads();
      int jbase = (nc-2)*128;
      for(int th=t; th<1024; th+=256){
        int row=th>>3, seg=th&7;
        int jg = jbase + row; int n = jg>>6, j = jg&63;
        *(uint4*)&Vt[(((size_t)(b*4+n)*64) + j)*512 + l0 + seg*8]
          = *(const uint4*)&stg[row*72 + seg*8];
      }
    } else {
      #pragma unroll
      for(int cc=0;cc<4;cc++){
        int colc = c0 + cc*16 + mrow;
        #pragma unroll
        for(int rr=0;rr<2;rr++){
          #pragma unroll
          for(int reg=0;reg<4;reg++){
            int rowl = r0 + rr*16 + quad*4 + reg;
            stg[rowl*136 + colc] = f2bf(acc[rr][cc][reg]);
          }
        }
      }
      __syncthreads();
      int gc0 = (nc-4)*128;
      for(int th=t; th<1024; th+=256){
        int row=th>>4, seg=th&15;
        *(uint4*)&G[((size_t)(tok0+row))*256 + gc0 + seg*8]
          = *(const uint4*)&stg[row*136 + seg*8];
      }
    }
  }
}

// ---------------- fused MLP v2: 51.2 KB LDS -> 3 blocks/CU ----------------
// Gated -> wo+resid -> Y(regs) -> LN2 -> Z(sT) -> ffn1 -> H(sT) -> ffn2+Y -> X + LN1(next)
__global__ __launch_bounds__(256) void mlp_kernel(
    const u16* __restrict__ Gated, const u16* __restrict__ Wo,
    const u16* __restrict__ W1t, const float* __restrict__ b1,
    const u16* __restrict__ W2t, const float* __restrict__ b2,
    const float* __restrict__ Xin,
    const float* __restrict__ ln2w, const float* __restrict__ ln2b,
    const float* __restrict__ ln1w, const float* __restrict__ ln1b,
    float* __restrict__ Xout, u16* __restrict__ xn)
{
  __shared__ u16 sT[16896];      // 33.8 KB: Z (stride136) / H (stride264) / fp32 stage (stride132 f32)
  __shared__ u16 sW[2][4352];    // 17.4 KB: weight chunks; then xn stage (stride 136)
  int t=threadIdx.x, lane=t&63, wid=t>>6, mrow=lane&15, quad=lane>>4, r0=wid*16;
  int tok0=blockIdx.x*64;

  // gfrag direct from global (own rows)
  bf16x8 gfrag[8];
  #pragma unroll
  for(int ks=0;ks<8;ks++)
    gfrag[ks]=*(const bf16x8*)&Gated[(size_t)(tok0+r0+mrow)*256 + ks*32+quad*8];

  // preload wo chunk 0
  for(int c=t;c<512;c+=256){ int row=c>>5, c8=(c&31)*8;
    *(uint4*)&sW[0][row*264+c8]=*(const uint4*)&Wo[(size_t)row*256+c8]; }
  __syncthreads();

  // ---- wo GEMM: K=256, N=128 in 8 chunks of 16 cols, double-buffered
  f32x4 yac[8];
  #pragma unroll
  for(int ch=0;ch<8;ch++) yac[ch]=(f32x4){0.f,0.f,0.f,0.f};
  #pragma unroll
  for(int ch=0; ch<8; ch++){
    if(ch<7){
      for(int c=t;c<512;c+=256){ int row=c>>5, c8=(c&31)*8;
        *(uint4*)&sW[(ch+1)&1][row*264+c8]=*(const uint4*)&Wo[(size_t)((ch+1)*16+row)*256+c8]; }
    }
    const u16* wb = sW[ch&1];
    #pragma unroll
    for(int ks=0;ks<8;ks++){
      bf16x8 b=*(const bf16x8*)&wb[mrow*264+ks*32+quad*8];
      yac[ch]=__builtin_amdgcn_mfma_f32_16x16x32_bf16(gfrag[ks],b,yac[ch],0,0,0);
    }
    if(ch<7) __syncthreads();
  }

  // ---- Y = yac + Xin (regs); LN2 -> Z bf16 (own rows, stride 136)
  float yv[8][4];
  #pragma unroll
  for(int reg=0;reg<4;reg++){
    int rowl=r0+quad*4+reg, rowg=tok0+rowl;
    float s=0.f, sq=0.f;
    #pragma unroll
    for(int ch=0;ch<8;ch++){
      float v=yac[ch][reg]+Xin[(size_t)rowg*128+ch*16+mrow];
      yv[ch][reg]=v; s+=v; sq+=v*v;
    }
    #pragma unroll
    for(int m=1;m<16;m<<=1){ s+=__shfl_xor(s,m); sq+=__shfl_xor(sq,m); }
    float mu=s*(1.f/128.f);
    float var=sq*(1.f/128.f)-mu*mu;
    float rstd=rsqrtf(var+1e-5f);
    #pragma unroll
    for(int ch=0;ch<8;ch++){
      int col=ch*16+mrow;
      sT[rowl*136+col]=f2bf((yv[ch][reg]-mu)*rstd*ln2w[col]+ln2b[col]);
    }
  }
  // az frags from own rows (same-wave LDS RAW, no barrier needed)
  bf16x8 az[4];
  #pragma unroll
  for(int ks=0;ks<4;ks++) az[ks]=*(const bf16x8*)&sT[(r0+mrow)*136+ks*32+quad*8];

  // preload ffn1 chunk 0; barrier also separates Z reads from H writes (cross-wave overlap)
  for(int c=t;c<512;c+=256){ int row=c>>4, c8=(c&15)*8;
    *(uint4*)&sW[0][row*136+c8]=*(const uint4*)&W1t[(size_t)row*128+c8]; }
  __syncthreads();

  // ---- ffn1: K=128, N=256 in 8 chunks of 32 cols; H -> sT stride 264
  #pragma unroll
  for(int ch=0; ch<8; ch++){
    if(ch<7){
      for(int c=t;c<512;c+=256){ int row=c>>4, c8=(c&15)*8;
        *(uint4*)&sW[(ch+1)&1][row*136+c8]=*(const uint4*)&W1t[(size_t)((ch+1)*32+row)*128+c8]; }
    }
    const u16* wb = sW[ch&1];
    f32x4 h0=(f32x4){0.f,0.f,0.f,0.f}, h1=(f32x4){0.f,0.f,0.f,0.f};
    #pragma unroll
    for(int ks=0;ks<4;ks++){
      bf16x8 bb0=*(const bf16x8*)&wb[mrow*136+ks*32+quad*8];
      bf16x8 bb1=*(const bf16x8*)&wb[(16+mrow)*136+ks*32+quad*8];
      h0=__builtin_amdgcn_mfma_f32_16x16x32_bf16(az[ks],bb0,h0,0,0,0);
      h1=__builtin_amdgcn_mfma_f32_16x16x32_bf16(az[ks],bb1,h1,0,0,0);
    }
    float bs0=b1[ch*32+mrow], bs1=b1[ch*32+16+mrow];
    #pragma unroll
    for(int reg=0;reg<4;reg++){
      int rowl=r0+quad*4+reg;
      sT[rowl*264+ch*32+mrow]    = f2bf(gelu_f(h0[reg]+bs0));
      sT[rowl*264+ch*32+16+mrow] = f2bf(gelu_f(h1[reg]+bs1));
    }
    if(ch<7) __syncthreads();
  }

  // hfrag from own rows (same-wave LDS RAW)
  bf16x8 hfrag[8];
  #pragma unroll
  for(int ks=0;ks<8;ks++) hfrag[ks]=*(const bf16x8*)&sT[(r0+mrow)*264+ks*32+quad*8];

  // preload ffn2 chunk 0 (sW[0] free: ffn1 ch7 used sW[1])
  for(int c=t;c<512;c+=256){ int row=c>>5, c8=(c&31)*8;
    *(uint4*)&sW[0][row*264+c8]=*(const uint4*)&W2t[(size_t)row*256+c8]; }
  __syncthreads();

  // ---- ffn2: K=256, N=128 in 8 chunks of 16 cols
  f32x4 xac[8];
  #pragma unroll
  for(int ch=0;ch<8;ch++) xac[ch]=(f32x4){0.f,0.f,0.f,0.f};
  #pragma unroll
  for(int ch=0; ch<8; ch++){
    if(ch<7){
      for(int c=t;c<512;c+=256){ int row=c>>5, c8=(c&31)*8;
        *(uint4*)&sW[(ch+1)&1][row*264+c8]=*(const uint4*)&W2t[(size_t)((ch+1)*16+row)*256+c8]; }
    }
    const u16* wb = sW[ch&1];
    #pragma unroll
    for(int ks=0;ks<8;ks++){
      bf16x8 b=*(const bf16x8*)&wb[mrow*264+ks*32+quad*8];
      xac[ch]=__builtin_amdgcn_mfma_f32_16x16x32_bf16(hfrag[ks],b,xac[ch],0,0,0);
    }
    if(ch<7) __syncthreads();
  }
  __syncthreads();   // ffn2 ch7 reads done; sW reusable as xn stage

  // ---- epilogue: X = xac + b2 + Y; LN1(next) -> xn; stage in sT(fp32)/sW(bf16)
  float* fst = (float*)sT;       // [64][132]
  u16*   xst = &sW[0][0];        // [64][136]
  #pragma unroll
  for(int reg=0;reg<4;reg++){
    int rowl=r0+quad*4+reg;
    float xv[8], s=0.f, sq=0.f;
    #pragma unroll
    for(int ch=0;ch<8;ch++){
      float v=xac[ch][reg]+b2[ch*16+mrow]+yv[ch][reg];
      xv[ch]=v; s+=v; sq+=v*v;
    }
    #pragma unroll
    for(int m=1;m<16;m<<=1){ s+=__shfl_xor(s,m); sq+=__shfl_xor(sq,m); }
    float mu=s*(1.f/128.f);
    float var=sq*(1.f/128.f)-mu*mu;
    float rstd=rsqrtf(var+1e-5f);
    #pragma unroll
    for(int ch=0;ch<8;ch++){
      int col=ch*16+mrow;
      fst[rowl*132+col]=xv[ch];
      xst[rowl*136+col]=f2bf((xv[ch]-mu)*rstd*ln1w[col]+ln1b[col]);
    }
  }
  __syncthreads();
  for(int th=t; th<2048; th+=256){
    int row=th>>5, c4=(th&31)*4;
    *(float4*)&Xout[(size_t)(tok0+row)*128+c4]=*(const float4*)&fst[row*132+c4];
  }
  for(int th=t; th<1024; th+=256){
    int row=th>>4, seg=th&15;
    *(uint4*)&xn[(size_t)(tok0+row)*128+seg*8]=*(const uint4*)&xst[row*136+seg*8];
  }
}

// ---------------- retention v2 + groupnorm + silu gate (no sQ; 23.6 KB LDS) ----------------
__global__ __launch_bounds__(256) void retmfma_kernel(
    const u16* __restrict__ Q, const u16* __restrict__ K,
    const u16* __restrict__ Vt, const u16* __restrict__ G,
    const float* __restrict__ gnw, const float* __restrict__ gnb,
    u16* __restrict__ Gated, float4 log2g)
{
  int idx = blockIdx.x;
  int bn = ((idx>>6)<<3) | (idx&7);
  int lt = (idx>>3)&7;
  int n = bn & 3, b = bn >> 2;
  float lg2g = (n==0)?log2g.x:(n==1)?log2g.y:(n==2)?log2g.z:log2g.w;
  __shared__ u16 sK[64][40];
  __shared__ u16 sVt[64][72];
  __shared__ u16 sS[64][72];
  int t = threadIdx.x, lane = t&63, wid = t>>6;
  int mrow = lane&15, quad = lane>>4;
  int r0 = wid*16;

  // qa direct from global (own rows)
  bf16x8 qa = *(const bf16x8*)&Q[((size_t)bn*512 + lt*64 + r0+mrow)*32 + quad*8];

  f32x4 oacc[4];
  #pragma unroll
  for(int cc=0;cc<4;cc++) oacc[cc] = (f32x4){0.f,0.f,0.f,0.f};
  float gp1 = exp2f(lg2g), gp2 = gp1*gp1, gp3 = gp2*gp1;
  float gpow[4] = {1.f, gp1, gp2, gp3};
  float gw[4], gb[4];
  #pragma unroll
  for(int cc=0;cc<4;cc++){ gw[cc]=gnw[n*64+cc*16+mrow]; gb[cc]=gnb[n*64+cc*16+mrow]; }
  int rowl0 = lt*64 + r0 + quad*4;

  for(int mt=0; mt<=lt; mt++){
    if(mt) __syncthreads();
    {
      int row = t>>2, c8 = (t&3)*8;
      *(uint4*)&sK[row][c8] = *(const uint4*)&K[((size_t)bn*512 + mt*64 + row)*32 + c8];
      int vrow = t>>3, vc8 = (t&7)*8;
      *(uint4*)&sVt[vrow][vc8]    = *(const uint4*)&Vt[((size_t)bn*64 + vrow)*512    + mt*64 + vc8];
      *(uint4*)&sVt[vrow+32][vc8] = *(const uint4*)&Vt[((size_t)bn*64 + vrow+32)*512 + mt*64 + vc8];
    }
    __syncthreads();
    f32x4 sacc[4];
    #pragma unroll
    for(int cc=0;cc<4;cc++){
      bf16x8 bb = *(const bf16x8*)&sK[cc*16+mrow][quad*8];
      sacc[cc] = __builtin_amdgcn_mfma_f32_16x16x32_bf16(qa,bb,(f32x4){0.f,0.f,0.f,0.f},0,0,0);
    }
    #pragma unroll
    for(int cc=0;cc<4;cc++){
      int colm = mt*64 + cc*16 + mrow;
      int d0 = rowl0 - colm;
      float w0 = exp2f(lg2g*(float)d0);
      #pragma unroll
      for(int reg=0;reg<4;reg++){
        float w = (d0+reg>=0) ? w0*gpow[reg] : 0.f;
        sS[r0+quad*4+reg][cc*16+mrow] = f2bf(sacc[cc][reg]*w);
      }
    }
    __syncthreads();
    #pragma unroll
    for(int ks=0;ks<2;ks++){
      bf16x8 a = *(const bf16x8*)&sS[r0+mrow][ks*32+quad*8];
      #pragma unroll
      for(int cc=0;cc<4;cc++){
        bf16x8 bb = *(const bf16x8*)&sVt[cc*16+mrow][ks*32+quad*8];
        oacc[cc] = __builtin_amdgcn_mfma_f32_16x16x32_bf16(a,bb,oacc[cc],0,0,0);
      }
    }
  }

  __syncthreads();
  #pragma unroll
  for(int reg=0;reg<4;reg++){
    float s=0.f, sq=0.f;
    #pragma unroll
    for(int cc=0;cc<4;cc++){ float v=oacc[cc][reg]; s+=v; sq+=v*v; }
    #pragma unroll
    for(int m=1;m<16;m<<=1){ s+=__shfl_xor(s,m); sq+=__shfl_xor(sq,m); }
    float mu = s*(1.f/64.f);
    float var = sq*(1.f/64.f) - mu*mu;
    float rn = rsqrtf(var + 1e-5f);
    int rowl = r0 + quad*4 + reg;
    int l = lt*64 + rowl;
    size_t gbase = ((size_t)(b*512 + l))*256 + n*64;
    #pragma unroll
    for(int cc=0;cc<4;cc++){
      float gg = bf2f(G[gbase + cc*16+mrow]);
      float gate = gg/(1.f+expf(-gg));
      sS[rowl][cc*16+mrow] = f2bf(gate*((oacc[cc][reg]-mu)*rn*gw[cc] + gb[cc]));
    }
  }
  __syncthreads();
  for(int th=t; th<512; th+=256){
    int row=th>>3, seg=th&7;
    *(uint4*)&Gated[((size_t)(b*512 + lt*64 + row))*256 + n*64 + seg*8]
      = *(const uint4*)&sS[row][seg*8];
  }
}

// ---------------- decoder (MFMA): softmax(gelu(X@w1+b1)@w2+b2) ----------------
__global__ __launch_bounds__(256) void dec_kernel(
    const float* __restrict__ X, const u16* __restrict__ W1t,
    const float* __restrict__ b1, const float* __restrict__ w2,
    const float* __restrict__ b2, float* __restrict__ out)
{
  __shared__ u16 sA[64][136];
  __shared__ u16 sW[64][136];
  __shared__ float sH[64][68];
  __shared__ float sL[64*20];
  __shared__ float sw2[64*20];
  __shared__ float sb2[20];
  int t = threadIdx.x, lane = t&63, wid = t>>6;
  int mrow = lane&15, quad = lane>>4;
  int tok0 = blockIdx.x*64;

  for(int th=t; th<2048; th+=256){
    int row=th>>5, c4=(th&31)*4;
    float4 v = *(const float4*)&X[(size_t)(tok0+row)*128 + c4];
    ushort4 p; p.x=f2bf(v.x); p.y=f2bf(v.y); p.z=f2bf(v.z); p.w=f2bf(v.w);
    *(ushort4*)&sA[row][c4] = p;
  }
  for(int th=t; th<1024; th+=256){
    int row=th>>4, c8=(th&15)*8;
    *(uint4*)&sW[row][c8] = *(const uint4*)&W1t[(size_t)row*128 + c8];
  }
  for(int i=t;i<1280;i+=256) sw2[i]=w2[i];
  if(t<20) sb2[t]=b2[t];
  __syncthreads();

  int r0 = wid*16;
  f32x4 acc[4];
  #pragma unroll
  for(int cc=0;cc<4;cc++) acc[cc] = (f32x4){0.f,0.f,0.f,0.f};
  #pragma unroll
  for(int ks=0; ks<4; ks++){
    int koff = ks*32 + quad*8;
    bf16x8 a = *(const bf16x8*)&sA[r0+mrow][koff];
    #pragma unroll
    for(int cc=0; cc<4; cc++){
      bf16x8 b = *(const bf16x8*)&sW[cc*16+mrow][koff];
      acc[cc] = __builtin_amdgcn_mfma_f32_16x16x32_bf16(a,b,acc[cc],0,0,0);
    }
  }
  #pragma unroll
  for(int cc=0;cc<4;cc++){
    int col = cc*16 + mrow;
    float bb = b1[col];
    #pragma unroll
    for(int reg=0;reg<4;reg++){
      sH[r0 + quad*4 + reg][col] = gelu_f(acc[cc][reg] + bb);
    }
  }
  __syncthreads();

  for(int task=t; task<1280; task+=256){
    int tk = task/20, o = task - tk*20;
    float a = sb2[o];
    for(int k=0;k<64;k++) a += sH[tk][k]*sw2[k*20+o];
    sL[tk*20+o] = a;
  }
  __syncthreads();
  if(t < 64){
    float mx = -1e30f;
    #pragma unroll
    for(int o=0;o<20;o++) mx = fmaxf(mx, sL[t*20+o]);
    float sum = 0.f;
    float e[20];
    #pragma unroll
    for(int o=0;o<20;o++){ e[o]=expf(sL[t*20+o]-mx); sum += e[o]; }
    float inv = 1.f/sum;
    #pragma unroll
    for(int o=0;o<20;o++) sL[t*20+o] = e[o]*inv;
  }
  __syncthreads();
  for(int th=t; th<1280; th+=256){
    out[(size_t)tok0*20 + th] = sL[th];
  }
}

extern "C" void kernel_launch(void* const* d_in, const int* in_sizes, int n_in,
                              void* d_out, int out_size, void* d_ws, size_t ws_size,
                              hipStream_t stream) {
  (void)in_sizes; (void)n_in; (void)out_size; (void)ws_size;
  const float* x      = (const float*)d_in[0];
  const float* rem_w1 = (const float*)d_in[1];
  const float* rem_b1 = (const float*)d_in[2];
  const float* rem_w2 = (const float*)d_in[3];
  const float* rem_b2 = (const float*)d_in[4];
  const float* rem_w3 = (const float*)d_in[5];
  const float* rem_b3 = (const float*)d_in[6];
  const float* wq     = (const float*)d_in[7];
  const float* wk     = (const float*)d_in[8];
  const float* wv     = (const float*)d_in[9];
  const float* wg     = (const float*)d_in[10];
  const float* wo     = (const float*)d_in[11];
  const float* gn_w   = (const float*)d_in[12];
  const float* gn_b   = (const float*)d_in[13];
  const float* ln1_w  = (const float*)d_in[14];
  const float* ln1_b  = (const float*)d_in[15];
  const float* ln2_w  = (const float*)d_in[16];
  const float* ln2_b  = (const float*)d_in[17];
  const float* ffn_w1 = (const float*)d_in[18];
  const float* ffn_b1 = (const float*)d_in[19];
  const float* ffn_w2 = (const float*)d_in[20];
  const float* ffn_b2 = (const float*)d_in[21];
  const float* dec_w1 = (const float*)d_in[22];
  const float* dec_b1 = (const float*)d_in[23];
  const float* dec_w2 = (const float*)d_in[24];
  const float* dec_b2 = (const float*)d_in[25];
  float* outp = (float*)d_out;

  const size_t S128 = (size_t)BT*128;
  const size_t S256 = (size_t)BT*256;
  float* ws = (float*)d_ws;
  float* Xb = ws;                  // residual X        (S128 f32)
  u16*  Qb16    = (u16*)(Xb + S128);     // Q bf16 head-layout (BT*32)
  u16*  Kb16    = Qb16 + (size_t)BT*32;
  u16*  Vt16    = Kb16 + (size_t)BT*32;  // V bf16 transposed (BT*64)
  u16*  XnBf    = Vt16 + (size_t)BT*64;  // LN out bf16   (S128)
  u16*  GBf     = XnBf + S128;           // G bf16        (S256)
  u16*  GatedBf = GBf + S256;            // gated        (S256)
  u16*  WtBf    = GatedBf + S256;        // bf16 weights  (804864 u16)

  double lgA = log(1.0/32.0), lgB = log(1.0/512.0);
  float4 l2g;
  {
    double g0 = 1.0 - exp(lgA + 0.0*(lgB-lgA)/3.0);
    double g1 = 1.0 - exp(lgA + 1.0*(lgB-lgA)/3.0);
    double g2 = 1.0 - exp(lgA + 2.0*(lgB-lgA)/3.0);
    double g3 = 1.0 - exp(lgA + 3.0*(lgB-lgA)/3.0);
    l2g.x = (float)(log(g0)/log(2.0));
    l2g.y = (float)(log(g1)/log(2.0));
    l2g.z = (float)(log(g2)/log(2.0));
    l2g.w = (float)(log(g3)/log(2.0));
  }

  wconv_kernel<<<3144, 256, 0, stream>>>(wq, wk, wv, wg, wo, ffn_w1, ffn_w2, dec_w1,
                                         rem_w2, rem_w3, WtBf);
  embed_kernel<<<BT/64, 256, 0, stream>>>(x, rem_w1, rem_b1, rem_b2, rem_b3,
                                          WtBf+794624, ln1_w, ln1_b, Xb, XnBf);

  for(int li=0; li<4; li++){
    u16* Wt_l = WtBf + (size_t)li*196608;
    const float* gnw_l = gn_w + (size_t)li*VDIM;
    const float* gnb_l = gn_b + (size_t)li*VDIM;
    const float* l2w = ln2_w + (size_t)li*HID, *l2b = ln2_b + (size_t)li*HID;
    const float* f1b = ffn_b1 + (size_t)li*FFND;
    const float* f2b = ffn_b2 + (size_t)li*HID;
    int nli = (li+1)&3;  // LN1 weights for next layer (unused result at li==3)
    const float* n1w = ln1_w + (size_t)nli*HID, *n1b = ln1_b + (size_t)nli*HID;

    qkvg_kernel<<<dim3(BT/64,2), 256, 0, stream>>>(XnBf, Wt_l, Qb16, Kb16, Vt16, GBf);
    retmfma_kernel<<<2048, 256, 0, stream>>>(Qb16, Kb16, Vt16, GBf, gnw_l, gnb_l, GatedBf, l2g);
    mlp_kernel<<<BT/64, 256, 0, stream>>>(
        GatedBf, Wt_l+98304, Wt_l+131072, f1b, Wt_l+163840, f2b,
        Xb, l2w, l2b, n1w, n1b, Xb, XnBf);
  }

  dec_kernel<<<BT/64, 256, 0, stream>>>(Xb, WtBf+786432, dec_b1, dec_w2, dec_b2, outp);
}